// Round 4
// baseline (660.662 us; speedup 1.0000x reference)
//
#include <hip/hip_runtime.h>

typedef unsigned short u16;
typedef __bf16 bf16x8 __attribute__((ext_vector_type(8)));
typedef float f4 __attribute__((ext_vector_type(4)));
typedef float float4v __attribute__((ext_vector_type(4)));
typedef u16 u16x4 __attribute__((ext_vector_type(4)));

#define NX 11796480   // B*T*D = 3840*3072
#define LDP 136       // padded LDS row (u16 elems) for P / Vt in temporal attn

__device__ __forceinline__ float bf2f(u16 u){ __bf16 h = __builtin_bit_cast(__bf16, u); return (float)h; }
__device__ __forceinline__ u16 f2bf(float f){ __bf16 h = (__bf16)f; return __builtin_bit_cast(u16, h); }

__device__ __forceinline__ void gload_lds16(const u16* g, u16* l){
  __builtin_amdgcn_global_load_lds((const __attribute__((address_space(1))) void*)g,
                                   (__attribute__((address_space(3))) void*)l, 16, 0, 0);
}

// ---------------- fused prep: zero BN accs + all fp32->bf16 conversions + QKV weight pack ----------------
__device__ __forceinline__ void cvt4seg(const float* __restrict__ in, u16* __restrict__ out, int i){
  float4v v = *(const float4v*)&in[i*4];
  u16x4 o;
  o[0]=f2bf(v[0]); o[1]=f2bf(v[1]); o[2]=f2bf(v[2]); o[3]=f2bf(v[3]);
  *(u16x4*)&out[i*4] = o;
}

// total items = 18432 + 2949120 + 2359296 + 2359296 + 196608 + 196608 + 2359296 = 10438656 = 40776*256
__global__ void k_prep(const float* __restrict__ src, u16* __restrict__ x_bf,
                       const float* __restrict__ wpt, u16* __restrict__ wptb,
                       const float* __restrict__ wps, u16* __restrict__ wpsb,
                       const float* __restrict__ w1,  u16* __restrict__ w1b,
                       const float* __restrict__ w2,  u16* __restrict__ w2b,
                       const float* __restrict__ wqt, const float* __restrict__ wkt,
                       const float* __restrict__ wvt, const float* __restrict__ wqs,
                       const float* __restrict__ wks, const float* __restrict__ wvs,
                       u16* __restrict__ wcat, float* __restrict__ accs){
  int i = blockIdx.x*256 + threadIdx.x;
  if (i < 18432){ accs[i] = 0.f; return; }
  i -= 18432;
  if (i < 2949120){ cvt4seg(src, x_bf, i); return; }
  i -= 2949120;
  if (i < 2359296){ cvt4seg(wpt, wptb, i); return; }
  i -= 2359296;
  if (i < 2359296){ cvt4seg(wps, wpsb, i); return; }
  i -= 2359296;
  if (i < 196608){ cvt4seg(w1, w1b, i); return; }
  i -= 196608;
  if (i < 196608){ cvt4seg(w2, w2b, i); return; }
  i -= 196608;
  // pack Wq_t|Wk_t|Wv_t|Wq_s|Wk_s|Wv_s into (J=24, N=768, K=128) row-major bf16
  int e = i & 127;
  int n = (i >> 7) % 768;
  int j = i / (768*128);
  float v;
  if (n < 512){
    int tn = n >> 7, hh = (n >> 4) & 7, dd = n & 15;
    const float* W = (tn==0)? wqt : (tn==1)? wkt : (tn==2)? wvt : wqs;  // (H,J,d,E)
    v = W[(((hh*24 + j)*16 + dd) << 7) + e];
  } else {
    int m = n - 512;
    int tn = m >> 7, hh = (m >> 4) & 7, dd = m & 15;
    const float* W = (tn==0)? wks : wvs;                                // (H,d,E)
    v = W[((hh*16 + dd) << 7) + e];
  }
  wcat[i] = f2bf(v);
}

// ---------------- MFMA GEMM core (BK=64): C[128,128] tile of A[M,K]*B[N,K]^T ----------------
// (kept for gemm_relu / gemm_ff2 — small-K GEMMs)
__device__ __forceinline__ void gemm_tile(const u16* __restrict__ Ab, int lda,
                                          const u16* __restrict__ Bb, int ldb,
                                          int K, f4 acc[4][4], u16* As, u16* Bs)
{
  const int tid  = threadIdx.x;
  const int lane = tid & 63;
  const int wid  = tid >> 6;
  const int waveM = (wid >> 1) * 64;
  const int waveN = (wid & 1) * 64;
  const int quad = lane >> 4;
  const int r16  = lane & 15;
  const int srow = tid >> 3;                       // 0..31
  const int gcol = ((tid & 7) ^ (srow & 7)) * 8;   // swizzled source column

  #pragma unroll
  for (int mt=0; mt<4; mt++)
    #pragma unroll
    for (int nt=0; nt<4; nt++)
      #pragma unroll
      for (int q=0; q<4; q++) acc[mt][nt][q] = 0.f;

  for (int k0 = 0; k0 < K; k0 += 64){
    __syncthreads();
    #pragma unroll
    for (int i=0; i<4; i++){
      int row = srow + i*32;
      gload_lds16(&Ab[(size_t)row*lda + k0 + gcol], As + wid*512 + i*2048);
      gload_lds16(&Bb[(size_t)row*ldb + k0 + gcol], Bs + wid*512 + i*2048);
    }
    __builtin_amdgcn_s_waitcnt(0);
    __syncthreads();
    #pragma unroll
    for (int kk=0; kk<2; kk++){
      bf16x8 af[4], bfr[4];
      const int soff = ((kk*4 + quad) ^ (r16 & 7)) * 8;   // swizzled read slot
      #pragma unroll
      for (int mt=0; mt<4; mt++)
        af[mt] = *(const bf16x8*)&As[(waveM + mt*16 + r16)*64 + soff];
      #pragma unroll
      for (int nt=0; nt<4; nt++)
        bfr[nt] = *(const bf16x8*)&Bs[(waveN + nt*16 + r16)*64 + soff];
      #pragma unroll
      for (int mt=0; mt<4; mt++)
        #pragma unroll
        for (int nt=0; nt<4; nt++)
          acc[mt][nt] = __builtin_amdgcn_mfma_f32_16x16x32_bf16(af[mt], bfr[nt], acc[mt][nt], 0, 0, 0);
    }
  }
  __syncthreads();
}

// ---------------- QKV GEMM: stage A once, loop 6 B-chunks of 128 (N=768 total) ----------------
__global__ __launch_bounds__(256)
void gemm_qkv(const u16* __restrict__ x, const u16* __restrict__ wcat,
              u16* __restrict__ qt, u16* __restrict__ kt, u16* __restrict__ vt,
              u16* __restrict__ qs, u16* __restrict__ ks, u16* __restrict__ vs)
{
  __shared__ __align__(16) u16 As[128*128];
  __shared__ __align__(16) u16 Bs[128*128];
  int m0 = blockIdx.x*128, j = blockIdx.y;
  const u16* Ab = x + (size_t)m0*3072 + j*128;
  const u16* Bbase = wcat + (size_t)j*98304;
  int tid = threadIdx.x, lane = tid & 63, wid = tid >> 6;
  int quad = lane >> 4, r16 = lane & 15;
  int srow16 = tid >> 4;                   // 0..15
  int cslot  = tid & 15;
  int gcol   = (cslot ^ srow16) * 8;       // swizzled source column

  #pragma unroll
  for (int it=0; it<8; it++){
    int row = srow16 + it*16;
    gload_lds16(&Ab[(size_t)row*3072 + gcol], As + tid*8 + it*2048);
  }

  int waveM = (wid>>1)*64, waveN = (wid&1)*64;

  for (int nc=0; nc<6; nc++){
    const u16* Bb = Bbase + (size_t)(nc*128)*128;
    #pragma unroll
    for (int it=0; it<8; it++){
      int row = srow16 + it*16;
      gload_lds16(&Bb[(size_t)row*128 + gcol], Bs + tid*8 + it*2048);
    }
    __builtin_amdgcn_s_waitcnt(0);
    __syncthreads();

    f4 acc[4][4];
    #pragma unroll
    for (int mt=0; mt<4; mt++)
      #pragma unroll
      for (int nt=0; nt<4; nt++)
        #pragma unroll
        for (int q=0; q<4; q++) acc[mt][nt][q] = 0.f;

    #pragma unroll
    for (int kk=0; kk<4; kk++){
      bf16x8 af[4], bfr[4];
      const int soff = ((kk*4 + quad) ^ r16) * 8;
      #pragma unroll
      for (int mt=0; mt<4; mt++)
        af[mt] = *(const bf16x8*)&As[(waveM + mt*16 + r16)*128 + soff];
      #pragma unroll
      for (int nt=0; nt<4; nt++)
        bfr[nt] = *(const bf16x8*)&Bs[(waveN + nt*16 + r16)*128 + soff];
      #pragma unroll
      for (int mt=0; mt<4; mt++)
        #pragma unroll
        for (int nt=0; nt<4; nt++)
          acc[mt][nt] = __builtin_amdgcn_mfma_f32_16x16x32_bf16(af[mt], bfr[nt], acc[mt][nt], 0, 0, 0);
    }

    #pragma unroll
    for (int mt=0; mt<4; mt++){
      #pragma unroll
      for (int reg=0; reg<4; reg++){
        int row = m0 + waveM + mt*16 + quad*4 + reg;   // bt index
        int b = row / 120, t = row % 120;
        #pragma unroll
        for (int nt=0; nt<4; nt++){
          int n = nc*128 + waveN + nt*16 + r16;
          u16 uv = f2bf(acc[mt][nt][reg]);
          if (n < 384){
            int tn = n >> 7, hh = (n >> 4) & 7, dd = n & 15;
            u16* base = (tn==0)? qt : (tn==1)? kt : vt;
            base[((((size_t)(b*8+hh)*24 + j)*120 + t) << 4) + dd] = uv;
          } else {
            int m2 = n - 384;
            int tn = m2 >> 7, hh = (m2 >> 4) & 7, dd = m2 & 15;
            u16* base = (tn==0)? qs : (tn==1)? ks : vs;
            base[((((size_t)row*8 + hh)*24 + j) << 4) + dd] = uv;
          }
        }
      }
    }
    __syncthreads();   // all waves done reading Bs before next chunk restages
  }
}

// ================= 256x384 dual-projection GEMM, BK=32, 3-slot rotating LDS =================
// Grid 15 x 8 x 2 = 240 blocks = ONE full round on 256 CUs (no tail).
// 512 threads = 8 waves (2M x 4N); per-wave output 128x96 (8 m-frags x 6 n-frags).
// LDS: 3 slots x { A[256][32] (16 KB) | B[384][32] (24 KB) } = 120 KiB.
// Ledger: tile t reads slot t%3; stages A(t+2),B(t+2) into slot (t+2)%3 (freed at end
// of t-1); vmcnt(5) at end of t retires all but tile t+2's 5 issues -> tile t+1 published.
// ONE barrier + ONE vmcnt per K-tile; never vmcnt(0) in the loop.
//
// R4 change: ALL 14 ds_reads (both m-groups) issued first, then both DMA stages, then one
// 48-MFMA cluster in a single setprio window. Previously the setprio builtins fenced the
// p1 ds_reads behind p0's MFMAs -> LDS pipe and MFMA pipe alternated instead of overlapping
// (measured 46% MfmaUtil ~ 1862 MFMA clk / 3350 tile clk with 896 LDS clk exposed serially).

__device__ __forceinline__ void stageA384(const u16* __restrict__ g, int kcol,
                                          u16* __restrict__ slotA, int lane, int wid){
  #pragma unroll
  for (int i=0;i<2;i++){
    int row = wid*32 + i*16 + (lane>>2);
    int sw  = (((lane & 3) ^ ((lane>>3) & 3)) << 3);   // inverse of read swizzle
    gload_lds16(&g[(size_t)row*3072 + kcol + sw], slotA + (wid*2+i)*512);
  }
}
__device__ __forceinline__ void stageB384(const u16* __restrict__ g, int kcol,
                                          u16* __restrict__ slotB, int lane, int wid){
  #pragma unroll
  for (int i=0;i<3;i++){
    int row = wid*48 + i*16 + (lane>>2);
    int sw  = (((lane & 3) ^ ((lane>>3) & 3)) << 3);
    gload_lds16(&g[(size_t)row*3072 + kcol + sw], slotB + (wid*3+i)*512);
  }
}

__global__ __launch_bounds__(512, 2)
void gemm_proj384(const u16* __restrict__ A0, const u16* __restrict__ B0, const float* __restrict__ b0,
                  const u16* __restrict__ A1, const u16* __restrict__ B1, const float* __restrict__ b1v,
                  const u16* __restrict__ resb, u16* __restrict__ O0, u16* __restrict__ O1,
                  float* __restrict__ st0, float* __restrict__ st1)
{
  __shared__ __align__(16) u16 smem[61440];     // 120 KiB = 3 slots x 20480 u16
  const int tid = threadIdx.x, lane = tid & 63, wid = tid >> 6;
  const int quad = lane >> 4, r16 = lane & 15;
  const int wm = wid >> 2, wn = wid & 3;

  // bijective XCD chunk swizzle over 240 blocks
  int lin = blockIdx.x + 15*blockIdx.y + 120*blockIdx.z;
  int nidx = (lin & 7)*30 + (lin >> 3);
  int zz = nidx / 120; int rem = nidx - zz*120;
  int by = rem / 15, bx = rem - by*15;

  const int m0 = bx*256, n0 = by*384;
  const u16* Ag = (zz ? A1 : A0) + (size_t)m0*3072;
  const u16* Bg = (zz ? B1 : B0) + (size_t)n0*3072;
  const float* bias = zz ? b1v : b0;
  u16* out = zz ? O1 : O0;
  float* stp = zz ? st1 : st0;

  const int soff = ((quad ^ ((r16>>1)&3)) << 3);
  const int arow = wm*128 + r16;
  const int brow = wn*96 + r16;

  f4 acc[8][6];
  #pragma unroll
  for (int i=0;i<8;i++)
    #pragma unroll
    for (int n=0;n<6;n++)
      #pragma unroll
      for (int q=0;q<4;q++) acc[i][n][q] = 0.f;

  u16* Sa = smem;            // slot holding tile t
  u16* Sb = smem + 20480;    // tile t+1
  u16* Sc = smem + 40960;    // tile t+2 (stage target)

  // prologue: tiles 0 and 1 (10 issues/wave)
  stageA384(Ag, 0,  Sa,        lane, wid);
  stageB384(Bg, 0,  Sa + 8192, lane, wid);
  stageA384(Ag, 32, Sb,        lane, wid);
  stageB384(Bg, 32, Sb + 8192, lane, wid);
  asm volatile("s_waitcnt vmcnt(5)" ::: "memory");   // tile 0 landed
  __builtin_amdgcn_s_barrier();

  const int NT = 96;                                 // K = 3072, BK = 32

  for (int t=0; t<NT; ++t){
    const int kc2 = ((t+2 < NT) ? (t+2) : 0) * 32;   // clamped tail lands in dead slot

    // ---- all reads for tile t first (no fences between reads and MFMA cluster) ----
    bf16x8 a0[4], a1[4], bb[6];
    #pragma unroll
    for (int i=0;i<4;i++) a0[i] = *(const bf16x8*)&Sa[(arow + i*16)*32 + soff];
    #pragma unroll
    for (int n=0;n<6;n++) bb[n] = *(const bf16x8*)&Sa[8192 + (brow + n*16)*32 + soff];
    #pragma unroll
    for (int i=0;i<4;i++) a1[i] = *(const bf16x8*)&Sa[(arow + 64 + i*16)*32 + soff];

    // ---- DMA stage tile t+2 (issues only; retired by future vmcnt) ----
    stageA384(Ag, kc2, Sc, lane, wid);
    stageB384(Bg, kc2, Sc + 8192, lane, wid);

    // ---- one MFMA cluster for the whole tile ----
    __builtin_amdgcn_s_setprio(1);
    #pragma unroll
    for (int i=0;i<4;i++)
      #pragma unroll
      for (int n=0;n<6;n++)
        acc[i][n] = __builtin_amdgcn_mfma_f32_16x16x32_bf16(a0[i], bb[n], acc[i][n], 0,0,0);
    #pragma unroll
    for (int i=0;i<4;i++)
      #pragma unroll
      for (int n=0;n<6;n++)
        acc[4+i][n] = __builtin_amdgcn_mfma_f32_16x16x32_bf16(a1[i], bb[n], acc[4+i][n], 0,0,0);
    __builtin_amdgcn_s_setprio(0);

    asm volatile("s_waitcnt vmcnt(5)" ::: "memory"); // tile t+1 published
    __builtin_amdgcn_s_barrier();
    u16* tp = Sa; Sa = Sb; Sb = Sc; Sc = tp;         // rotate slots
  }
  asm volatile("s_waitcnt vmcnt(0)" ::: "memory");   // drain clamped tail DMAs

  // ---------- epilogue: bias + residual + bf16 store + fused BN stats ----------
  float bv[6];
  #pragma unroll
  for (int n=0;n<6;n++) bv[n] = bias[n0 + wn*96 + n*16 + r16];
  float s[6] = {0,0,0,0,0,0}, s2[6] = {0,0,0,0,0,0};
  #pragma unroll
  for (int mf=0; mf<8; mf++){
    #pragma unroll
    for (int reg=0; reg<4; reg++){
      int grow = m0 + wm*128 + mf*16 + quad*4 + reg;
      #pragma unroll
      for (int n=0;n<6;n++){
        int gcol = n0 + wn*96 + n*16 + r16;
        size_t idx = (size_t)grow*3072 + gcol;
        float v = acc[mf][n][reg] + bv[n] + bf2f(resb[idx]);
        out[idx] = f2bf(v);
        s[n] += v; s2[n] += v*v;
      }
    }
  }
  #pragma unroll
  for (int n=0;n<6;n++){
    float a = s[n], b = s2[n];
    a += __shfl_xor(a, 16); a += __shfl_xor(a, 32);
    b += __shfl_xor(b, 16); b += __shfl_xor(b, 32);
    if (quad == 0){
      int col = n0 + wn*96 + n*16 + r16;
      atomicAdd(&stp[col], a);
      atomicAdd(&stp[3072 + col], b);
    }
  }
}

// ---------------- FF2 with fused BN stats ----------------
__global__ __launch_bounds__(256)
void gemm_ff2(const u16* __restrict__ A, const u16* __restrict__ B, const float* __restrict__ bias,
              const u16* __restrict__ resb, u16* __restrict__ out, float* __restrict__ stp)
{
  __shared__ __align__(16) u16 As[128*64];
  __shared__ __align__(16) u16 Bs[128*64];
  int m0 = blockIdx.x*128, n0 = blockIdx.y*128;
  f4 acc[4][4];
  gemm_tile(A + (size_t)m0*256, 256, B + (size_t)n0*256, 256, 256, acc, As, Bs);
  int lane = threadIdx.x & 63, wid = threadIdx.x >> 6;
  int waveM = (wid>>1)*64, waveN = (wid&1)*64;
  int quad = lane>>4, r16 = lane&15;
  float s[4] = {0,0,0,0}, s2[4] = {0,0,0,0};
  #pragma unroll
  for (int mt=0; mt<4; mt++){
    #pragma unroll
    for (int reg=0; reg<4; reg++){
      int grow = m0 + waveM + mt*16 + quad*4 + reg;
      #pragma unroll
      for (int nt=0; nt<4; nt++){
        int gcol = n0 + waveN + nt*16 + r16;
        size_t idx = (size_t)grow*3072 + gcol;
        float v = acc[mt][nt][reg] + bias[gcol] + bf2f(resb[idx]);
        out[idx] = f2bf(v);
        s[nt] += v; s2[nt] += v*v;
      }
    }
  }
  #pragma unroll
  for (int nt=0; nt<4; nt++){
    float a = s[nt], b = s2[nt];
    a += __shfl_xor(a, 16); a += __shfl_xor(a, 32);
    b += __shfl_xor(b, 16); b += __shfl_xor(b, 32);
    if (quad == 0){
      int col = n0 + waveN + nt*16 + r16;
      atomicAdd(&stp[col], a);
      atomicAdd(&stp[3072 + col], b);
    }
  }
}

// FF1: out bf16 = relu(A@B^T + bias)
__global__ __launch_bounds__(256)
void gemm_relu(const u16* __restrict__ A, const u16* __restrict__ B, int K, int N,
               const float* __restrict__ bias, u16* __restrict__ out)
{
  __shared__ __align__(16) u16 As[128*64];
  __shared__ __align__(16) u16 Bs[128*64];
  int m0 = blockIdx.x*128, n0 = blockIdx.y*128;
  f4 acc[4][4];
  gemm_tile(A + (size_t)m0*K, K, B + (size_t)n0*K, K, K, acc, As, Bs);
  int lane = threadIdx.x & 63, wid = threadIdx.x >> 6;
  int waveM = (wid>>1)*64, waveN = (wid&1)*64;
  int quad = lane>>4, r16 = lane&15;
  #pragma unroll
  for (int mt=0; mt<4; mt++){
    #pragma unroll
    for (int reg=0; reg<4; reg++){
      int grow = m0 + waveM + mt*16 + quad*4 + reg;
      #pragma unroll
      for (int nt=0; nt<4; nt++){
        int gcol = n0 + waveN + nt*16 + r16;
        float v = acc[mt][nt][reg] + bias[gcol];
        out[(size_t)grow*N + gcol] = f2bf(v > 0.f ? v : 0.f);
      }
    }
  }
}

// ---------------- merged attention: blocks [0,6144) temporal MFMA, [6144,9984) spatial ----------------
__global__ __launch_bounds__(256)
void attn_both(const u16* __restrict__ qt, const u16* __restrict__ kt,
               const u16* __restrict__ vt, u16* __restrict__ ta,
               const u16* __restrict__ qsp, const u16* __restrict__ ksp,
               const u16* __restrict__ vsp, u16* __restrict__ sa)
{
  __shared__ __align__(16) char smem[39168];
  int tid = threadIdx.x, lane = tid & 63, wid = tid >> 6;
  int quad = lane >> 4, r16 = lane & 15;

  if (blockIdx.x < 6144){
    // ---- temporal: one block per (b,h,j), T=120 pad 128, d=16 pad 32 ----
    u16* P  = (u16*)smem;             // 128*LDP
    u16* Vt = (u16*)(smem + 34816);   // 16*LDP
    int blk = blockIdx.x;
    int b = blk / 192;
    int rem = blk % 192;
    int h = rem / 24, j = rem % 24;
    const u16* qb = qt + (size_t)blk*1920;
    const u16* kb = kt + (size_t)blk*1920;
    const u16* vb = vt + (size_t)blk*1920;

    for (int e = tid; e < 1920; e += 256){
      int s = e >> 4, dd = e & 15;
      Vt[dd*LDP + s] = vb[e];
    }
    if (tid < 128){ int dd = tid >> 3, s = 120 + (tid & 7); Vt[dd*LDP + s] = 0; }
    __syncthreads();

    bf16x8 zv;
    #pragma unroll
    for (int i=0;i<8;i++) zv[i] = (__bf16)0.f;

    const int m0 = wid * 32;
    bf16x8 qf[2];
    #pragma unroll
    for (int mt=0; mt<2; mt++){
      int row = m0 + mt*16 + r16; if (row > 119) row = 119;
      qf[mt] = (quad < 2) ? *(const bf16x8*)&qb[row*16 + (quad&1)*8] : zv;
    }

    f4 S[2][8];
    #pragma unroll
    for (int nt=0; nt<8; nt++){
      int col = nt*16 + r16; int colc = col > 119 ? 119 : col;
      bf16x8 kf = (quad < 2) ? *(const bf16x8*)&kb[colc*16 + (quad&1)*8] : zv;
      #pragma unroll
      for (int mt=0; mt<2; mt++){
        f4 zz = {0.f, 0.f, 0.f, 0.f};
        S[mt][nt] = __builtin_amdgcn_mfma_f32_16x16x32_bf16(qf[mt], kf, zz, 0, 0, 0);
      }
    }

    #pragma unroll
    for (int mt=0; mt<2; mt++)
      #pragma unroll
      for (int nt=0; nt<8; nt++)
        #pragma unroll
        for (int reg=0; reg<4; reg++){
          int c = nt*16 + r16;
          int r = m0 + mt*16 + quad*4 + reg;
          float v = S[mt][nt][reg] * 0.25f;
          S[mt][nt][reg] = (c > r || c >= 120) ? -1e30f : v;
        }

    float Zr[2][4];
    #pragma unroll
    for (int mt=0; mt<2; mt++)
      #pragma unroll
      for (int reg=0; reg<4; reg++){
        float m = -1e30f;
        #pragma unroll
        for (int nt=0; nt<8; nt++) m = fmaxf(m, S[mt][nt][reg]);
        #pragma unroll
        for (int off=1; off<16; off<<=1) m = fmaxf(m, __shfl_xor(m, off, 16));
        float z = 0.f;
        #pragma unroll
        for (int nt=0; nt<8; nt++){
          float e = __expf(S[mt][nt][reg] - m);
          S[mt][nt][reg] = e;
          z += e;
        }
        #pragma unroll
        for (int off=1; off<16; off<<=1) z += __shfl_xor(z, off, 16);
        Zr[mt][reg] = z;
      }

    #pragma unroll
    for (int mt=0; mt<2; mt++)
      #pragma unroll
      for (int nt=0; nt<8; nt++)
        #pragma unroll
        for (int reg=0; reg<4; reg++)
          P[(m0 + mt*16 + quad*4 + reg)*LDP + nt*16 + r16] = f2bf(S[mt][nt][reg]);
    __syncthreads();

    f4 O[2];
    #pragma unroll
    for (int mt=0; mt<2; mt++){ O[mt][0]=0.f; O[mt][1]=0.f; O[mt][2]=0.f; O[mt][3]=0.f; }
    #pragma unroll
    for (int kt8=0; kt8<4; kt8++){
      bf16x8 vf = *(const bf16x8*)&Vt[r16*LDP + kt8*32 + quad*8];
      #pragma unroll
      for (int mt=0; mt<2; mt++){
        bf16x8 pf = *(const bf16x8*)&P[(m0 + mt*16 + r16)*LDP + kt8*32 + quad*8];
        O[mt] = __builtin_amdgcn_mfma_f32_16x16x32_bf16(pf, vf, O[mt], 0, 0, 0);
      }
    }

    #pragma unroll
    for (int mt=0; mt<2; mt++)
      #pragma unroll
      for (int reg=0; reg<4; reg++){
        int r = m0 + mt*16 + quad*4 + reg;
        if (r < 120){
          size_t idx = (size_t)(b*120 + r)*3072 + h*384 + j*16 + r16;
          ta[idx] = f2bf(O[mt][reg] / Zr[mt][reg]);
        }
      }
  } else {
    // ---- spatial: one block per (b,t); threads 0..191 = (h,j); softmax over 24 joints ----
    float* Ks = (float*)smem;            // 3072
    float* Vs = (float*)(smem + 12288);  // 3072
    int bt = blockIdx.x - 6144;
    size_t base = (size_t)bt * 3072;
    for (int c = tid; c < 384; c += 256){
      bf16x8 kv = *(const bf16x8*)&ksp[base + c*8];
      bf16x8 vv = *(const bf16x8*)&vsp[base + c*8];
      #pragma unroll
      for (int i=0;i<8;i++){ Ks[c*8+i] = (float)kv[i]; Vs[c*8+i] = (float)vv[i]; }
    }
    __syncthreads();
    if (tid < 192){
      int h = tid / 24, j = tid % 24;
      float q[16];
      #pragma unroll
      for (int d2=0; d2<16; d2++) q[d2] = bf2f(qsp[base + h*384 + j*16 + d2]);
      float sc[24], mx = -1e30f;
      #pragma unroll
      for (int kk=0; kk<24; kk++){
        float dot = 0.f;
        #pragma unroll
        for (int d2=0; d2<16; d2++) dot += q[d2]*Ks[h*384 + kk*16 + d2];
        sc[kk] = dot * 0.25f;
        mx = fmaxf(mx, sc[kk]);
      }
      float Z = 0.f, acc[16];
      #pragma unroll
      for (int d2=0; d2<16; d2++) acc[d2] = 0.f;
      #pragma unroll
      for (int kk=0; kk<24; kk++){
        float w = __expf(sc[kk] - mx);
        Z += w;
        #pragma unroll
        for (int d2=0; d2<16; d2++) acc[d2] += w*Vs[h*384 + kk*16 + d2];
      }
      float inv = 1.f / Z;
      #pragma unroll
      for (int d2=0; d2<16; d2++) sa[base + h*384 + j*16 + d2] = f2bf(acc[d2]*inv);
    }
  }
}

// ---------------- batchnorm ----------------
// blocks 0..11: temporal coefs; 12..23: spatial coefs
__global__ void bn_coef2(const float* __restrict__ accT, const float* __restrict__ gT,
                         const float* __restrict__ bT, float* __restrict__ cT,
                         const float* __restrict__ accS, const float* __restrict__ gS,
                         const float* __restrict__ bS, float* __restrict__ cS){
  int isS = blockIdx.x >= 12;
  const float* acc = isS ? accS : accT;
  const float* g   = isS ? gS : gT;
  const float* b   = isS ? bS : bT;
  float* coef      = isS ? cS : cT;
  int c = (blockIdx.x % 12)*256 + threadIdx.x;
  float mean = acc[c] * (1.f/3840.f);
  float var  = acc[3072+c] * (1.f/3840.f) - mean*mean;
  float sc = g[c] * rsqrtf(var + 1e-5f);
  coef[c] = sc;
  coef[3072+c] = b[c] - mean*sc;
}

__global__ void bn_coef(const float* __restrict__ acc, const float* __restrict__ g,
                        const float* __restrict__ b, float* __restrict__ coef){
  int c = blockIdx.x*256 + threadIdx.x;
  float mean = acc[c] * (1.f/3840.f);
  float var  = acc[3072+c] * (1.f/3840.f) - mean*mean;
  float sc = g[c] * rsqrtf(var + 1e-5f);
  coef[c] = sc;
  coef[3072+c] = b[c] - mean*sc;
}

// att = BN_t(Yt) + BN_s(Ys), vectorized x4  (channel = (i*4) mod 3072 — NOT a pow2 mask!)
__global__ void bn_apply2(const u16* __restrict__ Ytb, const u16* __restrict__ Ysb,
                          const float* __restrict__ ct, const float* __restrict__ cs,
                          u16* __restrict__ attB){
  int i = blockIdx.x*256 + threadIdx.x;     // < NX/4
  int c = (i*4) % 3072;
  u16x4 yt = *(const u16x4*)&Ytb[i*4];
  u16x4 ys = *(const u16x4*)&Ysb[i*4];
  u16x4 o;
  #pragma unroll
  for (int k=0;k<4;k++){
    float a = bf2f(yt[k])*ct[c+k] + ct[3072+c+k] + bf2f(ys[k])*cs[c+k] + cs[3072+c+k];
    o[k] = f2bf(a);
  }
  *(u16x4*)&attB[i*4] = o;
}

__global__ void bn_out(const u16* __restrict__ Yfb, const float* __restrict__ cf,
                       float* __restrict__ out){
  int i = blockIdx.x*256 + threadIdx.x;     // < NX/4
  int c = (i*4) % 3072;
  u16x4 yf = *(const u16x4*)&Yfb[i*4];
  float4v o;
  #pragma unroll
  for (int k=0;k<4;k++) o[k] = bf2f(yf[k])*cf[c+k] + cf[3072+c+k];
  *(float4v*)&out[i*4] = o;
}

// ---------------- launch ----------------
extern "C" void kernel_launch(void* const* d_in, const int* in_sizes, int n_in,
                              void* d_out, int out_size, void* d_ws, size_t ws_size,
                              hipStream_t stream)
{
  const float* src  = (const float*)d_in[0];
  const float* Wq_t = (const float*)d_in[1];
  const float* Wk_t = (const float*)d_in[2];
  const float* Wv_t = (const float*)d_in[3];
  const float* Wp_t = (const float*)d_in[4];
  const float* bp_t = (const float*)d_in[5];
  const float* g_t  = (const float*)d_in[6];
  const float* b_t  = (const float*)d_in[7];
  const float* Wq_s = (const float*)d_in[8];
  const float* Wk_s = (const float*)d_in[9];
  const float* Wv_s = (const float*)d_in[10];
  const float* Wp_s = (const float*)d_in[11];
  const float* bp_s = (const float*)d_in[12];
  const float* g_s  = (const float*)d_in[13];
  const float* b_s  = (const float*)d_in[14];
  const float* W1   = (const float*)d_in[15];
  const float* b1   = (const float*)d_in[16];
  const float* W2   = (const float*)d_in[17];
  const float* b2   = (const float*)d_in[18];
  const float* g_f  = (const float*)d_in[19];
  const float* b_f  = (const float*)d_in[20];

  char* ws = (char*)d_ws;
  u16* x_bf  = (u16*)(ws + 0ull);
  u16* wptb  = (u16*)(ws + 23592960ull);
  u16* wpsb  = (u16*)(ws + 42467328ull);
  u16* w1b   = (u16*)(ws + 61341696ull);
  u16* w2b   = (u16*)(ws + 62914560ull);
  u16* wcat  = (u16*)(ws + 64487424ull);
  u16* qt    = (u16*)(ws + 69206016ull);
  u16* kt    = qt + NX;
  u16* vt    = kt + NX;
  u16* qs    = vt + NX;
  u16* ks    = qs + NX;
  u16* vs    = ks + NX;
  u16* tab   = (u16*)(ws + 210763776ull);
  u16* sab   = (u16*)(ws + 234356736ull);
  float* accT = (float*)(ws + 257949696ull);
  float* accS = accT + 6144;
  float* accF = accS + 6144;
  float* cT   = accF + 6144;
  float* cS   = cT + 6144;
  float* cF   = cS + 6144;
  // bf16 aliases over dead regions
  u16* Ytb  = qt;   // dead after attention
  u16* Ysb  = kt;
  u16* attB = vt;
  u16* Yfb  = qs;
  u16* h1   = wcat; // dead after gemm_qkv
  float* out = (float*)d_out;

  // 1. fused prep (zero accs + conversions + weight pack)
  k_prep<<<40776, 256, 0, stream>>>(src, x_bf, Wp_t, wptb, Wp_s, wpsb, W1, w1b, W2, w2b,
                                    Wq_t, Wk_t, Wv_t, Wq_s, Wk_s, Wv_s, wcat, accT);
  // 2. QKV projections (per joint; A staged once, 6 B-chunks)
  gemm_qkv<<<dim3(30,24), 256, 0, stream>>>(x_bf, wcat, qt, kt, vt, qs, ks, vs);
  // 3. both attentions in one launch
  attn_both<<<9984, 256, 0, stream>>>(qt, kt, vt, tab, qs, ks, vs, sab);
  // 4. output projections + residual + fused BN stats (256x384, 240 blocks, XCD-chunked)
  gemm_proj384<<<dim3(15,8,2), 512, 0, stream>>>(tab, wptb, bp_t, sab, wpsb, bp_s,
                                                 x_bf, Ytb, Ysb, accT, accS);
  // 5. BN coefs (t+s) + fused apply
  bn_coef2<<<24, 256, 0, stream>>>(accT, g_t, b_t, cT, accS, g_s, b_s, cS);
  bn_apply2<<<11520, 256, 0, stream>>>(Ytb, Ysb, cT, cS, attB);
  // 6. feed-forward
  gemm_relu<<<dim3(30,2), 256, 0, stream>>>(attB, w1b, 3072, 256, b1, h1);
  gemm_ff2<<<dim3(30,24), 256, 0, stream>>>(h1, w2b, b2, attB, Yfb, accF);
  // 7. final BN
  bn_coef<<<12, 256, 0, stream>>>(accF, g_f, b_f, cF);
  bn_out<<<11520, 256, 0, stream>>>(Yfb, cF, out);
}

// Round 5
// 558.655 us; speedup vs baseline: 1.1826x; 1.1826x over previous
//
#include <hip/hip_runtime.h>

typedef unsigned short u16;
typedef __bf16 bf16x8 __attribute__((ext_vector_type(8)));
typedef float f4 __attribute__((ext_vector_type(4)));
typedef float float4v __attribute__((ext_vector_type(4)));
typedef u16 u16x4 __attribute__((ext_vector_type(4)));

#define NX 11796480   // B*T*D = 3840*3072
#define LDP 136       // padded LDS row (u16 elems) for P / Vt in temporal attn

__device__ __forceinline__ float bf2f(u16 u){ __bf16 h = __builtin_bit_cast(__bf16, u); return (float)h; }
__device__ __forceinline__ u16 f2bf(float f){ __bf16 h = (__bf16)f; return __builtin_bit_cast(u16, h); }

__device__ __forceinline__ void gload_lds16(const u16* g, u16* l){
  __builtin_amdgcn_global_load_lds((const __attribute__((address_space(1))) void*)g,
                                   (__attribute__((address_space(3))) void*)l, 16, 0, 0);
}

// ---------------- fused prep: zero BN accs + all fp32->bf16 conversions + QKV weight pack ----------------
__device__ __forceinline__ void cvt4seg(const float* __restrict__ in, u16* __restrict__ out, int i){
  float4v v = *(const float4v*)&in[i*4];
  u16x4 o;
  o[0]=f2bf(v[0]); o[1]=f2bf(v[1]); o[2]=f2bf(v[2]); o[3]=f2bf(v[3]);
  *(u16x4*)&out[i*4] = o;
}

// total items = 18432 + 2949120 + 2359296 + 2359296 + 196608 + 196608 + 2359296 = 10438656 = 40776*256
__global__ void k_prep(const float* __restrict__ src, u16* __restrict__ x_bf,
                       const float* __restrict__ wpt, u16* __restrict__ wptb,
                       const float* __restrict__ wps, u16* __restrict__ wpsb,
                       const float* __restrict__ w1,  u16* __restrict__ w1b,
                       const float* __restrict__ w2,  u16* __restrict__ w2b,
                       const float* __restrict__ wqt, const float* __restrict__ wkt,
                       const float* __restrict__ wvt, const float* __restrict__ wqs,
                       const float* __restrict__ wks, const float* __restrict__ wvs,
                       u16* __restrict__ wcat, float* __restrict__ accs){
  int i = blockIdx.x*256 + threadIdx.x;
  if (i < 18432){ accs[i] = 0.f; return; }
  i -= 18432;
  if (i < 2949120){ cvt4seg(src, x_bf, i); return; }
  i -= 2949120;
  if (i < 2359296){ cvt4seg(wpt, wptb, i); return; }
  i -= 2359296;
  if (i < 2359296){ cvt4seg(wps, wpsb, i); return; }
  i -= 2359296;
  if (i < 196608){ cvt4seg(w1, w1b, i); return; }
  i -= 196608;
  if (i < 196608){ cvt4seg(w2, w2b, i); return; }
  i -= 196608;
  // pack Wq_t|Wk_t|Wv_t|Wq_s|Wk_s|Wv_s into (J=24, N=768, K=128) row-major bf16
  int e = i & 127;
  int n = (i >> 7) % 768;
  int j = i / (768*128);
  float v;
  if (n < 512){
    int tn = n >> 7, hh = (n >> 4) & 7, dd = n & 15;
    const float* W = (tn==0)? wqt : (tn==1)? wkt : (tn==2)? wvt : wqs;  // (H,J,d,E)
    v = W[(((hh*24 + j)*16 + dd) << 7) + e];
  } else {
    int m = n - 512;
    int tn = m >> 7, hh = (m >> 4) & 7, dd = m & 15;
    const float* W = (tn==0)? wks : wvs;                                // (H,d,E)
    v = W[((hh*16 + dd) << 7) + e];
  }
  wcat[i] = f2bf(v);
}

// ---------------- MFMA GEMM core (BK=64): C[128,128] tile of A[M,K]*B[N,K]^T ----------------
// (kept for gemm_ff2 — small-K GEMM)
__device__ __forceinline__ void gemm_tile(const u16* __restrict__ Ab, int lda,
                                          const u16* __restrict__ Bb, int ldb,
                                          int K, f4 acc[4][4], u16* As, u16* Bs)
{
  const int tid  = threadIdx.x;
  const int lane = tid & 63;
  const int wid  = tid >> 6;
  const int waveM = (wid >> 1) * 64;
  const int waveN = (wid & 1) * 64;
  const int quad = lane >> 4;
  const int r16  = lane & 15;
  const int srow = tid >> 3;                       // 0..31
  const int gcol = ((tid & 7) ^ (srow & 7)) * 8;   // swizzled source column

  #pragma unroll
  for (int mt=0; mt<4; mt++)
    #pragma unroll
    for (int nt=0; nt<4; nt++)
      #pragma unroll
      for (int q=0; q<4; q++) acc[mt][nt][q] = 0.f;

  for (int k0 = 0; k0 < K; k0 += 64){
    __syncthreads();
    #pragma unroll
    for (int i=0; i<4; i++){
      int row = srow + i*32;
      gload_lds16(&Ab[(size_t)row*lda + k0 + gcol], As + wid*512 + i*2048);
      gload_lds16(&Bb[(size_t)row*ldb + k0 + gcol], Bs + wid*512 + i*2048);
    }
    __builtin_amdgcn_s_waitcnt(0);
    __syncthreads();
    #pragma unroll
    for (int kk=0; kk<2; kk++){
      bf16x8 af[4], bfr[4];
      const int soff = ((kk*4 + quad) ^ (r16 & 7)) * 8;   // swizzled read slot
      #pragma unroll
      for (int mt=0; mt<4; mt++)
        af[mt] = *(const bf16x8*)&As[(waveM + mt*16 + r16)*64 + soff];
      #pragma unroll
      for (int nt=0; nt<4; nt++)
        bfr[nt] = *(const bf16x8*)&Bs[(waveN + nt*16 + r16)*64 + soff];
      #pragma unroll
      for (int mt=0; mt<4; mt++)
        #pragma unroll
        for (int nt=0; nt<4; nt++)
          acc[mt][nt] = __builtin_amdgcn_mfma_f32_16x16x32_bf16(af[mt], bfr[nt], acc[mt][nt], 0, 0, 0);
    }
  }
  __syncthreads();
}

// ---------------- QKV GEMM: stage A once, loop 6 B-chunks of 128 (N=768 total) ----------------
__global__ __launch_bounds__(256)
void gemm_qkv(const u16* __restrict__ x, const u16* __restrict__ wcat,
              u16* __restrict__ qt, u16* __restrict__ kt, u16* __restrict__ vt,
              u16* __restrict__ qs, u16* __restrict__ ks, u16* __restrict__ vs)
{
  __shared__ __align__(16) u16 As[128*128];
  __shared__ __align__(16) u16 Bs[128*128];
  int m0 = blockIdx.x*128, j = blockIdx.y;
  const u16* Ab = x + (size_t)m0*3072 + j*128;
  const u16* Bbase = wcat + (size_t)j*98304;
  int tid = threadIdx.x, lane = tid & 63, wid = tid >> 6;
  int quad = lane >> 4, r16 = lane & 15;
  int srow16 = tid >> 4;                   // 0..15
  int cslot  = tid & 15;
  int gcol   = (cslot ^ srow16) * 8;       // swizzled source column

  #pragma unroll
  for (int it=0; it<8; it++){
    int row = srow16 + it*16;
    gload_lds16(&Ab[(size_t)row*3072 + gcol], As + tid*8 + it*2048);
  }

  int waveM = (wid>>1)*64, waveN = (wid&1)*64;

  for (int nc=0; nc<6; nc++){
    const u16* Bb = Bbase + (size_t)(nc*128)*128;
    #pragma unroll
    for (int it=0; it<8; it++){
      int row = srow16 + it*16;
      gload_lds16(&Bb[(size_t)row*128 + gcol], Bs + tid*8 + it*2048);
    }
    __builtin_amdgcn_s_waitcnt(0);
    __syncthreads();

    f4 acc[4][4];
    #pragma unroll
    for (int mt=0; mt<4; mt++)
      #pragma unroll
      for (int nt=0; nt<4; nt++)
        #pragma unroll
        for (int q=0; q<4; q++) acc[mt][nt][q] = 0.f;

    #pragma unroll
    for (int kk=0; kk<4; kk++){
      bf16x8 af[4], bfr[4];
      const int soff = ((kk*4 + quad) ^ r16) * 8;
      #pragma unroll
      for (int mt=0; mt<4; mt++)
        af[mt] = *(const bf16x8*)&As[(waveM + mt*16 + r16)*128 + soff];
      #pragma unroll
      for (int nt=0; nt<4; nt++)
        bfr[nt] = *(const bf16x8*)&Bs[(waveN + nt*16 + r16)*128 + soff];
      #pragma unroll
      for (int mt=0; mt<4; mt++)
        #pragma unroll
        for (int nt=0; nt<4; nt++)
          acc[mt][nt] = __builtin_amdgcn_mfma_f32_16x16x32_bf16(af[mt], bfr[nt], acc[mt][nt], 0, 0, 0);
    }

    #pragma unroll
    for (int mt=0; mt<4; mt++){
      #pragma unroll
      for (int reg=0; reg<4; reg++){
        int row = m0 + waveM + mt*16 + quad*4 + reg;   // bt index
        int b = row / 120, t = row % 120;
        #pragma unroll
        for (int nt=0; nt<4; nt++){
          int n = nc*128 + waveN + nt*16 + r16;
          u16 uv = f2bf(acc[mt][nt][reg]);
          if (n < 384){
            int tn = n >> 7, hh = (n >> 4) & 7, dd = n & 15;
            u16* base = (tn==0)? qt : (tn==1)? kt : vt;
            base[((((size_t)(b*8+hh)*24 + j)*120 + t) << 4) + dd] = uv;
          } else {
            int m2 = n - 384;
            int tn = m2 >> 7, hh = (m2 >> 4) & 7, dd = m2 & 15;
            u16* base = (tn==0)? qs : (tn==1)? ks : vs;
            base[((((size_t)row*8 + hh)*24 + j) << 4) + dd] = uv;
          }
        }
      }
    }
    __syncthreads();   // all waves done reading Bs before next chunk restages
  }
}

// ================= 256x384 dual-projection GEMM, BK=32, 3-slot rotating LDS =================
// (R3-verified structure: 133.9 µs, MfmaUtil 46.5%. R4's merged-cluster variant regressed —
//  the p0/p1 split + setprio fences form the software pipeline; do not merge.)
// Grid 15 x 8 x 2 = 240 blocks = ONE full round on 256 CUs (no tail).
// 512 threads = 8 waves (2M x 4N); per-wave output 128x96 (8 m-frags x 6 n-frags).
// LDS: 3 slots x { A[256][32] (16 KB) | B[384][32] (24 KB) } = 120 KiB.
// Ledger: tile t reads slot t%3; stages A(t+2),B(t+2) into slot (t+2)%3 (freed at end
// of t-1); vmcnt(5) at end of t retires all but tile t+2's 5 issues -> tile t+1 published.
// ONE barrier + ONE vmcnt per K-tile; never vmcnt(0) in the loop.

__device__ __forceinline__ void stageA384(const u16* __restrict__ g, int kcol,
                                          u16* __restrict__ slotA, int lane, int wid){
  #pragma unroll
  for (int i=0;i<2;i++){
    int row = wid*32 + i*16 + (lane>>2);
    int sw  = (((lane & 3) ^ ((lane>>3) & 3)) << 3);   // inverse of read swizzle
    gload_lds16(&g[(size_t)row*3072 + kcol + sw], slotA + (wid*2+i)*512);
  }
}
__device__ __forceinline__ void stageB384(const u16* __restrict__ g, int kcol,
                                          u16* __restrict__ slotB, int lane, int wid){
  #pragma unroll
  for (int i=0;i<3;i++){
    int row = wid*48 + i*16 + (lane>>2);
    int sw  = (((lane & 3) ^ ((lane>>3) & 3)) << 3);
    gload_lds16(&g[(size_t)row*3072 + kcol + sw], slotB + (wid*3+i)*512);
  }
}

__global__ __launch_bounds__(512, 2)
void gemm_proj384(const u16* __restrict__ A0, const u16* __restrict__ B0, const float* __restrict__ b0,
                  const u16* __restrict__ A1, const u16* __restrict__ B1, const float* __restrict__ b1v,
                  const u16* __restrict__ resb, u16* __restrict__ O0, u16* __restrict__ O1,
                  float* __restrict__ st0, float* __restrict__ st1)
{
  __shared__ __align__(16) u16 smem[61440];     // 120 KiB = 3 slots x 20480 u16
  const int tid = threadIdx.x, lane = tid & 63, wid = tid >> 6;
  const int quad = lane >> 4, r16 = lane & 15;
  const int wm = wid >> 2, wn = wid & 3;

  // bijective XCD chunk swizzle over 240 blocks
  int lin = blockIdx.x + 15*blockIdx.y + 120*blockIdx.z;
  int nidx = (lin & 7)*30 + (lin >> 3);
  int zz = nidx / 120; int rem = nidx - zz*120;
  int by = rem / 15, bx = rem - by*15;

  const int m0 = bx*256, n0 = by*384;
  const u16* Ag = (zz ? A1 : A0) + (size_t)m0*3072;
  const u16* Bg = (zz ? B1 : B0) + (size_t)n0*3072;
  const float* bias = zz ? b1v : b0;
  u16* out = zz ? O1 : O0;
  float* stp = zz ? st1 : st0;

  const int soff = ((quad ^ ((r16>>1)&3)) << 3);
  const int arow = wm*128 + r16;
  const int brow = wn*96 + r16;

  f4 acc[8][6];
  #pragma unroll
  for (int i=0;i<8;i++)
    #pragma unroll
    for (int n=0;n<6;n++)
      #pragma unroll
      for (int q=0;q<4;q++) acc[i][n][q] = 0.f;

  u16* Sa = smem;            // slot holding tile t
  u16* Sb = smem + 20480;    // tile t+1
  u16* Sc = smem + 40960;    // tile t+2 (stage target)

  // prologue: tiles 0 and 1 (10 issues/wave)
  stageA384(Ag, 0,  Sa,        lane, wid);
  stageB384(Bg, 0,  Sa + 8192, lane, wid);
  stageA384(Ag, 32, Sb,        lane, wid);
  stageB384(Bg, 32, Sb + 8192, lane, wid);
  asm volatile("s_waitcnt vmcnt(5)" ::: "memory");   // tile 0 landed
  __builtin_amdgcn_s_barrier();

  const int NT = 96;                                 // K = 3072, BK = 32
  bf16x8 af[4], bf[6];

  for (int t=0; t<NT; ++t){
    const int kc2 = ((t+2 < NT) ? (t+2) : 0) * 32;   // clamped tail lands in dead slot

    // ---- p0: m-group 0 + all B frags; stage A(t+2) ----
    #pragma unroll
    for (int i=0;i<4;i++) af[i] = *(const bf16x8*)&Sa[(arow + i*16)*32 + soff];
    #pragma unroll
    for (int n=0;n<6;n++) bf[n] = *(const bf16x8*)&Sa[8192 + (brow + n*16)*32 + soff];
    stageA384(Ag, kc2, Sc, lane, wid);
    __builtin_amdgcn_s_setprio(1);
    #pragma unroll
    for (int i=0;i<4;i++)
      #pragma unroll
      for (int n=0;n<6;n++)
        acc[i][n] = __builtin_amdgcn_mfma_f32_16x16x32_bf16(af[i], bf[n], acc[i][n], 0,0,0);
    __builtin_amdgcn_s_setprio(0);

    // ---- p1: m-group 1 (reuse bf); stage B(t+2) ----
    #pragma unroll
    for (int i=0;i<4;i++) af[i] = *(const bf16x8*)&Sa[(arow + 64 + i*16)*32 + soff];
    stageB384(Bg, kc2, Sc + 8192, lane, wid);
    __builtin_amdgcn_s_setprio(1);
    #pragma unroll
    for (int i=0;i<4;i++)
      #pragma unroll
      for (int n=0;n<6;n++)
        acc[4+i][n] = __builtin_amdgcn_mfma_f32_16x16x32_bf16(af[i], bf[n], acc[4+i][n], 0,0,0);
    __builtin_amdgcn_s_setprio(0);

    asm volatile("s_waitcnt vmcnt(5)" ::: "memory"); // tile t+1 published
    __builtin_amdgcn_s_barrier();
    u16* tp = Sa; Sa = Sb; Sb = Sc; Sc = tp;         // rotate slots
  }
  asm volatile("s_waitcnt vmcnt(0)" ::: "memory");   // drain clamped tail DMAs

  // ---------- epilogue: bias + residual + bf16 store + fused BN stats ----------
  float bv[6];
  #pragma unroll
  for (int n=0;n<6;n++) bv[n] = bias[n0 + wn*96 + n*16 + r16];
  float s[6] = {0,0,0,0,0,0}, s2[6] = {0,0,0,0,0,0};
  #pragma unroll
  for (int mf=0; mf<8; mf++){
    #pragma unroll
    for (int reg=0; reg<4; reg++){
      int grow = m0 + wm*128 + mf*16 + quad*4 + reg;
      #pragma unroll
      for (int n=0;n<6;n++){
        int gcol = n0 + wn*96 + n*16 + r16;
        size_t idx = (size_t)grow*3072 + gcol;
        float v = acc[mf][n][reg] + bv[n] + bf2f(resb[idx]);
        out[idx] = f2bf(v);
        s[n] += v; s2[n] += v*v;
      }
    }
  }
  #pragma unroll
  for (int n=0;n<6;n++){
    float a = s[n], b = s2[n];
    a += __shfl_xor(a, 16); a += __shfl_xor(a, 32);
    b += __shfl_xor(b, 16); b += __shfl_xor(b, 32);
    if (quad == 0){
      int col = n0 + wn*96 + n*16 + r16;
      atomicAdd(&stp[col], a);
      atomicAdd(&stp[3072 + col], b);
    }
  }
}

// ---------------- FF2 with fused BN stats ----------------
__global__ __launch_bounds__(256)
void gemm_ff2(const u16* __restrict__ A, const u16* __restrict__ B, const float* __restrict__ bias,
              const u16* __restrict__ resb, u16* __restrict__ out, float* __restrict__ stp)
{
  __shared__ __align__(16) u16 As[128*64];
  __shared__ __align__(16) u16 Bs[128*64];
  int m0 = blockIdx.x*128, n0 = blockIdx.y*128;
  f4 acc[4][4];
  gemm_tile(A + (size_t)m0*256, 256, B + (size_t)n0*256, 256, 256, acc, As, Bs);
  int lane = threadIdx.x & 63, wid = threadIdx.x >> 6;
  int waveM = (wid>>1)*64, waveN = (wid&1)*64;
  int quad = lane>>4, r16 = lane&15;
  float s[4] = {0,0,0,0}, s2[4] = {0,0,0,0};
  #pragma unroll
  for (int mt=0; mt<4; mt++){
    #pragma unroll
    for (int reg=0; reg<4; reg++){
      int grow = m0 + waveM + mt*16 + quad*4 + reg;
      #pragma unroll
      for (int nt=0; nt<4; nt++){
        int gcol = n0 + waveN + nt*16 + r16;
        size_t idx = (size_t)grow*3072 + gcol;
        float v = acc[mt][nt][reg] + bias[gcol] + bf2f(resb[idx]);
        out[idx] = f2bf(v);
        s[nt] += v; s2[nt] += v*v;
      }
    }
  }
  #pragma unroll
  for (int nt=0; nt<4; nt++){
    float a = s[nt], b = s2[nt];
    a += __shfl_xor(a, 16); a += __shfl_xor(a, 32);
    b += __shfl_xor(b, 16); b += __shfl_xor(b, 32);
    if (quad == 0){
      int col = n0 + waveN + nt*16 + r16;
      atomicAdd(&stp[col], a);
      atomicAdd(&stp[3072 + col], b);
    }
  }
}

// ---------------- FF1: out bf16 = relu(A@W1^T + bias), 32x128 tiles, 3-slot pipeline ----------------
// Grid (120,2) = 240 blocks (one full round; old version was 60 blocks = 23% of CUs with 48
// serial full-drain k-steps). Ledger identical to proj384: 5 issues/thread per K-tile
// (1 A + 4 B), vmcnt(5) at end of tile t publishes tile t+1. LDS 3 x 20 KB = 60 KB.
__device__ __forceinline__ void stageR_A(const u16* __restrict__ g, int kc, u16* __restrict__ slot,
                                         int tid, int srow, int gcol){
  gload_lds16(&g[(size_t)srow*3072 + kc + gcol], slot + tid*8);
}
__device__ __forceinline__ void stageR_B(const u16* __restrict__ g, int kc, u16* __restrict__ slot,
                                         int tid, int srow, int gcol){
  #pragma unroll
  for (int i=0;i<4;i++)
    gload_lds16(&g[(size_t)(srow + i*32)*3072 + kc + gcol], slot + 2048 + i*2048 + tid*8);
}

__global__ __launch_bounds__(256)
void gemm_relu(const u16* __restrict__ A, const u16* __restrict__ B,
               const float* __restrict__ bias, u16* __restrict__ out)
{
  __shared__ __align__(16) u16 smem[30720];   // 3 slots x (A 2048 + B 8192) u16 = 60 KB
  const int tid = threadIdx.x, lane = tid & 63, wid = tid >> 6;
  const int quad = lane >> 4, r16 = lane & 15;
  const int waveM = (wid >> 1) * 16, waveN = (wid & 1) * 64;
  const int m0 = blockIdx.x * 32, n0 = blockIdx.y * 128;
  const u16* Ag = A + (size_t)m0 * 3072;
  const u16* Bg = B + (size_t)n0 * 3072;

  const int srow = tid >> 3;                        // 0..31
  const int gcol = ((tid & 7) ^ (srow & 7)) * 8;    // swizzled source column

  f4 acc[4];
  #pragma unroll
  for (int n=0;n<4;n++)
    #pragma unroll
    for (int q=0;q<4;q++) acc[n][q] = 0.f;

  u16* Sa = smem;            // tile t
  u16* Sb = smem + 10240;    // tile t+1
  u16* Sc = smem + 20480;    // tile t+2 (stage target)

  stageR_A(Ag, 0,  Sa, tid, srow, gcol);
  stageR_B(Bg, 0,  Sa, tid, srow, gcol);
  stageR_A(Ag, 64, Sb, tid, srow, gcol);
  stageR_B(Bg, 64, Sb, tid, srow, gcol);
  asm volatile("s_waitcnt vmcnt(5)" ::: "memory");   // tile 0 landed
  __builtin_amdgcn_s_barrier();

  const int NT = 48;                                 // K = 3072, BK = 64
  const int s0 = (quad ^ (r16 & 7)) * 8;
  const int s1 = ((4 + quad) ^ (r16 & 7)) * 8;

  for (int t=0; t<NT; ++t){
    const int kc2 = ((t+2 < NT) ? (t+2) : 0) * 64;

    // p0: kk=0; stage A(t+2)
    bf16x8 a0 = *(const bf16x8*)&Sa[(waveM + r16)*64 + s0];
    bf16x8 b0[4];
    #pragma unroll
    for (int n=0;n<4;n++) b0[n] = *(const bf16x8*)&Sa[2048 + (waveN + n*16 + r16)*64 + s0];
    stageR_A(Ag, kc2, Sc, tid, srow, gcol);
    __builtin_amdgcn_s_setprio(1);
    #pragma unroll
    for (int n=0;n<4;n++)
      acc[n] = __builtin_amdgcn_mfma_f32_16x16x32_bf16(a0, b0[n], acc[n], 0,0,0);
    __builtin_amdgcn_s_setprio(0);

    // p1: kk=1; stage B(t+2)
    bf16x8 a1 = *(const bf16x8*)&Sa[(waveM + r16)*64 + s1];
    bf16x8 b1[4];
    #pragma unroll
    for (int n=0;n<4;n++) b1[n] = *(const bf16x8*)&Sa[2048 + (waveN + n*16 + r16)*64 + s1];
    stageR_B(Bg, kc2, Sc, tid, srow, gcol);
    __builtin_amdgcn_s_setprio(1);
    #pragma unroll
    for (int n=0;n<4;n++)
      acc[n] = __builtin_amdgcn_mfma_f32_16x16x32_bf16(a1, b1[n], acc[n], 0,0,0);
    __builtin_amdgcn_s_setprio(0);

    asm volatile("s_waitcnt vmcnt(5)" ::: "memory"); // tile t+1 published
    __builtin_amdgcn_s_barrier();
    u16* tp = Sa; Sa = Sb; Sb = Sc; Sc = tp;
  }
  asm volatile("s_waitcnt vmcnt(0)" ::: "memory");   // drain clamped tail DMAs

  #pragma unroll
  for (int n=0;n<4;n++){
    int gcolo = n0 + waveN + n*16 + r16;
    float bv = bias[gcolo];
    #pragma unroll
    for (int reg=0; reg<4; reg++){
      int grow = m0 + waveM + quad*4 + reg;
      float v = acc[n][reg] + bv;
      out[(size_t)grow*256 + gcolo] = f2bf(v > 0.f ? v : 0.f);
    }
  }
}

// ---------------- merged attention: blocks [0,6144) temporal MFMA, [6144,9984) spatial ----------------
__global__ __launch_bounds__(256)
void attn_both(const u16* __restrict__ qt, const u16* __restrict__ kt,
               const u16* __restrict__ vt, u16* __restrict__ ta,
               const u16* __restrict__ qsp, const u16* __restrict__ ksp,
               const u16* __restrict__ vsp, u16* __restrict__ sa)
{
  __shared__ __align__(16) char smem[39168];
  int tid = threadIdx.x, lane = tid & 63, wid = tid >> 6;
  int quad = lane >> 4, r16 = lane & 15;

  if (blockIdx.x < 6144){
    // ---- temporal: one block per (b,h,j), T=120 pad 128, d=16 pad 32 ----
    u16* P  = (u16*)smem;             // 128*LDP
    u16* Vt = (u16*)(smem + 34816);   // 16*LDP
    int blk = blockIdx.x;
    int b = blk / 192;
    int rem = blk % 192;
    int h = rem / 24, j = rem % 24;
    const u16* qb = qt + (size_t)blk*1920;
    const u16* kb = kt + (size_t)blk*1920;
    const u16* vb = vt + (size_t)blk*1920;

    // vectorized V staging: 240 threads x one bf16x8 (16B) global load, transpose into LDS
    if (tid < 240){
      int s = tid >> 1, hf = (tid & 1) * 8;
      bf16x8 vv = *(const bf16x8*)&vb[s*16 + hf];
      #pragma unroll
      for (int q=0;q<8;q++) Vt[(hf + q)*LDP + s] = __builtin_bit_cast(u16, (__bf16)vv[q]);
    }
    if (tid < 128){ int dd = tid >> 3, s = 120 + (tid & 7); Vt[dd*LDP + s] = 0; }
    __syncthreads();

    bf16x8 zv;
    #pragma unroll
    for (int i=0;i<8;i++) zv[i] = (__bf16)0.f;

    const int m0 = wid * 32;
    bf16x8 qf[2];
    #pragma unroll
    for (int mt=0; mt<2; mt++){
      int row = m0 + mt*16 + r16; if (row > 119) row = 119;
      qf[mt] = (quad < 2) ? *(const bf16x8*)&qb[row*16 + (quad&1)*8] : zv;
    }

    f4 S[2][8];
    #pragma unroll
    for (int nt=0; nt<8; nt++){
      int col = nt*16 + r16; int colc = col > 119 ? 119 : col;
      bf16x8 kf = (quad < 2) ? *(const bf16x8*)&kb[colc*16 + (quad&1)*8] : zv;
      #pragma unroll
      for (int mt=0; mt<2; mt++){
        f4 zz = {0.f, 0.f, 0.f, 0.f};
        S[mt][nt] = __builtin_amdgcn_mfma_f32_16x16x32_bf16(qf[mt], kf, zz, 0, 0, 0);
      }
    }

    #pragma unroll
    for (int mt=0; mt<2; mt++)
      #pragma unroll
      for (int nt=0; nt<8; nt++)
        #pragma unroll
        for (int reg=0; reg<4; reg++){
          int c = nt*16 + r16;
          int r = m0 + mt*16 + quad*4 + reg;
          float v = S[mt][nt][reg] * 0.25f;
          S[mt][nt][reg] = (c > r || c >= 120) ? -1e30f : v;
        }

    float Zr[2][4];
    #pragma unroll
    for (int mt=0; mt<2; mt++)
      #pragma unroll
      for (int reg=0; reg<4; reg++){
        float m = -1e30f;
        #pragma unroll
        for (int nt=0; nt<8; nt++) m = fmaxf(m, S[mt][nt][reg]);
        #pragma unroll
        for (int off=1; off<16; off<<=1) m = fmaxf(m, __shfl_xor(m, off, 16));
        float z = 0.f;
        #pragma unroll
        for (int nt=0; nt<8; nt++){
          float e = __expf(S[mt][nt][reg] - m);
          S[mt][nt][reg] = e;
          z += e;
        }
        #pragma unroll
        for (int off=1; off<16; off<<=1) z += __shfl_xor(z, off, 16);
        Zr[mt][reg] = z;
      }

    #pragma unroll
    for (int mt=0; mt<2; mt++)
      #pragma unroll
      for (int nt=0; nt<8; nt++)
        #pragma unroll
        for (int reg=0; reg<4; reg++)
          P[(m0 + mt*16 + quad*4 + reg)*LDP + nt*16 + r16] = f2bf(S[mt][nt][reg]);
    __syncthreads();

    f4 O[2];
    #pragma unroll
    for (int mt=0; mt<2; mt++){ O[mt][0]=0.f; O[mt][1]=0.f; O[mt][2]=0.f; O[mt][3]=0.f; }
    #pragma unroll
    for (int kt8=0; kt8<4; kt8++){
      bf16x8 vf = *(const bf16x8*)&Vt[r16*LDP + kt8*32 + quad*8];
      #pragma unroll
      for (int mt=0; mt<2; mt++){
        bf16x8 pf = *(const bf16x8*)&P[(m0 + mt*16 + r16)*LDP + kt8*32 + quad*8];
        O[mt] = __builtin_amdgcn_mfma_f32_16x16x32_bf16(pf, vf, O[mt], 0, 0, 0);
      }
    }

    #pragma unroll
    for (int mt=0; mt<2; mt++)
      #pragma unroll
      for (int reg=0; reg<4; reg++){
        int r = m0 + mt*16 + quad*4 + reg;
        if (r < 120){
          size_t idx = (size_t)(b*120 + r)*3072 + h*384 + j*16 + r16;
          ta[idx] = f2bf(O[mt][reg] / Zr[mt][reg]);
        }
      }
  } else {
    // ---- spatial: one block per (b,t); threads 0..191 = (h,j); softmax over 24 joints ----
    float* Ks = (float*)smem;            // 3072
    float* Vs = (float*)(smem + 12288);  // 3072
    int bt = blockIdx.x - 6144;
    size_t base = (size_t)bt * 3072;
    for (int c = tid; c < 384; c += 256){
      bf16x8 kv = *(const bf16x8*)&ksp[base + c*8];
      bf16x8 vv = *(const bf16x8*)&vsp[base + c*8];
      #pragma unroll
      for (int i=0;i<8;i++){ Ks[c*8+i] = (float)kv[i]; Vs[c*8+i] = (float)vv[i]; }
    }
    __syncthreads();
    if (tid < 192){
      int h = tid / 24, j = tid % 24;
      float q[16];
      #pragma unroll
      for (int d2=0; d2<16; d2++) q[d2] = bf2f(qsp[base + h*384 + j*16 + d2]);
      float sc[24], mx = -1e30f;
      #pragma unroll
      for (int kk=0; kk<24; kk++){
        float dot = 0.f;
        #pragma unroll
        for (int d2=0; d2<16; d2++) dot += q[d2]*Ks[h*384 + kk*16 + d2];
        sc[kk] = dot * 0.25f;
        mx = fmaxf(mx, sc[kk]);
      }
      float Z = 0.f, acc[16];
      #pragma unroll
      for (int d2=0; d2<16; d2++) acc[d2] = 0.f;
      #pragma unroll
      for (int kk=0; kk<24; kk++){
        float w = __expf(sc[kk] - mx);
        Z += w;
        #pragma unroll
        for (int d2=0; d2<16; d2++) acc[d2] += w*Vs[h*384 + kk*16 + d2];
      }
      float inv = 1.f / Z;
      #pragma unroll
      for (int d2=0; d2<16; d2++) sa[base + h*384 + j*16 + d2] = f2bf(acc[d2]*inv);
    }
  }
}

// ---------------- batchnorm ----------------
// blocks 0..11: temporal coefs; 12..23: spatial coefs
__global__ void bn_coef2(const float* __restrict__ accT, const float* __restrict__ gT,
                         const float* __restrict__ bT, float* __restrict__ cT,
                         const float* __restrict__ accS, const float* __restrict__ gS,
                         const float* __restrict__ bS, float* __restrict__ cS){
  int isS = blockIdx.x >= 12;
  const float* acc = isS ? accS : accT;
  const float* g   = isS ? gS : gT;
  const float* b   = isS ? bS : bT;
  float* coef      = isS ? cS : cT;
  int c = (blockIdx.x % 12)*256 + threadIdx.x;
  float mean = acc[c] * (1.f/3840.f);
  float var  = acc[3072+c] * (1.f/3840.f) - mean*mean;
  float sc = g[c] * rsqrtf(var + 1e-5f);
  coef[c] = sc;
  coef[3072+c] = b[c] - mean*sc;
}

__global__ void bn_coef(const float* __restrict__ acc, const float* __restrict__ g,
                        const float* __restrict__ b, float* __restrict__ coef){
  int c = blockIdx.x*256 + threadIdx.x;
  float mean = acc[c] * (1.f/3840.f);
  float var  = acc[3072+c] * (1.f/3840.f) - mean*mean;
  float sc = g[c] * rsqrtf(var + 1e-5f);
  coef[c] = sc;
  coef[3072+c] = b[c] - mean*sc;
}

// att = BN_t(Yt) + BN_s(Ys), vectorized x4  (channel = (i*4) mod 3072 — NOT a pow2 mask!)
__global__ void bn_apply2(const u16* __restrict__ Ytb, const u16* __restrict__ Ysb,
                          const float* __restrict__ ct, const float* __restrict__ cs,
                          u16* __restrict__ attB){
  int i = blockIdx.x*256 + threadIdx.x;     // < NX/4
  int c = (i*4) % 3072;
  u16x4 yt = *(const u16x4*)&Ytb[i*4];
  u16x4 ys = *(const u16x4*)&Ysb[i*4];
  u16x4 o;
  #pragma unroll
  for (int k=0;k<4;k++){
    float a = bf2f(yt[k])*ct[c+k] + ct[3072+c+k] + bf2f(ys[k])*cs[c+k] + cs[3072+c+k];
    o[k] = f2bf(a);
  }
  *(u16x4*)&attB[i*4] = o;
}

__global__ void bn_out(const u16* __restrict__ Yfb, const float* __restrict__ cf,
                       float* __restrict__ out){
  int i = blockIdx.x*256 + threadIdx.x;     // < NX/4
  int c = (i*4) % 3072;
  u16x4 yf = *(const u16x4*)&Yfb[i*4];
  float4v o;
  #pragma unroll
  for (int k=0;k<4;k++) o[k] = bf2f(yf[k])*cf[c+k] + cf[3072+c+k];
  *(float4v*)&out[i*4] = o;
}

// ---------------- launch ----------------
extern "C" void kernel_launch(void* const* d_in, const int* in_sizes, int n_in,
                              void* d_out, int out_size, void* d_ws, size_t ws_size,
                              hipStream_t stream)
{
  const float* src  = (const float*)d_in[0];
  const float* Wq_t = (const float*)d_in[1];
  const float* Wk_t = (const float*)d_in[2];
  const float* Wv_t = (const float*)d_in[3];
  const float* Wp_t = (const float*)d_in[4];
  const float* bp_t = (const float*)d_in[5];
  const float* g_t  = (const float*)d_in[6];
  const float* b_t  = (const float*)d_in[7];
  const float* Wq_s = (const float*)d_in[8];
  const float* Wk_s = (const float*)d_in[9];
  const float* Wv_s = (const float*)d_in[10];
  const float* Wp_s = (const float*)d_in[11];
  const float* bp_s = (const float*)d_in[12];
  const float* g_s  = (const float*)d_in[13];
  const float* b_s  = (const float*)d_in[14];
  const float* W1   = (const float*)d_in[15];
  const float* b1   = (const float*)d_in[16];
  const float* W2   = (const float*)d_in[17];
  const float* b2   = (const float*)d_in[18];
  const float* g_f  = (const float*)d_in[19];
  const float* b_f  = (const float*)d_in[20];

  char* ws = (char*)d_ws;
  u16* x_bf  = (u16*)(ws + 0ull);
  u16* wptb  = (u16*)(ws + 23592960ull);
  u16* wpsb  = (u16*)(ws + 42467328ull);
  u16* w1b   = (u16*)(ws + 61341696ull);
  u16* w2b   = (u16*)(ws + 62914560ull);
  u16* wcat  = (u16*)(ws + 64487424ull);
  u16* qt    = (u16*)(ws + 69206016ull);
  u16* kt    = qt + NX;
  u16* vt    = kt + NX;
  u16* qs    = vt + NX;
  u16* ks    = qs + NX;
  u16* vs    = ks + NX;
  u16* tab   = (u16*)(ws + 210763776ull);
  u16* sab   = (u16*)(ws + 234356736ull);
  float* accT = (float*)(ws + 257949696ull);
  float* accS = accT + 6144;
  float* accF = accS + 6144;
  float* cT   = accF + 6144;
  float* cS   = cT + 6144;
  float* cF   = cS + 6144;
  // bf16 aliases over dead regions
  u16* Ytb  = qt;   // dead after attention
  u16* Ysb  = kt;
  u16* attB = vt;
  u16* Yfb  = qs;
  u16* h1   = wcat; // dead after gemm_qkv
  float* out = (float*)d_out;

  // 1. fused prep (zero accs + conversions + weight pack)
  k_prep<<<40776, 256, 0, stream>>>(src, x_bf, Wp_t, wptb, Wp_s, wpsb, W1, w1b, W2, w2b,
                                    Wq_t, Wk_t, Wv_t, Wq_s, Wk_s, Wv_s, wcat, accT);
  // 2. QKV projections (per joint; A staged once, 6 B-chunks)
  gemm_qkv<<<dim3(30,24), 256, 0, stream>>>(x_bf, wcat, qt, kt, vt, qs, ks, vs);
  // 3. both attentions in one launch
  attn_both<<<9984, 256, 0, stream>>>(qt, kt, vt, tab, qs, ks, vs, sab);
  // 4. output projections + residual + fused BN stats (256x384, 240 blocks, XCD-chunked)
  gemm_proj384<<<dim3(15,8,2), 512, 0, stream>>>(tab, wptb, bp_t, sab, wpsb, bp_s,
                                                 x_bf, Ytb, Ysb, accT, accS);
  // 5. BN coefs (t+s) + fused apply
  bn_coef2<<<24, 256, 0, stream>>>(accT, g_t, b_t, cT, accS, g_s, b_s, cS);
  bn_apply2<<<11520, 256, 0, stream>>>(Ytb, Ysb, cT, cS, attB);
  // 6. feed-forward (FF1: 240-block pipelined; FF2 unchanged)
  gemm_relu<<<dim3(120,2), 256, 0, stream>>>(attB, w1b, b1, h1);
  gemm_ff2<<<dim3(30,24), 256, 0, stream>>>(h1, w2b, b2, attB, Yfb, accF);
  // 7. final BN
  bn_coef<<<12, 256, 0, stream>>>(accF, g_f, b_f, cF);
  bn_out<<<11520, 256, 0, stream>>>(Yfb, cF, out);
}

// Round 6
// 554.858 us; speedup vs baseline: 1.1907x; 1.0068x over previous
//
#include <hip/hip_runtime.h>

typedef unsigned short u16;
typedef __bf16 bf16x8 __attribute__((ext_vector_type(8)));
typedef float f4 __attribute__((ext_vector_type(4)));
typedef float float4v __attribute__((ext_vector_type(4)));
typedef u16 u16x4 __attribute__((ext_vector_type(4)));

#define NX 11796480   // B*T*D = 3840*3072
#define LDP 136       // padded LDS row (u16 elems) for P / Vt in temporal attn

__device__ __forceinline__ float bf2f(u16 u){ __bf16 h = __builtin_bit_cast(__bf16, u); return (float)h; }
__device__ __forceinline__ u16 f2bf(float f){ __bf16 h = (__bf16)f; return __builtin_bit_cast(u16, h); }

__device__ __forceinline__ void gload_lds16(const u16* g, u16* l){
  __builtin_amdgcn_global_load_lds((const __attribute__((address_space(1))) void*)g,
                                   (__attribute__((address_space(3))) void*)l, 16, 0, 0);
}

// ---------------- fused prep: zero BN accs + all fp32->bf16 conversions + QKV weight pack ----------------
__device__ __forceinline__ void cvt4seg(const float* __restrict__ in, u16* __restrict__ out, int i){
  float4v v = *(const float4v*)&in[i*4];
  u16x4 o;
  o[0]=f2bf(v[0]); o[1]=f2bf(v[1]); o[2]=f2bf(v[2]); o[3]=f2bf(v[3]);
  *(u16x4*)&out[i*4] = o;
}

// total items = 18432 + 2949120 + 2359296 + 2359296 + 196608 + 196608 + 2359296 = 10438656 = 40776*256
__global__ void k_prep(const float* __restrict__ src, u16* __restrict__ x_bf,
                       const float* __restrict__ wpt, u16* __restrict__ wptb,
                       const float* __restrict__ wps, u16* __restrict__ wpsb,
                       const float* __restrict__ w1,  u16* __restrict__ w1b,
                       const float* __restrict__ w2,  u16* __restrict__ w2b,
                       const float* __restrict__ wqt, const float* __restrict__ wkt,
                       const float* __restrict__ wvt, const float* __restrict__ wqs,
                       const float* __restrict__ wks, const float* __restrict__ wvs,
                       u16* __restrict__ wcat, float* __restrict__ accs){
  int i = blockIdx.x*256 + threadIdx.x;
  if (i < 18432){ accs[i] = 0.f; return; }
  i -= 18432;
  if (i < 2949120){ cvt4seg(src, x_bf, i); return; }
  i -= 2949120;
  if (i < 2359296){ cvt4seg(wpt, wptb, i); return; }
  i -= 2359296;
  if (i < 2359296){ cvt4seg(wps, wpsb, i); return; }
  i -= 2359296;
  if (i < 196608){ cvt4seg(w1, w1b, i); return; }
  i -= 196608;
  if (i < 196608){ cvt4seg(w2, w2b, i); return; }
  i -= 196608;
  // pack Wq_t|Wk_t|Wv_t|Wq_s|Wk_s|Wv_s into (J=24, N=768, K=128) row-major bf16
  int e = i & 127;
  int n = (i >> 7) % 768;
  int j = i / (768*128);
  float v;
  if (n < 512){
    int tn = n >> 7, hh = (n >> 4) & 7, dd = n & 15;
    const float* W = (tn==0)? wqt : (tn==1)? wkt : (tn==2)? wvt : wqs;  // (H,J,d,E)
    v = W[(((hh*24 + j)*16 + dd) << 7) + e];
  } else {
    int m = n - 512;
    int tn = m >> 7, hh = (m >> 4) & 7, dd = m & 15;
    const float* W = (tn==0)? wks : wvs;                                // (H,d,E)
    v = W[((hh*16 + dd) << 7) + e];
  }
  wcat[i] = f2bf(v);
}

// ---------------- QKV GEMM: A staged once; 12 B-chunks of 64 cols, double-buffered ----------------
// 4 waves, wave w owns rows w*32..w*32+31 of the 128-row tile, all 64 chunk cols.
// LDS: As 32 KB + Bs dbuf 2x16 KB = 64 KB (2 blocks/CU).
// Ledger: prologue A(8)+B0(4)+B1(4) -> vmcnt(4) retires A+B0 (leaves B1).
// Per chunk nc: compute+store; barrier (readers done with buf); stage B(nc+2)->buf[nc&1];
// vmcnt(4) leaves only B(nc+2)'s 4 (waits stores + B(nc+1)); barrier publishes.
// nc=10: no stage -> vmcnt(0) drains B11. No full drain per chunk anymore.
__device__ __forceinline__ void stageQB(const u16* __restrict__ Bb, u16* __restrict__ dst,
                                        int tid, int srow16, int gcol){
  #pragma unroll
  for (int it=0; it<4; it++){
    int row = srow16 + it*16;
    gload_lds16(&Bb[(size_t)row*128 + gcol], dst + tid*8 + it*2048);
  }
}

__global__ __launch_bounds__(256)
void gemm_qkv(const u16* __restrict__ x, const u16* __restrict__ wcat,
              u16* __restrict__ qt, u16* __restrict__ kt, u16* __restrict__ vt,
              u16* __restrict__ qs, u16* __restrict__ ks, u16* __restrict__ vs)
{
  __shared__ __align__(16) u16 smem[32768];    // 64 KB
  u16* As  = smem;
  u16* Bs0 = smem + 16384;
  u16* Bs1 = smem + 24576;
  int m0 = blockIdx.x*128, j = blockIdx.y;
  const u16* Ab = x + (size_t)m0*3072 + j*128;
  const u16* Bbase = wcat + (size_t)j*98304;
  int tid = threadIdx.x, lane = tid & 63, wid = tid >> 6;
  int quad = lane >> 4, r16 = lane & 15;
  int srow16 = tid >> 4;                   // 0..15
  int cslot  = tid & 15;
  int gcol   = (cslot ^ srow16) * 8;       // swizzled source column

  #pragma unroll
  for (int it=0; it<8; it++){
    int row = srow16 + it*16;
    gload_lds16(&Ab[(size_t)row*3072 + gcol], As + tid*8 + it*2048);
  }
  stageQB(Bbase,            Bs0, tid, srow16, gcol);   // B chunk 0
  stageQB(Bbase + 64*128,   Bs1, tid, srow16, gcol);   // B chunk 1
  asm volatile("s_waitcnt vmcnt(4)" ::: "memory");     // A + B0 landed
  __builtin_amdgcn_s_barrier();

  for (int nc=0; nc<12; nc++){
    const u16* Bc = (nc & 1) ? Bs1 : Bs0;

    f4 acc[2][4];
    #pragma unroll
    for (int mt=0; mt<2; mt++)
      #pragma unroll
      for (int nt=0; nt<4; nt++)
        #pragma unroll
        for (int q=0; q<4; q++) acc[mt][nt][q] = 0.f;

    #pragma unroll
    for (int kk=0; kk<4; kk++){
      const int soff = ((kk*4 + quad) ^ r16) * 8;
      bf16x8 af[2], bfr[4];
      #pragma unroll
      for (int mt=0; mt<2; mt++)
        af[mt] = *(const bf16x8*)&As[(wid*32 + mt*16 + r16)*128 + soff];
      #pragma unroll
      for (int nt=0; nt<4; nt++)
        bfr[nt] = *(const bf16x8*)&Bc[(nt*16 + r16)*128 + soff];
      #pragma unroll
      for (int mt=0; mt<2; mt++)
        #pragma unroll
        for (int nt=0; nt<4; nt++)
          acc[mt][nt] = __builtin_amdgcn_mfma_f32_16x16x32_bf16(af[mt], bfr[nt], acc[mt][nt], 0, 0, 0);
    }

    #pragma unroll
    for (int mt=0; mt<2; mt++){
      #pragma unroll
      for (int reg=0; reg<4; reg++){
        int row = m0 + wid*32 + mt*16 + quad*4 + reg;   // bt index
        int b = row / 120, t = row % 120;
        #pragma unroll
        for (int nt=0; nt<4; nt++){
          int n = nc*64 + nt*16 + r16;
          u16 uv = f2bf(acc[mt][nt][reg]);
          if (n < 384){
            int tn = n >> 7, hh = (n >> 4) & 7, dd = n & 15;
            u16* base = (tn==0)? qt : (tn==1)? kt : vt;
            base[((((size_t)(b*8+hh)*24 + j)*120 + t) << 4) + dd] = uv;
          } else {
            int m2 = n - 384;
            int tn = m2 >> 7, hh = (m2 >> 4) & 7, dd = m2 & 15;
            u16* base = (tn==0)? qs : (tn==1)? ks : vs;
            base[((((size_t)row*8 + hh)*24 + j) << 4) + dd] = uv;
          }
        }
      }
    }

    if (nc < 11){
      __builtin_amdgcn_s_barrier();                    // all waves done reading buf[nc&1]
      if (nc + 2 < 12){
        stageQB(Bbase + (size_t)(nc+2)*64*128, (nc & 1) ? Bs1 : Bs0, tid, srow16, gcol);
        asm volatile("s_waitcnt vmcnt(4)" ::: "memory");   // B(nc+1) published
      } else {
        asm volatile("s_waitcnt vmcnt(0)" ::: "memory");   // drain B11
      }
      __builtin_amdgcn_s_barrier();
    }
  }
}

// ================= 256x384 dual-projection GEMM, BK=32, 3-slot rotating LDS =================
// (R3-verified structure: ~134-147 µs (session clock variance), MfmaUtil 42-47%.
//  R4's merged-cluster variant regressed — the p0/p1 split + setprio fences ARE the pipeline.
//  LDS-read pipe analysis: 112 wave-reads x 1KB / 128B/clk ~ 896 cyc/CU/tile vs MFMA 466 ->
//  structural ceiling ~52% MfmaUtil; we're near it. Do not touch without L2-operand rewrite.)
__device__ __forceinline__ void stageA384(const u16* __restrict__ g, int kcol,
                                          u16* __restrict__ slotA, int lane, int wid){
  #pragma unroll
  for (int i=0;i<2;i++){
    int row = wid*32 + i*16 + (lane>>2);
    int sw  = (((lane & 3) ^ ((lane>>3) & 3)) << 3);   // inverse of read swizzle
    gload_lds16(&g[(size_t)row*3072 + kcol + sw], slotA + (wid*2+i)*512);
  }
}
__device__ __forceinline__ void stageB384(const u16* __restrict__ g, int kcol,
                                          u16* __restrict__ slotB, int lane, int wid){
  #pragma unroll
  for (int i=0;i<3;i++){
    int row = wid*48 + i*16 + (lane>>2);
    int sw  = (((lane & 3) ^ ((lane>>3) & 3)) << 3);
    gload_lds16(&g[(size_t)row*3072 + kcol + sw], slotB + (wid*3+i)*512);
  }
}

__global__ __launch_bounds__(512, 2)
void gemm_proj384(const u16* __restrict__ A0, const u16* __restrict__ B0, const float* __restrict__ b0,
                  const u16* __restrict__ A1, const u16* __restrict__ B1, const float* __restrict__ b1v,
                  const u16* __restrict__ resb, u16* __restrict__ O0, u16* __restrict__ O1,
                  float* __restrict__ st0, float* __restrict__ st1)
{
  __shared__ __align__(16) u16 smem[61440];     // 120 KiB = 3 slots x 20480 u16
  const int tid = threadIdx.x, lane = tid & 63, wid = tid >> 6;
  const int quad = lane >> 4, r16 = lane & 15;
  const int wm = wid >> 2, wn = wid & 3;

  // bijective XCD chunk swizzle over 240 blocks
  int lin = blockIdx.x + 15*blockIdx.y + 120*blockIdx.z;
  int nidx = (lin & 7)*30 + (lin >> 3);
  int zz = nidx / 120; int rem = nidx - zz*120;
  int by = rem / 15, bx = rem - by*15;

  const int m0 = bx*256, n0 = by*384;
  const u16* Ag = (zz ? A1 : A0) + (size_t)m0*3072;
  const u16* Bg = (zz ? B1 : B0) + (size_t)n0*3072;
  const float* bias = zz ? b1v : b0;
  u16* out = zz ? O1 : O0;
  float* stp = zz ? st1 : st0;

  const int soff = ((quad ^ ((r16>>1)&3)) << 3);
  const int arow = wm*128 + r16;
  const int brow = wn*96 + r16;

  f4 acc[8][6];
  #pragma unroll
  for (int i=0;i<8;i++)
    #pragma unroll
    for (int n=0;n<6;n++)
      #pragma unroll
      for (int q=0;q<4;q++) acc[i][n][q] = 0.f;

  u16* Sa = smem;            // slot holding tile t
  u16* Sb = smem + 20480;    // tile t+1
  u16* Sc = smem + 40960;    // tile t+2 (stage target)

  // prologue: tiles 0 and 1 (10 issues/wave)
  stageA384(Ag, 0,  Sa,        lane, wid);
  stageB384(Bg, 0,  Sa + 8192, lane, wid);
  stageA384(Ag, 32, Sb,        lane, wid);
  stageB384(Bg, 32, Sb + 8192, lane, wid);
  asm volatile("s_waitcnt vmcnt(5)" ::: "memory");   // tile 0 landed
  __builtin_amdgcn_s_barrier();

  const int NT = 96;                                 // K = 3072, BK = 32
  bf16x8 af[4], bf[6];

  for (int t=0; t<NT; ++t){
    const int kc2 = ((t+2 < NT) ? (t+2) : 0) * 32;   // clamped tail lands in dead slot

    // ---- p0: m-group 0 + all B frags; stage A(t+2) ----
    #pragma unroll
    for (int i=0;i<4;i++) af[i] = *(const bf16x8*)&Sa[(arow + i*16)*32 + soff];
    #pragma unroll
    for (int n=0;n<6;n++) bf[n] = *(const bf16x8*)&Sa[8192 + (brow + n*16)*32 + soff];
    stageA384(Ag, kc2, Sc, lane, wid);
    __builtin_amdgcn_s_setprio(1);
    #pragma unroll
    for (int i=0;i<4;i++)
      #pragma unroll
      for (int n=0;n<6;n++)
        acc[i][n] = __builtin_amdgcn_mfma_f32_16x16x32_bf16(af[i], bf[n], acc[i][n], 0,0,0);
    __builtin_amdgcn_s_setprio(0);

    // ---- p1: m-group 1 (reuse bf); stage B(t+2) ----
    #pragma unroll
    for (int i=0;i<4;i++) af[i] = *(const bf16x8*)&Sa[(arow + 64 + i*16)*32 + soff];
    stageB384(Bg, kc2, Sc + 8192, lane, wid);
    __builtin_amdgcn_s_setprio(1);
    #pragma unroll
    for (int i=0;i<4;i++)
      #pragma unroll
      for (int n=0;n<6;n++)
        acc[4+i][n] = __builtin_amdgcn_mfma_f32_16x16x32_bf16(af[i], bf[n], acc[4+i][n], 0,0,0);
    __builtin_amdgcn_s_setprio(0);

    asm volatile("s_waitcnt vmcnt(5)" ::: "memory"); // tile t+1 published
    __builtin_amdgcn_s_barrier();
    u16* tp = Sa; Sa = Sb; Sb = Sc; Sc = tp;         // rotate slots
  }
  asm volatile("s_waitcnt vmcnt(0)" ::: "memory");   // drain clamped tail DMAs

  // ---------- epilogue: bias + residual + bf16 store + fused BN stats ----------
  float bv[6];
  #pragma unroll
  for (int n=0;n<6;n++) bv[n] = bias[n0 + wn*96 + n*16 + r16];
  float s[6] = {0,0,0,0,0,0}, s2[6] = {0,0,0,0,0,0};
  #pragma unroll
  for (int mf=0; mf<8; mf++){
    #pragma unroll
    for (int reg=0; reg<4; reg++){
      int grow = m0 + wm*128 + mf*16 + quad*4 + reg;
      #pragma unroll
      for (int n=0;n<6;n++){
        int gcol = n0 + wn*96 + n*16 + r16;
        size_t idx = (size_t)grow*3072 + gcol;
        float v = acc[mf][n][reg] + bv[n] + bf2f(resb[idx]);
        out[idx] = f2bf(v);
        s[n] += v; s2[n] += v*v;
      }
    }
  }
  #pragma unroll
  for (int n=0;n<6;n++){
    float a = s[n], b = s2[n];
    a += __shfl_xor(a, 16); a += __shfl_xor(a, 32);
    b += __shfl_xor(b, 16); b += __shfl_xor(b, 32);
    if (quad == 0){
      int col = n0 + wn*96 + n*16 + r16;
      atomicAdd(&stp[col], a);
      atomicAdd(&stp[3072 + col], b);
    }
  }
}

// ---------------- FF2 with fused BN stats: 128x128, K=256, double-buffered pipeline ----------------
// LDS: A dbuf 2x16 KB + B dbuf 2x16 KB = 64 KB (2 blocks/CU). Stores all in epilogue -> clean ledger.
// Ledger: prologue k0(8)+k1(8) -> vmcnt(8) retires k0. Per step t: compute buf[t&1]; barrier;
// stage k(t+2)->buf[t&1] (8 issues) then vmcnt(8) retires k(t+1); t=2 -> vmcnt(0) drains k3.
__device__ __forceinline__ void stageF(const u16* __restrict__ g, int k0,
                                       u16* __restrict__ dst, int wid, int srow, int gcol){
  #pragma unroll
  for (int i=0;i<4;i++){
    int row = srow + i*32;
    gload_lds16(&g[(size_t)row*256 + k0 + gcol], dst + wid*512 + i*2048);
  }
}

__global__ __launch_bounds__(256)
void gemm_ff2(const u16* __restrict__ A, const u16* __restrict__ B, const float* __restrict__ bias,
              const u16* __restrict__ resb, u16* __restrict__ out, float* __restrict__ stp)
{
  __shared__ __align__(16) u16 smem[32768];   // 64 KB
  u16* Asb0 = smem;          u16* Asb1 = smem + 8192;
  u16* Bsb0 = smem + 16384;  u16* Bsb1 = smem + 24576;
  int m0 = blockIdx.x*128, n0 = blockIdx.y*128;
  const u16* Ag = A + (size_t)m0*256;
  const u16* Bg = B + (size_t)n0*256;
  int tid = threadIdx.x, lane = tid & 63, wid = tid >> 6;
  int quad = lane>>4, r16 = lane&15;
  int srow = tid >> 3;                       // 0..31
  int gcol = ((tid & 7) ^ (srow & 7)) * 8;   // swizzled source column
  int waveM = (wid>>1)*64, waveN = (wid&1)*64;

  f4 acc[4][4];
  #pragma unroll
  for (int mt=0; mt<4; mt++)
    #pragma unroll
    for (int nt=0; nt<4; nt++)
      #pragma unroll
      for (int q=0; q<4; q++) acc[mt][nt][q] = 0.f;

  stageF(Ag, 0,  Asb0, wid, srow, gcol);
  stageF(Bg, 0,  Bsb0, wid, srow, gcol);
  stageF(Ag, 64, Asb1, wid, srow, gcol);
  stageF(Bg, 64, Bsb1, wid, srow, gcol);
  asm volatile("s_waitcnt vmcnt(8)" ::: "memory");    // k0 landed
  __builtin_amdgcn_s_barrier();

  for (int t=0; t<4; t++){
    const u16* As = (t & 1) ? Asb1 : Asb0;
    const u16* Bs = (t & 1) ? Bsb1 : Bsb0;
    #pragma unroll
    for (int kk=0; kk<2; kk++){
      bf16x8 af[4], bfr[4];
      const int soff = ((kk*4 + quad) ^ (r16 & 7)) * 8;
      #pragma unroll
      for (int mt=0; mt<4; mt++)
        af[mt] = *(const bf16x8*)&As[(waveM + mt*16 + r16)*64 + soff];
      #pragma unroll
      for (int nt=0; nt<4; nt++)
        bfr[nt] = *(const bf16x8*)&Bs[(waveN + nt*16 + r16)*64 + soff];
      #pragma unroll
      for (int mt=0; mt<4; mt++)
        #pragma unroll
        for (int nt=0; nt<4; nt++)
          acc[mt][nt] = __builtin_amdgcn_mfma_f32_16x16x32_bf16(af[mt], bfr[nt], acc[mt][nt], 0, 0, 0);
    }
    if (t < 3){
      __builtin_amdgcn_s_barrier();                   // readers done with buf[t&1]
      if (t + 2 < 4){
        stageF(Ag, (t+2)*64, (t & 1) ? Asb1 : Asb0, wid, srow, gcol);
        stageF(Bg, (t+2)*64, (t & 1) ? Bsb1 : Bsb0, wid, srow, gcol);
        asm volatile("s_waitcnt vmcnt(8)" ::: "memory");  // k(t+1) published
      } else {
        asm volatile("s_waitcnt vmcnt(0)" ::: "memory");  // drain k3
      }
      __builtin_amdgcn_s_barrier();
    }
  }

  float s[4] = {0,0,0,0}, s2[4] = {0,0,0,0};
  #pragma unroll
  for (int mt=0; mt<4; mt++){
    #pragma unroll
    for (int reg=0; reg<4; reg++){
      int grow = m0 + waveM + mt*16 + quad*4 + reg;
      #pragma unroll
      for (int nt=0; nt<4; nt++){
        int gcolo = n0 + waveN + nt*16 + r16;
        size_t idx = (size_t)grow*3072 + gcolo;
        float v = acc[mt][nt][reg] + bias[gcolo] + bf2f(resb[idx]);
        out[idx] = f2bf(v);
        s[nt] += v; s2[nt] += v*v;
      }
    }
  }
  #pragma unroll
  for (int nt=0; nt<4; nt++){
    float a = s[nt], b = s2[nt];
    a += __shfl_xor(a, 16); a += __shfl_xor(a, 32);
    b += __shfl_xor(b, 16); b += __shfl_xor(b, 32);
    if (quad == 0){
      int col = n0 + waveN + nt*16 + r16;
      atomicAdd(&stp[col], a);
      atomicAdd(&stp[3072 + col], b);
    }
  }
}

// ---------------- FF1: out bf16 = relu(A@W1^T + bias), 32x128 tiles, 3-slot pipeline ----------------
__device__ __forceinline__ void stageR_A(const u16* __restrict__ g, int kc, u16* __restrict__ slot,
                                         int tid, int srow, int gcol){
  gload_lds16(&g[(size_t)srow*3072 + kc + gcol], slot + tid*8);
}
__device__ __forceinline__ void stageR_B(const u16* __restrict__ g, int kc, u16* __restrict__ slot,
                                         int tid, int srow, int gcol){
  #pragma unroll
  for (int i=0;i<4;i++)
    gload_lds16(&g[(size_t)(srow + i*32)*3072 + kc + gcol], slot + 2048 + i*2048 + tid*8);
}

__global__ __launch_bounds__(256)
void gemm_relu(const u16* __restrict__ A, const u16* __restrict__ B,
               const float* __restrict__ bias, u16* __restrict__ out)
{
  __shared__ __align__(16) u16 smem[30720];   // 3 slots x (A 2048 + B 8192) u16 = 60 KB
  const int tid = threadIdx.x, lane = tid & 63, wid = tid >> 6;
  const int quad = lane >> 4, r16 = lane & 15;
  const int waveM = (wid >> 1) * 16, waveN = (wid & 1) * 64;
  const int m0 = blockIdx.x * 32, n0 = blockIdx.y * 128;
  const u16* Ag = A + (size_t)m0 * 3072;
  const u16* Bg = B + (size_t)n0 * 3072;

  const int srow = tid >> 3;                        // 0..31
  const int gcol = ((tid & 7) ^ (srow & 7)) * 8;    // swizzled source column

  f4 acc[4];
  #pragma unroll
  for (int n=0;n<4;n++)
    #pragma unroll
    for (int q=0;q<4;q++) acc[n][q] = 0.f;

  u16* Sa = smem;            // tile t
  u16* Sb = smem + 10240;    // tile t+1
  u16* Sc = smem + 20480;    // tile t+2 (stage target)

  stageR_A(Ag, 0,  Sa, tid, srow, gcol);
  stageR_B(Bg, 0,  Sa, tid, srow, gcol);
  stageR_A(Ag, 64, Sb, tid, srow, gcol);
  stageR_B(Bg, 64, Sb, tid, srow, gcol);
  asm volatile("s_waitcnt vmcnt(5)" ::: "memory");   // tile 0 landed
  __builtin_amdgcn_s_barrier();

  const int NT = 48;                                 // K = 3072, BK = 64
  const int s0 = (quad ^ (r16 & 7)) * 8;
  const int s1 = ((4 + quad) ^ (r16 & 7)) * 8;

  for (int t=0; t<NT; ++t){
    const int kc2 = ((t+2 < NT) ? (t+2) : 0) * 64;

    // p0: kk=0; stage A(t+2)
    bf16x8 a0 = *(const bf16x8*)&Sa[(waveM + r16)*64 + s0];
    bf16x8 b0[4];
    #pragma unroll
    for (int n=0;n<4;n++) b0[n] = *(const bf16x8*)&Sa[2048 + (waveN + n*16 + r16)*64 + s0];
    stageR_A(Ag, kc2, Sc, tid, srow, gcol);
    __builtin_amdgcn_s_setprio(1);
    #pragma unroll
    for (int n=0;n<4;n++)
      acc[n] = __builtin_amdgcn_mfma_f32_16x16x32_bf16(a0, b0[n], acc[n], 0,0,0);
    __builtin_amdgcn_s_setprio(0);

    // p1: kk=1; stage B(t+2)
    bf16x8 a1 = *(const bf16x8*)&Sa[(waveM + r16)*64 + s1];
    bf16x8 b1[4];
    #pragma unroll
    for (int n=0;n<4;n++) b1[n] = *(const bf16x8*)&Sa[2048 + (waveN + n*16 + r16)*64 + s1];
    stageR_B(Bg, kc2, Sc, tid, srow, gcol);
    __builtin_amdgcn_s_setprio(1);
    #pragma unroll
    for (int n=0;n<4;n++)
      acc[n] = __builtin_amdgcn_mfma_f32_16x16x32_bf16(a1, b1[n], acc[n], 0,0,0);
    __builtin_amdgcn_s_setprio(0);

    asm volatile("s_waitcnt vmcnt(5)" ::: "memory"); // tile t+1 published
    __builtin_amdgcn_s_barrier();
    u16* tp = Sa; Sa = Sb; Sb = Sc; Sc = tp;
  }
  asm volatile("s_waitcnt vmcnt(0)" ::: "memory");   // drain clamped tail DMAs

  #pragma unroll
  for (int n=0;n<4;n++){
    int gcolo = n0 + waveN + n*16 + r16;
    float bv = bias[gcolo];
    #pragma unroll
    for (int reg=0; reg<4; reg++){
      int grow = m0 + waveM + quad*4 + reg;
      float v = acc[n][reg] + bv;
      out[(size_t)grow*256 + gcolo] = f2bf(v > 0.f ? v : 0.f);
    }
  }
}

// ---------------- merged attention: blocks [0,6144) temporal MFMA, [6144,9984) spatial ----------------
__global__ __launch_bounds__(256)
void attn_both(const u16* __restrict__ qt, const u16* __restrict__ kt,
               const u16* __restrict__ vt, u16* __restrict__ ta,
               const u16* __restrict__ qsp, const u16* __restrict__ ksp,
               const u16* __restrict__ vsp, u16* __restrict__ sa)
{
  __shared__ __align__(16) char smem[39168];
  int tid = threadIdx.x, lane = tid & 63, wid = tid >> 6;
  int quad = lane >> 4, r16 = lane & 15;

  if (blockIdx.x < 6144){
    // ---- temporal: one block per (b,h,j), T=120 pad 128, d=16 pad 32 ----
    u16* P  = (u16*)smem;             // 128*LDP
    u16* Vt = (u16*)(smem + 34816);   // 16*LDP
    int blk = blockIdx.x;
    int b = blk / 192;
    int rem = blk % 192;
    int h = rem / 24, j = rem % 24;
    const u16* qb = qt + (size_t)blk*1920;
    const u16* kb = kt + (size_t)blk*1920;
    const u16* vb = vt + (size_t)blk*1920;

    // vectorized V staging: 240 threads x one bf16x8 (16B) global load, transpose into LDS
    if (tid < 240){
      int s = tid >> 1, hf = (tid & 1) * 8;
      bf16x8 vv = *(const bf16x8*)&vb[s*16 + hf];
      #pragma unroll
      for (int q=0;q<8;q++) Vt[(hf + q)*LDP + s] = __builtin_bit_cast(u16, (__bf16)vv[q]);
    }
    if (tid < 128){ int dd = tid >> 3, s = 120 + (tid & 7); Vt[dd*LDP + s] = 0; }
    __syncthreads();

    bf16x8 zv;
    #pragma unroll
    for (int i=0;i<8;i++) zv[i] = (__bf16)0.f;

    const int m0 = wid * 32;
    bf16x8 qf[2];
    #pragma unroll
    for (int mt=0; mt<2; mt++){
      int row = m0 + mt*16 + r16; if (row > 119) row = 119;
      qf[mt] = (quad < 2) ? *(const bf16x8*)&qb[row*16 + (quad&1)*8] : zv;
    }

    f4 S[2][8];
    #pragma unroll
    for (int nt=0; nt<8; nt++){
      int col = nt*16 + r16; int colc = col > 119 ? 119 : col;
      bf16x8 kf = (quad < 2) ? *(const bf16x8*)&kb[colc*16 + (quad&1)*8] : zv;
      #pragma unroll
      for (int mt=0; mt<2; mt++){
        f4 zz = {0.f, 0.f, 0.f, 0.f};
        S[mt][nt] = __builtin_amdgcn_mfma_f32_16x16x32_bf16(qf[mt], kf, zz, 0, 0, 0);
      }
    }

    #pragma unroll
    for (int mt=0; mt<2; mt++)
      #pragma unroll
      for (int nt=0; nt<8; nt++)
        #pragma unroll
        for (int reg=0; reg<4; reg++){
          int c = nt*16 + r16;
          int r = m0 + mt*16 + quad*4 + reg;
          float v = S[mt][nt][reg] * 0.25f;
          S[mt][nt][reg] = (c > r || c >= 120) ? -1e30f : v;
        }

    float Zr[2][4];
    #pragma unroll
    for (int mt=0; mt<2; mt++)
      #pragma unroll
      for (int reg=0; reg<4; reg++){
        float m = -1e30f;
        #pragma unroll
        for (int nt=0; nt<8; nt++) m = fmaxf(m, S[mt][nt][reg]);
        #pragma unroll
        for (int off=1; off<16; off<<=1) m = fmaxf(m, __shfl_xor(m, off, 16));
        float z = 0.f;
        #pragma unroll
        for (int nt=0; nt<8; nt++){
          float e = __expf(S[mt][nt][reg] - m);
          S[mt][nt][reg] = e;
          z += e;
        }
        #pragma unroll
        for (int off=1; off<16; off<<=1) z += __shfl_xor(z, off, 16);
        Zr[mt][reg] = z;
      }

    #pragma unroll
    for (int mt=0; mt<2; mt++)
      #pragma unroll
      for (int nt=0; nt<8; nt++)
        #pragma unroll
        for (int reg=0; reg<4; reg++)
          P[(m0 + mt*16 + quad*4 + reg)*LDP + nt*16 + r16] = f2bf(S[mt][nt][reg]);
    // NO barrier here: PV reads only P rows m0..m0+31, written by THIS wave
    // (rows are wave-private); compiler inserts the intra-wave lgkmcnt wait.

    f4 O[2];
    #pragma unroll
    for (int mt=0; mt<2; mt++){ O[mt][0]=0.f; O[mt][1]=0.f; O[mt][2]=0.f; O[mt][3]=0.f; }
    #pragma unroll
    for (int kt8=0; kt8<4; kt8++){
      bf16x8 vf = *(const bf16x8*)&Vt[r16*LDP + kt8*32 + quad*8];
      #pragma unroll
      for (int mt=0; mt<2; mt++){
        bf16x8 pf = *(const bf16x8*)&P[(m0 + mt*16 + r16)*LDP + kt8*32 + quad*8];
        O[mt] = __builtin_amdgcn_mfma_f32_16x16x32_bf16(pf, vf, O[mt], 0, 0, 0);
      }
    }

    #pragma unroll
    for (int mt=0; mt<2; mt++)
      #pragma unroll
      for (int reg=0; reg<4; reg++){
        int r = m0 + mt*16 + quad*4 + reg;
        if (r < 120){
          size_t idx = (size_t)(b*120 + r)*3072 + h*384 + j*16 + r16;
          ta[idx] = f2bf(O[mt][reg] / Zr[mt][reg]);
        }
      }
  } else {
    // ---- spatial: one block per (b,t); threads 0..191 = (h,j); softmax over 24 joints ----
    float* Ks = (float*)smem;            // 3072
    float* Vs = (float*)(smem + 12288);  // 3072
    int bt = blockIdx.x - 6144;
    size_t base = (size_t)bt * 3072;
    for (int c = tid; c < 384; c += 256){
      bf16x8 kv = *(const bf16x8*)&ksp[base + c*8];
      bf16x8 vv = *(const bf16x8*)&vsp[base + c*8];
      #pragma unroll
      for (int i=0;i<8;i++){ Ks[c*8+i] = (float)kv[i]; Vs[c*8+i] = (float)vv[i]; }
    }
    __syncthreads();
    if (tid < 192){
      int h = tid / 24, j = tid % 24;
      float q[16];
      #pragma unroll
      for (int d2=0; d2<16; d2++) q[d2] = bf2f(qsp[base + h*384 + j*16 + d2]);
      float sc[24], mx = -1e30f;
      #pragma unroll
      for (int kk=0; kk<24; kk++){
        float dot = 0.f;
        #pragma unroll
        for (int d2=0; d2<16; d2++) dot += q[d2]*Ks[h*384 + kk*16 + d2];
        sc[kk] = dot * 0.25f;
        mx = fmaxf(mx, sc[kk]);
      }
      float Z = 0.f, acc[16];
      #pragma unroll
      for (int d2=0; d2<16; d2++) acc[d2] = 0.f;
      #pragma unroll
      for (int kk=0; kk<24; kk++){
        float w = __expf(sc[kk] - mx);
        Z += w;
        #pragma unroll
        for (int d2=0; d2<16; d2++) acc[d2] += w*Vs[h*384 + kk*16 + d2];
      }
      float inv = 1.f / Z;
      #pragma unroll
      for (int d2=0; d2<16; d2++) sa[base + h*384 + j*16 + d2] = f2bf(acc[d2]*inv);
    }
  }
}

// ---------------- batchnorm ----------------
// blocks 0..11: temporal coefs; 12..23: spatial coefs
__global__ void bn_coef2(const float* __restrict__ accT, const float* __restrict__ gT,
                         const float* __restrict__ bT, float* __restrict__ cT,
                         const float* __restrict__ accS, const float* __restrict__ gS,
                         const float* __restrict__ bS, float* __restrict__ cS){
  int isS = blockIdx.x >= 12;
  const float* acc = isS ? accS : accT;
  const float* g   = isS ? gS : gT;
  const float* b   = isS ? bS : bT;
  float* coef      = isS ? cS : cT;
  int c = (blockIdx.x % 12)*256 + threadIdx.x;
  float mean = acc[c] * (1.f/3840.f);
  float var  = acc[3072+c] * (1.f/3840.f) - mean*mean;
  float sc = g[c] * rsqrtf(var + 1e-5f);
  coef[c] = sc;
  coef[3072+c] = b[c] - mean*sc;
}

__global__ void bn_coef(const float* __restrict__ acc, const float* __restrict__ g,
                        const float* __restrict__ b, float* __restrict__ coef){
  int c = blockIdx.x*256 + threadIdx.x;
  float mean = acc[c] * (1.f/3840.f);
  float var  = acc[3072+c] * (1.f/3840.f) - mean*mean;
  float sc = g[c] * rsqrtf(var + 1e-5f);
  coef[c] = sc;
  coef[3072+c] = b[c] - mean*sc;
}

// att = BN_t(Yt) + BN_s(Ys), vectorized x4  (channel = (i*4) mod 3072 — NOT a pow2 mask!)
__global__ void bn_apply2(const u16* __restrict__ Ytb, const u16* __restrict__ Ysb,
                          const float* __restrict__ ct, const float* __restrict__ cs,
                          u16* __restrict__ attB){
  int i = blockIdx.x*256 + threadIdx.x;     // < NX/4
  int c = (i*4) % 3072;
  u16x4 yt = *(const u16x4*)&Ytb[i*4];
  u16x4 ys = *(const u16x4*)&Ysb[i*4];
  u16x4 o;
  #pragma unroll
  for (int k=0;k<4;k++){
    float a = bf2f(yt[k])*ct[c+k] + ct[3072+c+k] + bf2f(ys[k])*cs[c+k] + cs[3072+c+k];
    o[k] = f2bf(a);
  }
  *(u16x4*)&attB[i*4] = o;
}

__global__ void bn_out(const u16* __restrict__ Yfb, const float* __restrict__ cf,
                       float* __restrict__ out){
  int i = blockIdx.x*256 + threadIdx.x;     // < NX/4
  int c = (i*4) % 3072;
  u16x4 yf = *(const u16x4*)&Yfb[i*4];
  float4v o;
  #pragma unroll
  for (int k=0;k<4;k++) o[k] = bf2f(yf[k])*cf[c+k] + cf[3072+c+k];
  *(float4v*)&out[i*4] = o;
}

// ---------------- launch ----------------
extern "C" void kernel_launch(void* const* d_in, const int* in_sizes, int n_in,
                              void* d_out, int out_size, void* d_ws, size_t ws_size,
                              hipStream_t stream)
{
  const float* src  = (const float*)d_in[0];
  const float* Wq_t = (const float*)d_in[1];
  const float* Wk_t = (const float*)d_in[2];
  const float* Wv_t = (const float*)d_in[3];
  const float* Wp_t = (const float*)d_in[4];
  const float* bp_t = (const float*)d_in[5];
  const float* g_t  = (const float*)d_in[6];
  const float* b_t  = (const float*)d_in[7];
  const float* Wq_s = (const float*)d_in[8];
  const float* Wk_s = (const float*)d_in[9];
  const float* Wv_s = (const float*)d_in[10];
  const float* Wp_s = (const float*)d_in[11];
  const float* bp_s = (const float*)d_in[12];
  const float* g_s  = (const float*)d_in[13];
  const float* b_s  = (const float*)d_in[14];
  const float* W1   = (const float*)d_in[15];
  const float* b1   = (const float*)d_in[16];
  const float* W2   = (const float*)d_in[17];
  const float* b2   = (const float*)d_in[18];
  const float* g_f  = (const float*)d_in[19];
  const float* b_f  = (const float*)d_in[20];

  char* ws = (char*)d_ws;
  u16* x_bf  = (u16*)(ws + 0ull);
  u16* wptb  = (u16*)(ws + 23592960ull);
  u16* wpsb  = (u16*)(ws + 42467328ull);
  u16* w1b   = (u16*)(ws + 61341696ull);
  u16* w2b   = (u16*)(ws + 62914560ull);
  u16* wcat  = (u16*)(ws + 64487424ull);
  u16* qt    = (u16*)(ws + 69206016ull);
  u16* kt    = qt + NX;
  u16* vt    = kt + NX;
  u16* qs    = vt + NX;
  u16* ks    = qs + NX;
  u16* vs    = ks + NX;
  u16* tab   = (u16*)(ws + 210763776ull);
  u16* sab   = (u16*)(ws + 234356736ull);
  float* accT = (float*)(ws + 257949696ull);
  float* accS = accT + 6144;
  float* accF = accS + 6144;
  float* cT   = accF + 6144;
  float* cS   = cT + 6144;
  float* cF   = cS + 6144;
  // bf16 aliases over dead regions
  u16* Ytb  = qt;   // dead after attention
  u16* Ysb  = kt;
  u16* attB = vt;
  u16* Yfb  = qs;
  u16* h1   = wcat; // dead after gemm_qkv
  float* out = (float*)d_out;

  // 1. fused prep (zero accs + conversions + weight pack)
  k_prep<<<40776, 256, 0, stream>>>(src, x_bf, Wp_t, wptb, Wp_s, wpsb, W1, w1b, W2, w2b,
                                    Wq_t, Wk_t, Wv_t, Wq_s, Wk_s, Wv_s, wcat, accT);
  // 2. QKV projections (per joint; A staged once, 12 double-buffered B-chunks)
  gemm_qkv<<<dim3(30,24), 256, 0, stream>>>(x_bf, wcat, qt, kt, vt, qs, ks, vs);
  // 3. both attentions in one launch
  attn_both<<<9984, 256, 0, stream>>>(qt, kt, vt, tab, qs, ks, vs, sab);
  // 4. output projections + residual + fused BN stats (256x384, 240 blocks, XCD-chunked)
  gemm_proj384<<<dim3(15,8,2), 512, 0, stream>>>(tab, wptb, bp_t, sab, wpsb, bp_s,
                                                 x_bf, Ytb, Ysb, accT, accS);
  // 5. BN coefs (t+s) + fused apply
  bn_coef2<<<24, 256, 0, stream>>>(accT, g_t, b_t, cT, accS, g_s, b_s, cS);
  bn_apply2<<<11520, 256, 0, stream>>>(Ytb, Ysb, cT, cS, attB);
  // 6. feed-forward (FF1: 240-block pipelined; FF2: double-buffered)
  gemm_relu<<<dim3(120,2), 256, 0, stream>>>(attB, w1b, b1, h1);
  gemm_ff2<<<dim3(30,24), 256, 0, stream>>>(h1, w2b, b2, attB, Yfb, accF);
  // 7. final BN
  bn_coef<<<12, 256, 0, stream>>>(accF, g_f, b_f, cF);
  bn_out<<<11520, 256, 0, stream>>>(Yfb, cF, out);
}

// Round 8
// 519.650 us; speedup vs baseline: 1.2714x; 1.0678x over previous
//
#include <hip/hip_runtime.h>

typedef unsigned short u16;
typedef __bf16 bf16x8 __attribute__((ext_vector_type(8)));
typedef float f4 __attribute__((ext_vector_type(4)));
typedef float float4v __attribute__((ext_vector_type(4)));
typedef u16 u16x4 __attribute__((ext_vector_type(4)));

#define NX 11796480   // B*T*D = 3840*3072
#define LDP 136       // padded LDS row (u16 elems) for P / Vt in temporal attn

__device__ __forceinline__ float bf2f(u16 u){ __bf16 h = __builtin_bit_cast(__bf16, u); return (float)h; }
__device__ __forceinline__ u16 f2bf(float f){ __bf16 h = (__bf16)f; return __builtin_bit_cast(u16, h); }

__device__ __forceinline__ void gload_lds16(const u16* g, u16* l){
  __builtin_amdgcn_global_load_lds((const __attribute__((address_space(1))) void*)g,
                                   (__attribute__((address_space(3))) void*)l, 16, 0, 0);
}

// ---------------- fused prep: zero BN accs + all fp32->bf16 conversions + QKV weight pack ----------------
__device__ __forceinline__ void cvt4seg(const float* __restrict__ in, u16* __restrict__ out, int i){
  float4v v = *(const float4v*)&in[i*4];
  u16x4 o;
  o[0]=f2bf(v[0]); o[1]=f2bf(v[1]); o[2]=f2bf(v[2]); o[3]=f2bf(v[3]);
  *(u16x4*)&out[i*4] = o;
}

// total items = 18432 + 2949120 + 2359296 + 2359296 + 196608 + 196608 + 2359296 = 10438656 = 40776*256
__global__ void k_prep(const float* __restrict__ src, u16* __restrict__ x_bf,
                       const float* __restrict__ wpt, u16* __restrict__ wptb,
                       const float* __restrict__ wps, u16* __restrict__ wpsb,
                       const float* __restrict__ w1,  u16* __restrict__ w1b,
                       const float* __restrict__ w2,  u16* __restrict__ w2b,
                       const float* __restrict__ wqt, const float* __restrict__ wkt,
                       const float* __restrict__ wvt, const float* __restrict__ wqs,
                       const float* __restrict__ wks, const float* __restrict__ wvs,
                       u16* __restrict__ wcat, float* __restrict__ accs){
  int i = blockIdx.x*256 + threadIdx.x;
  if (i < 18432){ accs[i] = 0.f; return; }
  i -= 18432;
  if (i < 2949120){ cvt4seg(src, x_bf, i); return; }
  i -= 2949120;
  if (i < 2359296){ cvt4seg(wpt, wptb, i); return; }
  i -= 2359296;
  if (i < 2359296){ cvt4seg(wps, wpsb, i); return; }
  i -= 2359296;
  if (i < 196608){ cvt4seg(w1, w1b, i); return; }
  i -= 196608;
  if (i < 196608){ cvt4seg(w2, w2b, i); return; }
  i -= 196608;
  // pack Wq_t|Wk_t|Wv_t|Wq_s|Wk_s|Wv_s into (J=24, N=768, K=128) row-major bf16
  int e = i & 127;
  int n = (i >> 7) % 768;
  int j = i / (768*128);
  float v;
  if (n < 512){
    int tn = n >> 7, hh = (n >> 4) & 7, dd = n & 15;
    const float* W = (tn==0)? wqt : (tn==1)? wkt : (tn==2)? wvt : wqs;  // (H,J,d,E)
    v = W[(((hh*24 + j)*16 + dd) << 7) + e];
  } else {
    int m = n - 512;
    int tn = m >> 7, hh = (m >> 4) & 7, dd = m & 15;
    const float* W = (tn==0)? wks : wvs;                                // (H,d,E)
    v = W[((hh*16 + dd) << 7) + e];
  }
  wcat[i] = f2bf(v);
}

// ---------------- QKV GEMM: A staged once; 12 B-chunks of 64 cols, double-buffered ----------------
// R8 FIX: raw s_barrier does NOT drain lgkmcnt — the Ct ds_writes needed an explicit
// s_waitcnt lgkmcnt(0) BEFORE the mid barrier (cross-wave ds_write -> ds_read hand-off).
// R7's race: wave A's Ct writes still in flight while wave B (past barrier) read stale data.
// The vmcnt pipeline is untouched: lgkmcnt(0) does not drain the store/B-stage vmcnt queue.
//
// Epilogue: C-chunk (128x64) staged into Ct, stored with threads mapped to OUTPUT layout:
// 8 x u16x4 (8B) stores/thread, 512B-contiguous (temporal) / 128B-contiguous (spatial (bt,j,h,d)).
// Ledger (per-wave FIFO): steady state at the wait point the queue is
// [stores(nc-1)(8), B(nc+1)(4), stores(nc)(8), B(nc+2)(4)] -> vmcnt(12) retires through
// B(nc+1), leaves stores(nc)+B(nc+2). nc=10: vmcnt(8) retires B11, leaves stores(10).
__device__ __forceinline__ void stageQB(const u16* __restrict__ Bb, u16* __restrict__ dst,
                                        int tid, int srow16, int gcol){
  #pragma unroll
  for (int it=0; it<4; it++){
    int row = srow16 + it*16;
    gload_lds16(&Bb[(size_t)row*128 + gcol], dst + tid*8 + it*2048);
  }
}

__global__ __launch_bounds__(256)
void gemm_qkv(const u16* __restrict__ x, const u16* __restrict__ wcat,
              u16* __restrict__ qt, u16* __restrict__ kt, u16* __restrict__ vt,
              u16* __restrict__ qs, u16* __restrict__ ks, u16* __restrict__ vs)
{
  __shared__ __align__(16) u16 smem[40960];    // 80 KB (2 blocks/CU)
  u16* As  = smem;            // 32 KB: A tile 128x128
  u16* Bs0 = smem + 16384;    // 16 KB
  u16* Bs1 = smem + 24576;    // 16 KB
  u16* Ct  = smem + 32768;    // 16 KB: C chunk 128x64
  int m0 = blockIdx.x*128, j = blockIdx.y;
  const u16* Ab = x + (size_t)m0*3072 + j*128;
  const u16* Bbase = wcat + (size_t)j*98304;
  int tid = threadIdx.x, lane = tid & 63, wid = tid >> 6;
  int quad = lane >> 4, r16 = lane & 15;
  int srow16 = tid >> 4;                   // 0..15
  int gcol   = ((tid & 15) ^ srow16) * 8;  // swizzled source column

  #pragma unroll
  for (int it=0; it<8; it++){
    int row = srow16 + it*16;
    gload_lds16(&Ab[(size_t)row*3072 + gcol], As + tid*8 + it*2048);
  }
  stageQB(Bbase,            Bs0, tid, srow16, gcol);   // B chunk 0
  stageQB(Bbase + 64*128,   Bs1, tid, srow16, gcol);   // B chunk 1
  asm volatile("s_waitcnt vmcnt(4)" ::: "memory");     // A + B0 landed
  __builtin_amdgcn_s_barrier();

  // epilogue store mapping (constant per thread)
  const int c0 = (tid & 15) * 4;      // col base 0..60
  const int hl = c0 >> 4;             // hh_local 0..3
  const int d0 = c0 & 15;             // 0,4,8,12

  for (int nc=0; nc<12; nc++){
    const u16* Bc = (nc & 1) ? Bs1 : Bs0;

    f4 acc[2][4];
    #pragma unroll
    for (int mt=0; mt<2; mt++)
      #pragma unroll
      for (int nt=0; nt<4; nt++)
        #pragma unroll
        for (int q=0; q<4; q++) acc[mt][nt][q] = 0.f;

    #pragma unroll
    for (int kk=0; kk<4; kk++){
      const int soff = ((kk*4 + quad) ^ r16) * 8;
      bf16x8 af[2], bfr[4];
      #pragma unroll
      for (int mt=0; mt<2; mt++)
        af[mt] = *(const bf16x8*)&As[(wid*32 + mt*16 + r16)*128 + soff];
      #pragma unroll
      for (int nt=0; nt<4; nt++)
        bfr[nt] = *(const bf16x8*)&Bc[(nt*16 + r16)*128 + soff];
      #pragma unroll
      for (int mt=0; mt<2; mt++)
        #pragma unroll
        for (int nt=0; nt<4; nt++)
          acc[mt][nt] = __builtin_amdgcn_mfma_f32_16x16x32_bf16(af[mt], bfr[nt], acc[mt][nt], 0, 0, 0);
    }

    // ---- C chunk -> LDS ----
    #pragma unroll
    for (int mt=0; mt<2; mt++)
      #pragma unroll
      for (int reg=0; reg<4; reg++){
        int row = wid*32 + mt*16 + quad*4 + reg;
        #pragma unroll
        for (int nt=0; nt<4; nt++)
          Ct[row*64 + nt*16 + r16] = f2bf(acc[mt][nt][reg]);
      }
    asm volatile("s_waitcnt lgkmcnt(0)" ::: "memory");  // R8 FIX: drain Ct ds_writes
    __builtin_amdgcn_s_barrier();          // Ct published; all waves done reading Bs[nc&1]

    // ---- coalesced u16x4 stores from Ct ----
    if (nc < 6){
      int tn = nc >> 1;
      u16* base = (tn==0)? qt : (tn==1)? kt : vt;
      int hh = (nc & 1)*4 + hl;
      #pragma unroll
      for (int g=0; g<8; g++){
        int row = g*16 + (tid >> 4);
        int gr = m0 + row;
        int b = gr / 120, t = gr - b*120;
        u16x4 v = *(const u16x4*)&Ct[row*64 + c0];
        *(u16x4*)&base[((((size_t)(b*8+hh)*24 + j)*120 + t) << 4) + d0] = v;
      }
    } else {
      int tn = (nc - 6) >> 1;
      u16* base = (tn==0)? qs : (tn==1)? ks : vs;
      int hh = ((nc - 6) & 1)*4 + hl;
      #pragma unroll
      for (int g=0; g<8; g++){
        int row = g*16 + (tid >> 4);
        size_t gr = (size_t)(m0 + row);
        u16x4 v = *(const u16x4*)&Ct[row*64 + c0];
        *(u16x4*)&base[gr*3072 + j*128 + hh*16 + d0] = v;   // (bt, j, h, d) layout
      }
    }

    if (nc < 11){
      if (nc + 2 < 12){
        stageQB(Bbase + (size_t)(nc+2)*64*128, (nc & 1) ? Bs1 : Bs0, tid, srow16, gcol);
        asm volatile("s_waitcnt vmcnt(12)" ::: "memory");  // B(nc+1) retired; stores+B(nc+2) fly
      } else {
        asm volatile("s_waitcnt vmcnt(8)" ::: "memory");   // B11 retired; stores(10) fly
      }
      __builtin_amdgcn_s_barrier();
    }
  }
}

// ================= 256x384 dual-projection GEMM, BK=32, 3-slot rotating LDS =================
// (R3-verified structure: ~134-147 µs (session clock variance), MfmaUtil 42-47%.
//  R4's merged-cluster variant regressed — the p0/p1 split + setprio fences ARE the pipeline.
//  LDS-read pipe analysis: ~896 cyc/CU/tile LDS vs 466 MFMA -> structural ceiling ~52% MfmaUtil;
//  we're near it. Do not touch without an L2-operand rewrite.)
__device__ __forceinline__ void stageA384(const u16* __restrict__ g, int kcol,
                                          u16* __restrict__ slotA, int lane, int wid){
  #pragma unroll
  for (int i=0;i<2;i++){
    int row = wid*32 + i*16 + (lane>>2);
    int sw  = (((lane & 3) ^ ((lane>>3) & 3)) << 3);   // inverse of read swizzle
    gload_lds16(&g[(size_t)row*3072 + kcol + sw], slotA + (wid*2+i)*512);
  }
}
__device__ __forceinline__ void stageB384(const u16* __restrict__ g, int kcol,
                                          u16* __restrict__ slotB, int lane, int wid){
  #pragma unroll
  for (int i=0;i<3;i++){
    int row = wid*48 + i*16 + (lane>>2);
    int sw  = (((lane & 3) ^ ((lane>>3) & 3)) << 3);
    gload_lds16(&g[(size_t)row*3072 + kcol + sw], slotB + (wid*3+i)*512);
  }
}

__global__ __launch_bounds__(512, 2)
void gemm_proj384(const u16* __restrict__ A0, const u16* __restrict__ B0, const float* __restrict__ b0,
                  const u16* __restrict__ A1, const u16* __restrict__ B1, const float* __restrict__ b1v,
                  const u16* __restrict__ resb, u16* __restrict__ O0, u16* __restrict__ O1,
                  float* __restrict__ st0, float* __restrict__ st1)
{
  __shared__ __align__(16) u16 smem[61440];     // 120 KiB = 3 slots x 20480 u16
  const int tid = threadIdx.x, lane = tid & 63, wid = tid >> 6;
  const int quad = lane >> 4, r16 = lane & 15;
  const int wm = wid >> 2, wn = wid & 3;

  // bijective XCD chunk swizzle over 240 blocks
  int lin = blockIdx.x + 15*blockIdx.y + 120*blockIdx.z;
  int nidx = (lin & 7)*30 + (lin >> 3);
  int zz = nidx / 120; int rem = nidx - zz*120;
  int by = rem / 15, bx = rem - by*15;

  const int m0 = bx*256, n0 = by*384;
  const u16* Ag = (zz ? A1 : A0) + (size_t)m0*3072;
  const u16* Bg = (zz ? B1 : B0) + (size_t)n0*3072;
  const float* bias = zz ? b1v : b0;
  u16* out = zz ? O1 : O0;
  float* stp = zz ? st1 : st0;

  const int soff = ((quad ^ ((r16>>1)&3)) << 3);
  const int arow = wm*128 + r16;
  const int brow = wn*96 + r16;

  f4 acc[8][6];
  #pragma unroll
  for (int i=0;i<8;i++)
    #pragma unroll
    for (int n=0;n<6;n++)
      #pragma unroll
      for (int q=0;q<4;q++) acc[i][n][q] = 0.f;

  u16* Sa = smem;            // slot holding tile t
  u16* Sb = smem + 20480;    // tile t+1
  u16* Sc = smem + 40960;    // tile t+2 (stage target)

  // prologue: tiles 0 and 1 (10 issues/wave)
  stageA384(Ag, 0,  Sa,        lane, wid);
  stageB384(Bg, 0,  Sa + 8192, lane, wid);
  stageA384(Ag, 32, Sb,        lane, wid);
  stageB384(Bg, 32, Sb + 8192, lane, wid);
  asm volatile("s_waitcnt vmcnt(5)" ::: "memory");   // tile 0 landed
  __builtin_amdgcn_s_barrier();

  const int NT = 96;                                 // K = 3072, BK = 32
  bf16x8 af[4], bf[6];

  for (int t=0; t<NT; ++t){
    const int kc2 = ((t+2 < NT) ? (t+2) : 0) * 32;   // clamped tail lands in dead slot

    // ---- p0: m-group 0 + all B frags; stage A(t+2) ----
    #pragma unroll
    for (int i=0;i<4;i++) af[i] = *(const bf16x8*)&Sa[(arow + i*16)*32 + soff];
    #pragma unroll
    for (int n=0;n<6;n++) bf[n] = *(const bf16x8*)&Sa[8192 + (brow + n*16)*32 + soff];
    stageA384(Ag, kc2, Sc, lane, wid);
    __builtin_amdgcn_s_setprio(1);
    #pragma unroll
    for (int i=0;i<4;i++)
      #pragma unroll
      for (int n=0;n<6;n++)
        acc[i][n] = __builtin_amdgcn_mfma_f32_16x16x32_bf16(af[i], bf[n], acc[i][n], 0,0,0);
    __builtin_amdgcn_s_setprio(0);

    // ---- p1: m-group 1 (reuse bf); stage B(t+2) ----
    #pragma unroll
    for (int i=0;i<4;i++) af[i] = *(const bf16x8*)&Sa[(arow + 64 + i*16)*32 + soff];
    stageB384(Bg, kc2, Sc + 8192, lane, wid);
    __builtin_amdgcn_s_setprio(1);
    #pragma unroll
    for (int i=0;i<4;i++)
      #pragma unroll
      for (int n=0;n<6;n++)
        acc[4+i][n] = __builtin_amdgcn_mfma_f32_16x16x32_bf16(af[i], bf[n], acc[4+i][n], 0,0,0);
    __builtin_amdgcn_s_setprio(0);

    asm volatile("s_waitcnt vmcnt(5)" ::: "memory"); // tile t+1 published
    __builtin_amdgcn_s_barrier();
    u16* tp = Sa; Sa = Sb; Sb = Sc; Sc = tp;         // rotate slots
  }
  asm volatile("s_waitcnt vmcnt(0)" ::: "memory");   // drain clamped tail DMAs

  // ---------- epilogue: bias + residual + bf16 store + fused BN stats ----------
  float bv[6];
  #pragma unroll
  for (int n=0;n<6;n++) bv[n] = bias[n0 + wn*96 + n*16 + r16];
  float s[6] = {0,0,0,0,0,0}, s2[6] = {0,0,0,0,0,0};
  #pragma unroll
  for (int mf=0; mf<8; mf++){
    #pragma unroll
    for (int reg=0; reg<4; reg++){
      int grow = m0 + wm*128 + mf*16 + quad*4 + reg;
      #pragma unroll
      for (int n=0;n<6;n++){
        int gcol = n0 + wn*96 + n*16 + r16;
        size_t idx = (size_t)grow*3072 + gcol;
        float v = acc[mf][n][reg] + bv[n] + bf2f(resb[idx]);
        out[idx] = f2bf(v);
        s[n] += v; s2[n] += v*v;
      }
    }
  }
  #pragma unroll
  for (int n=0;n<6;n++){
    float a = s[n], b = s2[n];
    a += __shfl_xor(a, 16); a += __shfl_xor(a, 32);
    b += __shfl_xor(b, 16); b += __shfl_xor(b, 32);
    if (quad == 0){
      int col = n0 + wn*96 + n*16 + r16;
      atomicAdd(&stp[col], a);
      atomicAdd(&stp[3072 + col], b);
    }
  }
}

// ---------------- FF2 with fused BN stats: 128x128, K=256, double-buffered pipeline ----------------
__device__ __forceinline__ void stageF(const u16* __restrict__ g, int k0,
                                       u16* __restrict__ dst, int wid, int srow, int gcol){
  #pragma unroll
  for (int i=0;i<4;i++){
    int row = srow + i*32;
    gload_lds16(&g[(size_t)row*256 + k0 + gcol], dst + wid*512 + i*2048);
  }
}

__global__ __launch_bounds__(256)
void gemm_ff2(const u16* __restrict__ A, const u16* __restrict__ B, const float* __restrict__ bias,
              const u16* __restrict__ resb, u16* __restrict__ out, float* __restrict__ stp)
{
  __shared__ __align__(16) u16 smem[32768];   // 64 KB
  u16* Asb0 = smem;          u16* Asb1 = smem + 8192;
  u16* Bsb0 = smem + 16384;  u16* Bsb1 = smem + 24576;
  int m0 = blockIdx.x*128, n0 = blockIdx.y*128;
  const u16* Ag = A + (size_t)m0*256;
  const u16* Bg = B + (size_t)n0*256;
  int tid = threadIdx.x, lane = tid & 63, wid = tid >> 6;
  int quad = lane>>4, r16 = lane&15;
  int srow = tid >> 3;                       // 0..31
  int gcol = ((tid & 7) ^ (srow & 7)) * 8;   // swizzled source column
  int waveM = (wid>>1)*64, waveN = (wid&1)*64;

  f4 acc[4][4];
  #pragma unroll
  for (int mt=0; mt<4; mt++)
    #pragma unroll
    for (int nt=0; nt<4; nt++)
      #pragma unroll
      for (int q=0; q<4; q++) acc[mt][nt][q] = 0.f;

  stageF(Ag, 0,  Asb0, wid, srow, gcol);
  stageF(Bg, 0,  Bsb0, wid, srow, gcol);
  stageF(Ag, 64, Asb1, wid, srow, gcol);
  stageF(Bg, 64, Bsb1, wid, srow, gcol);
  asm volatile("s_waitcnt vmcnt(8)" ::: "memory");    // k0 landed
  __builtin_amdgcn_s_barrier();

  for (int t=0; t<4; t++){
    const u16* As = (t & 1) ? Asb1 : Asb0;
    const u16* Bs = (t & 1) ? Bsb1 : Bsb0;
    #pragma unroll
    for (int kk=0; kk<2; kk++){
      bf16x8 af[4], bfr[4];
      const int soff = ((kk*4 + quad) ^ (r16 & 7)) * 8;
      #pragma unroll
      for (int mt=0; mt<4; mt++)
        af[mt] = *(const bf16x8*)&As[(waveM + mt*16 + r16)*64 + soff];
      #pragma unroll
      for (int nt=0; nt<4; nt++)
        bfr[nt] = *(const bf16x8*)&Bs[(waveN + nt*16 + r16)*64 + soff];
      #pragma unroll
      for (int mt=0; mt<4; mt++)
        #pragma unroll
        for (int nt=0; nt<4; nt++)
          acc[mt][nt] = __builtin_amdgcn_mfma_f32_16x16x32_bf16(af[mt], bfr[nt], acc[mt][nt], 0, 0, 0);
    }
    if (t < 3){
      __builtin_amdgcn_s_barrier();                   // readers done with buf[t&1]
      if (t + 2 < 4){
        stageF(Ag, (t+2)*64, (t & 1) ? Asb1 : Asb0, wid, srow, gcol);
        stageF(Bg, (t+2)*64, (t & 1) ? Bsb1 : Bsb0, wid, srow, gcol);
        asm volatile("s_waitcnt vmcnt(8)" ::: "memory");  // k(t+1) published
      } else {
        asm volatile("s_waitcnt vmcnt(0)" ::: "memory");  // drain k3
      }
      __builtin_amdgcn_s_barrier();
    }
  }

  float s[4] = {0,0,0,0}, s2[4] = {0,0,0,0};
  #pragma unroll
  for (int mt=0; mt<4; mt++){
    #pragma unroll
    for (int reg=0; reg<4; reg++){
      int grow = m0 + waveM + mt*16 + quad*4 + reg;
      #pragma unroll
      for (int nt=0; nt<4; nt++){
        int gcolo = n0 + waveN + nt*16 + r16;
        size_t idx = (size_t)grow*3072 + gcolo;
        float v = acc[mt][nt][reg] + bias[gcolo] + bf2f(resb[idx]);
        out[idx] = f2bf(v);
        s[nt] += v; s2[nt] += v*v;
      }
    }
  }
  #pragma unroll
  for (int nt=0; nt<4; nt++){
    float a = s[nt], b = s2[nt];
    a += __shfl_xor(a, 16); a += __shfl_xor(a, 32);
    b += __shfl_xor(b, 16); b += __shfl_xor(b, 32);
    if (quad == 0){
      int col = n0 + waveN + nt*16 + r16;
      atomicAdd(&stp[col], a);
      atomicAdd(&stp[3072 + col], b);
    }
  }
}

// ---------------- FF1: out bf16 = relu(A@W1^T + bias), 32x128 tiles, 3-slot pipeline ----------------
__device__ __forceinline__ void stageR_A(const u16* __restrict__ g, int kc, u16* __restrict__ slot,
                                         int tid, int srow, int gcol){
  gload_lds16(&g[(size_t)srow*3072 + kc + gcol], slot + tid*8);
}
__device__ __forceinline__ void stageR_B(const u16* __restrict__ g, int kc, u16* __restrict__ slot,
                                         int tid, int srow, int gcol){
  #pragma unroll
  for (int i=0;i<4;i++)
    gload_lds16(&g[(size_t)(srow + i*32)*3072 + kc + gcol], slot + 2048 + i*2048 + tid*8);
}

__global__ __launch_bounds__(256)
void gemm_relu(const u16* __restrict__ A, const u16* __restrict__ B,
               const float* __restrict__ bias, u16* __restrict__ out)
{
  __shared__ __align__(16) u16 smem[30720];   // 3 slots x (A 2048 + B 8192) u16 = 60 KB
  const int tid = threadIdx.x, lane = tid & 63, wid = tid >> 6;
  const int quad = lane >> 4, r16 = lane & 15;
  const int waveM = (wid >> 1) * 16, waveN = (wid & 1) * 64;
  const int m0 = blockIdx.x * 32, n0 = blockIdx.y * 128;
  const u16* Ag = A + (size_t)m0 * 3072;
  const u16* Bg = B + (size_t)n0 * 3072;

  const int srow = tid >> 3;                        // 0..31
  const int gcol = ((tid & 7) ^ (srow & 7)) * 8;    // swizzled source column

  f4 acc[4];
  #pragma unroll
  for (int n=0;n<4;n++)
    #pragma unroll
    for (int q=0;q<4;q++) acc[n][q] = 0.f;

  u16* Sa = smem;            // tile t
  u16* Sb = smem + 10240;    // tile t+1
  u16* Sc = smem + 20480;    // tile t+2 (stage target)

  stageR_A(Ag, 0,  Sa, tid, srow, gcol);
  stageR_B(Bg, 0,  Sa, tid, srow, gcol);
  stageR_A(Ag, 64, Sb, tid, srow, gcol);
  stageR_B(Bg, 64, Sb, tid, srow, gcol);
  asm volatile("s_waitcnt vmcnt(5)" ::: "memory");   // tile 0 landed
  __builtin_amdgcn_s_barrier();

  const int NT = 48;                                 // K = 3072, BK = 64
  const int s0 = (quad ^ (r16 & 7)) * 8;
  const int s1 = ((4 + quad) ^ (r16 & 7)) * 8;

  for (int t=0; t<NT; ++t){
    const int kc2 = ((t+2 < NT) ? (t+2) : 0) * 64;

    // p0: kk=0; stage A(t+2)
    bf16x8 a0 = *(const bf16x8*)&Sa[(waveM + r16)*64 + s0];
    bf16x8 b0[4];
    #pragma unroll
    for (int n=0;n<4;n++) b0[n] = *(const bf16x8*)&Sa[2048 + (waveN + n*16 + r16)*64 + s0];
    stageR_A(Ag, kc2, Sc, tid, srow, gcol);
    __builtin_amdgcn_s_setprio(1);
    #pragma unroll
    for (int n=0;n<4;n++)
      acc[n] = __builtin_amdgcn_mfma_f32_16x16x32_bf16(a0, b0[n], acc[n], 0,0,0);
    __builtin_amdgcn_s_setprio(0);

    // p1: kk=1; stage B(t+2)
    bf16x8 a1 = *(const bf16x8*)&Sa[(waveM + r16)*64 + s1];
    bf16x8 b1[4];
    #pragma unroll
    for (int n=0;n<4;n++) b1[n] = *(const bf16x8*)&Sa[2048 + (waveN + n*16 + r16)*64 + s1];
    stageR_B(Bg, kc2, Sc, tid, srow, gcol);
    __builtin_amdgcn_s_setprio(1);
    #pragma unroll
    for (int n=0;n<4;n++)
      acc[n] = __builtin_amdgcn_mfma_f32_16x16x32_bf16(a1, b1[n], acc[n], 0,0,0);
    __builtin_amdgcn_s_setprio(0);

    asm volatile("s_waitcnt vmcnt(5)" ::: "memory"); // tile t+1 published
    __builtin_amdgcn_s_barrier();
    u16* tp = Sa; Sa = Sb; Sb = Sc; Sc = tp;
  }
  asm volatile("s_waitcnt vmcnt(0)" ::: "memory");   // drain clamped tail DMAs

  #pragma unroll
  for (int n=0;n<4;n++){
    int gcolo = n0 + waveN + n*16 + r16;
    float bv = bias[gcolo];
    #pragma unroll
    for (int reg=0; reg<4; reg++){
      int grow = m0 + waveM + quad*4 + reg;
      float v = acc[n][reg] + bv;
      out[(size_t)grow*256 + gcolo] = f2bf(v > 0.f ? v : 0.f);
    }
  }
}

// ---------------- merged attention: blocks [0,6144) temporal MFMA, [6144,9984) spatial ----------------
// Spatial q/k/v use (bt, j, h, d) layout (qkv epilogue coalescing); sa output layout unchanged.
__global__ __launch_bounds__(256)
void attn_both(const u16* __restrict__ qt, const u16* __restrict__ kt,
               const u16* __restrict__ vt, u16* __restrict__ ta,
               const u16* __restrict__ qsp, const u16* __restrict__ ksp,
               const u16* __restrict__ vsp, u16* __restrict__ sa)
{
  __shared__ __align__(16) char smem[39168];
  int tid = threadIdx.x, lane = tid & 63, wid = tid >> 6;
  int quad = lane >> 4, r16 = lane & 15;

  if (blockIdx.x < 6144){
    // ---- temporal: one block per (b,h,j), T=120 pad 128, d=16 pad 32 ----
    u16* P  = (u16*)smem;             // 128*LDP
    u16* Vt = (u16*)(smem + 34816);   // 16*LDP
    int blk = blockIdx.x;
    int b = blk / 192;
    int rem = blk % 192;
    int h = rem / 24, j = rem % 24;
    const u16* qb = qt + (size_t)blk*1920;
    const u16* kb = kt + (size_t)blk*1920;
    const u16* vb = vt + (size_t)blk*1920;

    // vectorized V staging: 240 threads x one bf16x8 (16B) global load, transpose into LDS
    if (tid < 240){
      int s = tid >> 1, hf = (tid & 1) * 8;
      bf16x8 vv = *(const bf16x8*)&vb[s*16 + hf];
      #pragma unroll
      for (int q=0;q<8;q++) Vt[(hf + q)*LDP + s] = __builtin_bit_cast(u16, (__bf16)vv[q]);
    }
    if (tid < 128){ int dd = tid >> 3, s = 120 + (tid & 7); Vt[dd*LDP + s] = 0; }
    __syncthreads();

    bf16x8 zv;
    #pragma unroll
    for (int i=0;i<8;i++) zv[i] = (__bf16)0.f;

    const int m0 = wid * 32;
    bf16x8 qf[2];
    #pragma unroll
    for (int mt=0; mt<2; mt++){
      int row = m0 + mt*16 + r16; if (row > 119) row = 119;
      qf[mt] = (quad < 2) ? *(const bf16x8*)&qb[row*16 + (quad&1)*8] : zv;
    }

    f4 S[2][8];
    #pragma unroll
    for (int nt=0; nt<8; nt++){
      int col = nt*16 + r16; int colc = col > 119 ? 119 : col;
      bf16x8 kf = (quad < 2) ? *(const bf16x8*)&kb[colc*16 + (quad&1)*8] : zv;
      #pragma unroll
      for (int mt=0; mt<2; mt++){
        f4 zz = {0.f, 0.f, 0.f, 0.f};
        S[mt][nt] = __builtin_amdgcn_mfma_f32_16x16x32_bf16(qf[mt], kf, zz, 0, 0, 0);
      }
    }

    #pragma unroll
    for (int mt=0; mt<2; mt++)
      #pragma unroll
      for (int nt=0; nt<8; nt++)
        #pragma unroll
        for (int reg=0; reg<4; reg++){
          int c = nt*16 + r16;
          int r = m0 + mt*16 + quad*4 + reg;
          float v = S[mt][nt][reg] * 0.25f;
          S[mt][nt][reg] = (c > r || c >= 120) ? -1e30f : v;
        }

    float Zr[2][4];
    #pragma unroll
    for (int mt=0; mt<2; mt++)
      #pragma unroll
      for (int reg=0; reg<4; reg++){
        float m = -1e30f;
        #pragma unroll
        for (int nt=0; nt<8; nt++) m = fmaxf(m, S[mt][nt][reg]);
        #pragma unroll
        for (int off=1; off<16; off<<=1) m = fmaxf(m, __shfl_xor(m, off, 16));
        float z = 0.f;
        #pragma unroll
        for (int nt=0; nt<8; nt++){
          float e = __expf(S[mt][nt][reg] - m);
          S[mt][nt][reg] = e;
          z += e;
        }
        #pragma unroll
        for (int off=1; off<16; off<<=1) z += __shfl_xor(z, off, 16);
        Zr[mt][reg] = z;
      }

    #pragma unroll
    for (int mt=0; mt<2; mt++)
      #pragma unroll
      for (int nt=0; nt<8; nt++)
        #pragma unroll
        for (int reg=0; reg<4; reg++)
          P[(m0 + mt*16 + quad*4 + reg)*LDP + nt*16 + r16] = f2bf(S[mt][nt][reg]);
    // NO barrier here: PV reads only P rows m0..m0+31, written by THIS wave
    // (rows are wave-private); compiler inserts the intra-wave lgkmcnt wait.

    f4 O[2];
    #pragma unroll
    for (int mt=0; mt<2; mt++){ O[mt][0]=0.f; O[mt][1]=0.f; O[mt][2]=0.f; O[mt][3]=0.f; }
    #pragma unroll
    for (int kt8=0; kt8<4; kt8++){
      bf16x8 vf = *(const bf16x8*)&Vt[r16*LDP + kt8*32 + quad*8];
      #pragma unroll
      for (int mt=0; mt<2; mt++){
        bf16x8 pf = *(const bf16x8*)&P[(m0 + mt*16 + r16)*LDP + kt8*32 + quad*8];
        O[mt] = __builtin_amdgcn_mfma_f32_16x16x32_bf16(pf, vf, O[mt], 0, 0, 0);
      }
    }

    #pragma unroll
    for (int mt=0; mt<2; mt++)
      #pragma unroll
      for (int reg=0; reg<4; reg++){
        int r = m0 + mt*16 + quad*4 + reg;
        if (r < 120){
          size_t idx = (size_t)(b*120 + r)*3072 + h*384 + j*16 + r16;
          ta[idx] = f2bf(O[mt][reg] / Zr[mt][reg]);
        }
      }
  } else {
    // ---- spatial: one block per (b,t); threads 0..191 = (h,j); softmax over 24 joints ----
    float* Ks = (float*)smem;            // 3072
    float* Vs = (float*)(smem + 12288);  // 3072
    int bt = blockIdx.x - 6144;
    size_t base = (size_t)bt * 3072;
    for (int c = tid; c < 384; c += 256){
      bf16x8 kv = *(const bf16x8*)&ksp[base + c*8];
      bf16x8 vv = *(const bf16x8*)&vsp[base + c*8];
      #pragma unroll
      for (int i=0;i<8;i++){ Ks[c*8+i] = (float)kv[i]; Vs[c*8+i] = (float)vv[i]; }
    }
    __syncthreads();
    if (tid < 192){
      int h = tid / 24, j = tid % 24;
      float q[16];
      #pragma unroll
      for (int d2=0; d2<16; d2++) q[d2] = bf2f(qsp[base + j*128 + h*16 + d2]);   // (bt,j,h,d)
      float sc[24], mx = -1e30f;
      #pragma unroll
      for (int kk=0; kk<24; kk++){
        float dot = 0.f;
        #pragma unroll
        for (int d2=0; d2<16; d2++) dot += q[d2]*Ks[kk*128 + h*16 + d2];         // (j,h,d)
        sc[kk] = dot * 0.25f;
        mx = fmaxf(mx, sc[kk]);
      }
      float Z = 0.f, acc[16];
      #pragma unroll
      for (int d2=0; d2<16; d2++) acc[d2] = 0.f;
      #pragma unroll
      for (int kk=0; kk<24; kk++){
        float w = __expf(sc[kk] - mx);
        Z += w;
        #pragma unroll
        for (int d2=0; d2<16; d2++) acc[d2] += w*Vs[kk*128 + h*16 + d2];         // (j,h,d)
      }
      float inv = 1.f / Z;
      #pragma unroll
      for (int d2=0; d2<16; d2++) sa[base + h*384 + j*16 + d2] = f2bf(acc[d2]*inv);  // UNCHANGED layout
    }
  }
}

// ---------------- batchnorm ----------------
// blocks 0..11: temporal coefs; 12..23: spatial coefs
__global__ void bn_coef2(const float* __restrict__ accT, const float* __restrict__ gT,
                         const float* __restrict__ bT, float* __restrict__ cT,
                         const float* __restrict__ accS, const float* __restrict__ gS,
                         const float* __restrict__ bS, float* __restrict__ cS){
  int isS = blockIdx.x >= 12;
  const float* acc = isS ? accS : accT;
  const float* g   = isS ? gS : gT;
  const float* b   = isS ? bS : bT;
  float* coef      = isS ? cS : cT;
  int c = (blockIdx.x % 12)*256 + threadIdx.x;
  float mean = acc[c] * (1.f/3840.f);
  float var  = acc[3072+c] * (1.f/3840.f) - mean*mean;
  float sc = g[c] * rsqrtf(var + 1e-5f);
  coef[c] = sc;
  coef[3072+c] = b[c] - mean*sc;
}

__global__ void bn_coef(const float* __restrict__ acc, const float* __restrict__ g,
                        const float* __restrict__ b, float* __restrict__ coef){
  int c = blockIdx.x*256 + threadIdx.x;
  float mean = acc[c] * (1.f/3840.f);
  float var  = acc[3072+c] * (1.f/3840.f) - mean*mean;
  float sc = g[c] * rsqrtf(var + 1e-5f);
  coef[c] = sc;
  coef[3072+c] = b[c] - mean*sc;
}

// att = BN_t(Yt) + BN_s(Ys), vectorized x4  (channel = (i*4) mod 3072 — NOT a pow2 mask!)
__global__ void bn_apply2(const u16* __restrict__ Ytb, const u16* __restrict__ Ysb,
                          const float* __restrict__ ct, const float* __restrict__ cs,
                          u16* __restrict__ attB){
  int i = blockIdx.x*256 + threadIdx.x;     // < NX/4
  int c = (i*4) % 3072;
  u16x4 yt = *(const u16x4*)&Ytb[i*4];
  u16x4 ys = *(const u16x4*)&Ysb[i*4];
  u16x4 o;
  #pragma unroll
  for (int k=0;k<4;k++){
    float a = bf2f(yt[k])*ct[c+k] + ct[3072+c+k] + bf2f(ys[k])*cs[c+k] + cs[3072+c+k];
    o[k] = f2bf(a);
  }
  *(u16x4*)&attB[i*4] = o;
}

__global__ void bn_out(const u16* __restrict__ Yfb, const float* __restrict__ cf,
                       float* __restrict__ out){
  int i = blockIdx.x*256 + threadIdx.x;     // < NX/4
  int c = (i*4) % 3072;
  u16x4 yf = *(const u16x4*)&Yfb[i*4];
  float4v o;
  #pragma unroll
  for (int k=0;k<4;k++) o[k] = bf2f(yf[k])*cf[c+k] + cf[3072+c+k];
  *(float4v*)&out[i*4] = o;
}

// ---------------- launch ----------------
extern "C" void kernel_launch(void* const* d_in, const int* in_sizes, int n_in,
                              void* d_out, int out_size, void* d_ws, size_t ws_size,
                              hipStream_t stream)
{
  const float* src  = (const float*)d_in[0];
  const float* Wq_t = (const float*)d_in[1];
  const float* Wk_t = (const float*)d_in[2];
  const float* Wv_t = (const float*)d_in[3];
  const float* Wp_t = (const float*)d_in[4];
  const float* bp_t = (const float*)d_in[5];
  const float* g_t  = (const float*)d_in[6];
  const float* b_t  = (const float*)d_in[7];
  const float* Wq_s = (const float*)d_in[8];
  const float* Wk_s = (const float*)d_in[9];
  const float* Wv_s = (const float*)d_in[10];
  const float* Wp_s = (const float*)d_in[11];
  const float* bp_s = (const float*)d_in[12];
  const float* g_s  = (const float*)d_in[13];
  const float* b_s  = (const float*)d_in[14];
  const float* W1   = (const float*)d_in[15];
  const float* b1   = (const float*)d_in[16];
  const float* W2   = (const float*)d_in[17];
  const float* b2   = (const float*)d_in[18];
  const float* g_f  = (const float*)d_in[19];
  const float* b_f  = (const float*)d_in[20];

  char* ws = (char*)d_ws;
  u16* x_bf  = (u16*)(ws + 0ull);
  u16* wptb  = (u16*)(ws + 23592960ull);
  u16* wpsb  = (u16*)(ws + 42467328ull);
  u16* w1b   = (u16*)(ws + 61341696ull);
  u16* w2b   = (u16*)(ws + 62914560ull);
  u16* wcat  = (u16*)(ws + 64487424ull);
  u16* qt    = (u16*)(ws + 69206016ull);
  u16* kt    = qt + NX;
  u16* vt    = kt + NX;
  u16* qs    = vt + NX;
  u16* ks    = qs + NX;
  u16* vs    = ks + NX;
  u16* tab   = (u16*)(ws + 210763776ull);
  u16* sab   = (u16*)(ws + 234356736ull);
  float* accT = (float*)(ws + 257949696ull);
  float* accS = accT + 6144;
  float* accF = accS + 6144;
  float* cT   = accF + 6144;
  float* cS   = cT + 6144;
  float* cF   = cS + 6144;
  // bf16 aliases over dead regions
  u16* Ytb  = qt;   // dead after attention
  u16* Ysb  = kt;
  u16* attB = vt;
  u16* Yfb  = qs;
  u16* h1   = wcat; // dead after gemm_qkv
  float* out = (float*)d_out;

  // 1. fused prep (zero accs + conversions + weight pack)
  k_prep<<<40776, 256, 0, stream>>>(src, x_bf, Wp_t, wptb, Wp_s, wpsb, W1, w1b, W2, w2b,
                                    Wq_t, Wk_t, Wv_t, Wq_s, Wk_s, Wv_s, wcat, accT);
  // 2. QKV projections (per joint; A staged once, 12 double-buffered B-chunks, coalesced stores)
  gemm_qkv<<<dim3(30,24), 256, 0, stream>>>(x_bf, wcat, qt, kt, vt, qs, ks, vs);
  // 3. both attentions in one launch
  attn_both<<<9984, 256, 0, stream>>>(qt, kt, vt, tab, qs, ks, vs, sab);
  // 4. output projections + residual + fused BN stats (256x384, 240 blocks, XCD-chunked)
  gemm_proj384<<<dim3(15,8,2), 512, 0, stream>>>(tab, wptb, bp_t, sab, wpsb, bp_s,
                                                 x_bf, Ytb, Ysb, accT, accS);
  // 5. BN coefs (t+s) + fused apply
  bn_coef2<<<24, 256, 0, stream>>>(accT, g_t, b_t, cT, accS, g_s, b_s, cS);
  bn_apply2<<<11520, 256, 0, stream>>>(Ytb, Ysb, cT, cS, attB);
  // 6. feed-forward (FF1: 240-block pipelined; FF2: double-buffered)
  gemm_relu<<<dim3(120,2), 256, 0, stream>>>(attB, w1b, b1, h1);
  gemm_ff2<<<dim3(30,24), 256, 0, stream>>>(h1, w2b, b2, attB, Yfb, accF);
  // 7. final BN
  bn_coef<<<12, 256, 0, stream>>>(accF, g_f, b_f, cF);
  bn_out<<<11520, 256, 0, stream>>>(Yfb, cF, out);
}

// Round 9
// 512.670 us; speedup vs baseline: 1.2887x; 1.0136x over previous
//
#include <hip/hip_runtime.h>

typedef unsigned short u16;
typedef __bf16 bf16x8 __attribute__((ext_vector_type(8)));
typedef float f4 __attribute__((ext_vector_type(4)));
typedef float float4v __attribute__((ext_vector_type(4)));
typedef u16 u16x4 __attribute__((ext_vector_type(4)));

#define NX 11796480   // B*T*D = 3840*3072
#define LDP 136       // padded LDS row (u16 elems) for P / Vt in temporal attn

__device__ __forceinline__ float bf2f(u16 u){ __bf16 h = __builtin_bit_cast(__bf16, u); return (float)h; }
__device__ __forceinline__ u16 f2bf(float f){ __bf16 h = (__bf16)f; return __builtin_bit_cast(u16, h); }

__device__ __forceinline__ void gload_lds16(const u16* g, u16* l){
  __builtin_amdgcn_global_load_lds((const __attribute__((address_space(1))) void*)g,
                                   (__attribute__((address_space(3))) void*)l, 16, 0, 0);
}

// ---------------- fused prep: zero BN accs + all fp32->bf16 conversions + QKV weight pack ----------------
__device__ __forceinline__ void cvt4seg(const float* __restrict__ in, u16* __restrict__ out, int i){
  float4v v = *(const float4v*)&in[i*4];
  u16x4 o;
  o[0]=f2bf(v[0]); o[1]=f2bf(v[1]); o[2]=f2bf(v[2]); o[3]=f2bf(v[3]);
  *(u16x4*)&out[i*4] = o;
}

// total items = 18432 + 2949120 + 2359296 + 2359296 + 196608 + 196608 + 2359296 = 10438656 = 40776*256
__global__ void k_prep(const float* __restrict__ src, u16* __restrict__ x_bf,
                       const float* __restrict__ wpt, u16* __restrict__ wptb,
                       const float* __restrict__ wps, u16* __restrict__ wpsb,
                       const float* __restrict__ w1,  u16* __restrict__ w1b,
                       const float* __restrict__ w2,  u16* __restrict__ w2b,
                       const float* __restrict__ wqt, const float* __restrict__ wkt,
                       const float* __restrict__ wvt, const float* __restrict__ wqs,
                       const float* __restrict__ wks, const float* __restrict__ wvs,
                       u16* __restrict__ wcat, float* __restrict__ accs){
  int i = blockIdx.x*256 + threadIdx.x;
  if (i < 18432){ accs[i] = 0.f; return; }
  i -= 18432;
  if (i < 2949120){ cvt4seg(src, x_bf, i); return; }
  i -= 2949120;
  if (i < 2359296){ cvt4seg(wpt, wptb, i); return; }
  i -= 2359296;
  if (i < 2359296){ cvt4seg(wps, wpsb, i); return; }
  i -= 2359296;
  if (i < 196608){ cvt4seg(w1, w1b, i); return; }
  i -= 196608;
  if (i < 196608){ cvt4seg(w2, w2b, i); return; }
  i -= 196608;
  // pack Wq_t|Wk_t|Wv_t|Wq_s|Wk_s|Wv_s into (J=24, N=768, K=128) row-major bf16
  int e = i & 127;
  int n = (i >> 7) % 768;
  int j = i / (768*128);
  float v;
  if (n < 512){
    int tn = n >> 7, hh = (n >> 4) & 7, dd = n & 15;
    const float* W = (tn==0)? wqt : (tn==1)? wkt : (tn==2)? wvt : wqs;  // (H,J,d,E)
    v = W[(((hh*24 + j)*16 + dd) << 7) + e];
  } else {
    int m = n - 512;
    int tn = m >> 7, hh = (m >> 4) & 7, dd = m & 15;
    const float* W = (tn==0)? wks : wvs;                                // (H,d,E)
    v = W[((hh*16 + dd) << 7) + e];
  }
  wcat[i] = f2bf(v);
}

// ---------------- QKV GEMM: A staged once; 12 B-chunks of 64 cols, double-buffered ----------------
// R9: XCD chunk swizzle (720 = 8x90 bijective): XCD k gets j in [3k,3k+3) x all 30 m-stripes,
// so each j-slice of wcat (196KB) is fetched once per XCD (L2-resident) instead of 8x.
// R8: lgkmcnt(0) before the mid barrier (cross-wave Ct ds_write -> ds_read hand-off).
// Epilogue: C-chunk staged into Ct, stored with threads mapped to OUTPUT layout:
// 8 x u16x4 (8B) stores/thread, 512B-contiguous (temporal) / 128B-contiguous (spatial (bt,j,h,d)).
// Ledger (per-wave FIFO): steady state at wait point queue is
// [stores(nc-1)(8), B(nc+1)(4), stores(nc)(8), B(nc+2)(4)] -> vmcnt(12) retires through
// B(nc+1), leaves stores(nc)+B(nc+2). nc=10: vmcnt(8) retires B11, leaves stores(10).
__device__ __forceinline__ void stageQB(const u16* __restrict__ Bb, u16* __restrict__ dst,
                                        int tid, int srow16, int gcol){
  #pragma unroll
  for (int it=0; it<4; it++){
    int row = srow16 + it*16;
    gload_lds16(&Bb[(size_t)row*128 + gcol], dst + tid*8 + it*2048);
  }
}

__global__ __launch_bounds__(256)
void gemm_qkv(const u16* __restrict__ x, const u16* __restrict__ wcat,
              u16* __restrict__ qt, u16* __restrict__ kt, u16* __restrict__ vt,
              u16* __restrict__ qs, u16* __restrict__ ks, u16* __restrict__ vs)
{
  __shared__ __align__(16) u16 smem[40960];    // 80 KB (2 blocks/CU)
  u16* As  = smem;            // 32 KB: A tile 128x128
  u16* Bs0 = smem + 16384;    // 16 KB
  u16* Bs1 = smem + 24576;    // 16 KB
  u16* Ct  = smem + 32768;    // 16 KB: C chunk 128x64
  // bijective XCD chunk swizzle over 720 blocks (grid 30x24)
  int lin = blockIdx.x + 30*blockIdx.y;
  int nl  = (lin & 7)*90 + (lin >> 3);
  int j   = nl / 30;
  int bx  = nl - j*30;
  int m0  = bx*128;
  const u16* Ab = x + (size_t)m0*3072 + j*128;
  const u16* Bbase = wcat + (size_t)j*98304;
  int tid = threadIdx.x, lane = tid & 63, wid = tid >> 6;
  int quad = lane >> 4, r16 = lane & 15;
  int srow16 = tid >> 4;                   // 0..15
  int gcol   = ((tid & 15) ^ srow16) * 8;  // swizzled source column

  #pragma unroll
  for (int it=0; it<8; it++){
    int row = srow16 + it*16;
    gload_lds16(&Ab[(size_t)row*3072 + gcol], As + tid*8 + it*2048);
  }
  stageQB(Bbase,            Bs0, tid, srow16, gcol);   // B chunk 0
  stageQB(Bbase + 64*128,   Bs1, tid, srow16, gcol);   // B chunk 1
  asm volatile("s_waitcnt vmcnt(4)" ::: "memory");     // A + B0 landed
  __builtin_amdgcn_s_barrier();

  // epilogue store mapping (constant per thread)
  const int c0 = (tid & 15) * 4;      // col base 0..60
  const int hl = c0 >> 4;             // hh_local 0..3
  const int d0 = c0 & 15;             // 0,4,8,12

  for (int nc=0; nc<12; nc++){
    const u16* Bc = (nc & 1) ? Bs1 : Bs0;

    f4 acc[2][4];
    #pragma unroll
    for (int mt=0; mt<2; mt++)
      #pragma unroll
      for (int nt=0; nt<4; nt++)
        #pragma unroll
        for (int q=0; q<4; q++) acc[mt][nt][q] = 0.f;

    #pragma unroll
    for (int kk=0; kk<4; kk++){
      const int soff = ((kk*4 + quad) ^ r16) * 8;
      bf16x8 af[2], bfr[4];
      #pragma unroll
      for (int mt=0; mt<2; mt++)
        af[mt] = *(const bf16x8*)&As[(wid*32 + mt*16 + r16)*128 + soff];
      #pragma unroll
      for (int nt=0; nt<4; nt++)
        bfr[nt] = *(const bf16x8*)&Bc[(nt*16 + r16)*128 + soff];
      #pragma unroll
      for (int mt=0; mt<2; mt++)
        #pragma unroll
        for (int nt=0; nt<4; nt++)
          acc[mt][nt] = __builtin_amdgcn_mfma_f32_16x16x32_bf16(af[mt], bfr[nt], acc[mt][nt], 0, 0, 0);
    }

    // ---- C chunk -> LDS ----
    #pragma unroll
    for (int mt=0; mt<2; mt++)
      #pragma unroll
      for (int reg=0; reg<4; reg++){
        int row = wid*32 + mt*16 + quad*4 + reg;
        #pragma unroll
        for (int nt=0; nt<4; nt++)
          Ct[row*64 + nt*16 + r16] = f2bf(acc[mt][nt][reg]);
      }
    asm volatile("s_waitcnt lgkmcnt(0)" ::: "memory");  // drain Ct ds_writes (raw barrier doesn't)
    __builtin_amdgcn_s_barrier();          // Ct published; all waves done reading Bs[nc&1]

    // ---- coalesced u16x4 stores from Ct ----
    if (nc < 6){
      int tn = nc >> 1;
      u16* base = (tn==0)? qt : (tn==1)? kt : vt;
      int hh = (nc & 1)*4 + hl;
      #pragma unroll
      for (int g=0; g<8; g++){
        int row = g*16 + (tid >> 4);
        int gr = m0 + row;
        int b = gr / 120, t = gr - b*120;
        u16x4 v = *(const u16x4*)&Ct[row*64 + c0];
        *(u16x4*)&base[((((size_t)(b*8+hh)*24 + j)*120 + t) << 4) + d0] = v;
      }
    } else {
      int tn = (nc - 6) >> 1;
      u16* base = (tn==0)? qs : (tn==1)? ks : vs;
      int hh = ((nc - 6) & 1)*4 + hl;
      #pragma unroll
      for (int g=0; g<8; g++){
        int row = g*16 + (tid >> 4);
        size_t gr = (size_t)(m0 + row);
        u16x4 v = *(const u16x4*)&Ct[row*64 + c0];
        *(u16x4*)&base[gr*3072 + j*128 + hh*16 + d0] = v;   // (bt, j, h, d) layout
      }
    }

    if (nc < 11){
      if (nc + 2 < 12){
        stageQB(Bbase + (size_t)(nc+2)*64*128, (nc & 1) ? Bs1 : Bs0, tid, srow16, gcol);
        asm volatile("s_waitcnt vmcnt(12)" ::: "memory");  // B(nc+1) retired; stores+B(nc+2) fly
      } else {
        asm volatile("s_waitcnt vmcnt(8)" ::: "memory");   // B11 retired; stores(10) fly
      }
      __builtin_amdgcn_s_barrier();
    }
  }
}

// ================= 256x384 dual-projection GEMM, BK=32, 3-slot rotating LDS =================
// (R3-verified structure: ~132-147 µs (session clock variance), MfmaUtil 42-48%.
//  R4's merged-cluster variant regressed — the p0/p1 split + setprio fences ARE the pipeline.
//  LDS-read pipe analysis: ~896 cyc/CU/tile LDS vs 466 MFMA -> structural ceiling ~52% MfmaUtil;
//  measured ~47% = 90% of ceiling. Do not touch without a larger-register-tile rewrite.)
__device__ __forceinline__ void stageA384(const u16* __restrict__ g, int kcol,
                                          u16* __restrict__ slotA, int lane, int wid){
  #pragma unroll
  for (int i=0;i<2;i++){
    int row = wid*32 + i*16 + (lane>>2);
    int sw  = (((lane & 3) ^ ((lane>>3) & 3)) << 3);   // inverse of read swizzle
    gload_lds16(&g[(size_t)row*3072 + kcol + sw], slotA + (wid*2+i)*512);
  }
}
__device__ __forceinline__ void stageB384(const u16* __restrict__ g, int kcol,
                                          u16* __restrict__ slotB, int lane, int wid){
  #pragma unroll
  for (int i=0;i<3;i++){
    int row = wid*48 + i*16 + (lane>>2);
    int sw  = (((lane & 3) ^ ((lane>>3) & 3)) << 3);
    gload_lds16(&g[(size_t)row*3072 + kcol + sw], slotB + (wid*3+i)*512);
  }
}

__global__ __launch_bounds__(512, 2)
void gemm_proj384(const u16* __restrict__ A0, const u16* __restrict__ B0, const float* __restrict__ b0,
                  const u16* __restrict__ A1, const u16* __restrict__ B1, const float* __restrict__ b1v,
                  const u16* __restrict__ resb, u16* __restrict__ O0, u16* __restrict__ O1,
                  float* __restrict__ st0, float* __restrict__ st1)
{
  __shared__ __align__(16) u16 smem[61440];     // 120 KiB = 3 slots x 20480 u16
  const int tid = threadIdx.x, lane = tid & 63, wid = tid >> 6;
  const int quad = lane >> 4, r16 = lane & 15;
  const int wm = wid >> 2, wn = wid & 3;

  // bijective XCD chunk swizzle over 240 blocks
  int lin = blockIdx.x + 15*blockIdx.y + 120*blockIdx.z;
  int nidx = (lin & 7)*30 + (lin >> 3);
  int zz = nidx / 120; int rem = nidx - zz*120;
  int by = rem / 15, bx = rem - by*15;

  const int m0 = bx*256, n0 = by*384;
  const u16* Ag = (zz ? A1 : A0) + (size_t)m0*3072;
  const u16* Bg = (zz ? B1 : B0) + (size_t)n0*3072;
  const float* bias = zz ? b1v : b0;
  u16* out = zz ? O1 : O0;
  float* stp = zz ? st1 : st0;

  const int soff = ((quad ^ ((r16>>1)&3)) << 3);
  const int arow = wm*128 + r16;
  const int brow = wn*96 + r16;

  f4 acc[8][6];
  #pragma unroll
  for (int i=0;i<8;i++)
    #pragma unroll
    for (int n=0;n<6;n++)
      #pragma unroll
      for (int q=0;q<4;q++) acc[i][n][q] = 0.f;

  u16* Sa = smem;            // slot holding tile t
  u16* Sb = smem + 20480;    // tile t+1
  u16* Sc = smem + 40960;    // tile t+2 (stage target)

  // prologue: tiles 0 and 1 (10 issues/wave)
  stageA384(Ag, 0,  Sa,        lane, wid);
  stageB384(Bg, 0,  Sa + 8192, lane, wid);
  stageA384(Ag, 32, Sb,        lane, wid);
  stageB384(Bg, 32, Sb + 8192, lane, wid);
  asm volatile("s_waitcnt vmcnt(5)" ::: "memory");   // tile 0 landed
  __builtin_amdgcn_s_barrier();

  const int NT = 96;                                 // K = 3072, BK = 32
  bf16x8 af[4], bf[6];

  for (int t=0; t<NT; ++t){
    const int kc2 = ((t+2 < NT) ? (t+2) : 0) * 32;   // clamped tail lands in dead slot

    // ---- p0: m-group 0 + all B frags; stage A(t+2) ----
    #pragma unroll
    for (int i=0;i<4;i++) af[i] = *(const bf16x8*)&Sa[(arow + i*16)*32 + soff];
    #pragma unroll
    for (int n=0;n<6;n++) bf[n] = *(const bf16x8*)&Sa[8192 + (brow + n*16)*32 + soff];
    stageA384(Ag, kc2, Sc, lane, wid);
    __builtin_amdgcn_s_setprio(1);
    #pragma unroll
    for (int i=0;i<4;i++)
      #pragma unroll
      for (int n=0;n<6;n++)
        acc[i][n] = __builtin_amdgcn_mfma_f32_16x16x32_bf16(af[i], bf[n], acc[i][n], 0,0,0);
    __builtin_amdgcn_s_setprio(0);

    // ---- p1: m-group 1 (reuse bf); stage B(t+2) ----
    #pragma unroll
    for (int i=0;i<4;i++) af[i] = *(const bf16x8*)&Sa[(arow + 64 + i*16)*32 + soff];
    stageB384(Bg, kc2, Sc + 8192, lane, wid);
    __builtin_amdgcn_s_setprio(1);
    #pragma unroll
    for (int i=0;i<4;i++)
      #pragma unroll
      for (int n=0;n<6;n++)
        acc[4+i][n] = __builtin_amdgcn_mfma_f32_16x16x32_bf16(af[i], bf[n], acc[4+i][n], 0,0,0);
    __builtin_amdgcn_s_setprio(0);

    asm volatile("s_waitcnt vmcnt(5)" ::: "memory"); // tile t+1 published
    __builtin_amdgcn_s_barrier();
    u16* tp = Sa; Sa = Sb; Sb = Sc; Sc = tp;         // rotate slots
  }
  asm volatile("s_waitcnt vmcnt(0)" ::: "memory");   // drain clamped tail DMAs

  // ---------- epilogue: bias + residual + bf16 store + fused BN stats ----------
  float bv[6];
  #pragma unroll
  for (int n=0;n<6;n++) bv[n] = bias[n0 + wn*96 + n*16 + r16];
  float s[6] = {0,0,0,0,0,0}, s2[6] = {0,0,0,0,0,0};
  #pragma unroll
  for (int mf=0; mf<8; mf++){
    #pragma unroll
    for (int reg=0; reg<4; reg++){
      int grow = m0 + wm*128 + mf*16 + quad*4 + reg;
      #pragma unroll
      for (int n=0;n<6;n++){
        int gcol = n0 + wn*96 + n*16 + r16;
        size_t idx = (size_t)grow*3072 + gcol;
        float v = acc[mf][n][reg] + bv[n] + bf2f(resb[idx]);
        out[idx] = f2bf(v);
        s[n] += v; s2[n] += v*v;
      }
    }
  }
  #pragma unroll
  for (int n=0;n<6;n++){
    float a = s[n], b = s2[n];
    a += __shfl_xor(a, 16); a += __shfl_xor(a, 32);
    b += __shfl_xor(b, 16); b += __shfl_xor(b, 32);
    if (quad == 0){
      int col = n0 + wn*96 + n*16 + r16;
      atomicAdd(&stp[col], a);
      atomicAdd(&stp[3072 + col], b);
    }
  }
}

// ---------------- FF2 with fused BN stats: 128x128, K=256, double-buffered pipeline ----------------
// R9: XCD chunk swizzle (720 = 8x90): each XCD gets a contiguous m-range x all n,
// so h1 (1.9 MB) is L2-resident per XCD instead of refetched per (x,y).
__device__ __forceinline__ void stageF(const u16* __restrict__ g, int k0,
                                       u16* __restrict__ dst, int wid, int srow, int gcol){
  #pragma unroll
  for (int i=0;i<4;i++){
    int row = srow + i*32;
    gload_lds16(&g[(size_t)row*256 + k0 + gcol], dst + wid*512 + i*2048);
  }
}

__global__ __launch_bounds__(256)
void gemm_ff2(const u16* __restrict__ A, const u16* __restrict__ B, const float* __restrict__ bias,
              const u16* __restrict__ resb, u16* __restrict__ out, float* __restrict__ stp)
{
  __shared__ __align__(16) u16 smem[32768];   // 64 KB
  u16* Asb0 = smem;          u16* Asb1 = smem + 8192;
  u16* Bsb0 = smem + 16384;  u16* Bsb1 = smem + 24576;
  // bijective XCD chunk swizzle over 720 blocks (grid 30x24): m-major chunks
  int lin = blockIdx.x + 30*blockIdx.y;
  int nl  = (lin & 7)*90 + (lin >> 3);
  int bxx = nl / 24;
  int byy = nl - bxx*24;
  int m0 = bxx*128, n0 = byy*128;
  const u16* Ag = A + (size_t)m0*256;
  const u16* Bg = B + (size_t)n0*256;
  int tid = threadIdx.x, lane = tid & 63, wid = tid >> 6;
  int quad = lane>>4, r16 = lane&15;
  int srow = tid >> 3;                       // 0..31
  int gcol = ((tid & 7) ^ (srow & 7)) * 8;   // swizzled source column
  int waveM = (wid>>1)*64, waveN = (wid&1)*64;

  f4 acc[4][4];
  #pragma unroll
  for (int mt=0; mt<4; mt++)
    #pragma unroll
    for (int nt=0; nt<4; nt++)
      #pragma unroll
      for (int q=0; q<4; q++) acc[mt][nt][q] = 0.f;

  stageF(Ag, 0,  Asb0, wid, srow, gcol);
  stageF(Bg, 0,  Bsb0, wid, srow, gcol);
  stageF(Ag, 64, Asb1, wid, srow, gcol);
  stageF(Bg, 64, Bsb1, wid, srow, gcol);
  asm volatile("s_waitcnt vmcnt(8)" ::: "memory");    // k0 landed
  __builtin_amdgcn_s_barrier();

  for (int t=0; t<4; t++){
    const u16* As = (t & 1) ? Asb1 : Asb0;
    const u16* Bs = (t & 1) ? Bsb1 : Bsb0;
    #pragma unroll
    for (int kk=0; kk<2; kk++){
      bf16x8 af[4], bfr[4];
      const int soff = ((kk*4 + quad) ^ (r16 & 7)) * 8;
      #pragma unroll
      for (int mt=0; mt<4; mt++)
        af[mt] = *(const bf16x8*)&As[(waveM + mt*16 + r16)*64 + soff];
      #pragma unroll
      for (int nt=0; nt<4; nt++)
        bfr[nt] = *(const bf16x8*)&Bs[(waveN + nt*16 + r16)*64 + soff];
      #pragma unroll
      for (int mt=0; mt<4; mt++)
        #pragma unroll
        for (int nt=0; nt<4; nt++)
          acc[mt][nt] = __builtin_amdgcn_mfma_f32_16x16x32_bf16(af[mt], bfr[nt], acc[mt][nt], 0, 0, 0);
    }
    if (t < 3){
      __builtin_amdgcn_s_barrier();                   // readers done with buf[t&1]
      if (t + 2 < 4){
        stageF(Ag, (t+2)*64, (t & 1) ? Asb1 : Asb0, wid, srow, gcol);
        stageF(Bg, (t+2)*64, (t & 1) ? Bsb1 : Bsb0, wid, srow, gcol);
        asm volatile("s_waitcnt vmcnt(8)" ::: "memory");  // k(t+1) published
      } else {
        asm volatile("s_waitcnt vmcnt(0)" ::: "memory");  // drain k3
      }
      __builtin_amdgcn_s_barrier();
    }
  }

  float s[4] = {0,0,0,0}, s2[4] = {0,0,0,0};
  #pragma unroll
  for (int mt=0; mt<4; mt++){
    #pragma unroll
    for (int reg=0; reg<4; reg++){
      int grow = m0 + waveM + mt*16 + quad*4 + reg;
      #pragma unroll
      for (int nt=0; nt<4; nt++){
        int gcolo = n0 + waveN + nt*16 + r16;
        size_t idx = (size_t)grow*3072 + gcolo;
        float v = acc[mt][nt][reg] + bias[gcolo] + bf2f(resb[idx]);
        out[idx] = f2bf(v);
        s[nt] += v; s2[nt] += v*v;
      }
    }
  }
  #pragma unroll
  for (int nt=0; nt<4; nt++){
    float a = s[nt], b = s2[nt];
    a += __shfl_xor(a, 16); a += __shfl_xor(a, 32);
    b += __shfl_xor(b, 16); b += __shfl_xor(b, 32);
    if (quad == 0){
      int col = n0 + waveN + nt*16 + r16;
      atomicAdd(&stp[col], a);
      atomicAdd(&stp[3072 + col], b);
    }
  }
}

// ---------------- FF1: out bf16 = relu(A@W1^T + bias), 32x128 tiles, 3-slot pipeline ----------------
__device__ __forceinline__ void stageR_A(const u16* __restrict__ g, int kc, u16* __restrict__ slot,
                                         int tid, int srow, int gcol){
  gload_lds16(&g[(size_t)srow*3072 + kc + gcol], slot + tid*8);
}
__device__ __forceinline__ void stageR_B(const u16* __restrict__ g, int kc, u16* __restrict__ slot,
                                         int tid, int srow, int gcol){
  #pragma unroll
  for (int i=0;i<4;i++)
    gload_lds16(&g[(size_t)(srow + i*32)*3072 + kc + gcol], slot + 2048 + i*2048 + tid*8);
}

__global__ __launch_bounds__(256)
void gemm_relu(const u16* __restrict__ A, const u16* __restrict__ B,
               const float* __restrict__ bias, u16* __restrict__ out)
{
  __shared__ __align__(16) u16 smem[30720];   // 3 slots x (A 2048 + B 8192) u16 = 60 KB
  const int tid = threadIdx.x, lane = tid & 63, wid = tid >> 6;
  const int quad = lane >> 4, r16 = lane & 15;
  const int waveM = (wid >> 1) * 16, waveN = (wid & 1) * 64;
  const int m0 = blockIdx.x * 32, n0 = blockIdx.y * 128;
  const u16* Ag = A + (size_t)m0 * 3072;
  const u16* Bg = B + (size_t)n0 * 3072;

  const int srow = tid >> 3;                        // 0..31
  const int gcol = ((tid & 7) ^ (srow & 7)) * 8;    // swizzled source column

  f4 acc[4];
  #pragma unroll
  for (int n=0;n<4;n++)
    #pragma unroll
    for (int q=0;q<4;q++) acc[n][q] = 0.f;

  u16* Sa = smem;            // tile t
  u16* Sb = smem + 10240;    // tile t+1
  u16* Sc = smem + 20480;    // tile t+2 (stage target)

  stageR_A(Ag, 0,  Sa, tid, srow, gcol);
  stageR_B(Bg, 0,  Sa, tid, srow, gcol);
  stageR_A(Ag, 64, Sb, tid, srow, gcol);
  stageR_B(Bg, 64, Sb, tid, srow, gcol);
  asm volatile("s_waitcnt vmcnt(5)" ::: "memory");   // tile 0 landed
  __builtin_amdgcn_s_barrier();

  const int NT = 48;                                 // K = 3072, BK = 64
  const int s0 = (quad ^ (r16 & 7)) * 8;
  const int s1 = ((4 + quad) ^ (r16 & 7)) * 8;

  for (int t=0; t<NT; ++t){
    const int kc2 = ((t+2 < NT) ? (t+2) : 0) * 64;

    // p0: kk=0; stage A(t+2)
    bf16x8 a0 = *(const bf16x8*)&Sa[(waveM + r16)*64 + s0];
    bf16x8 b0[4];
    #pragma unroll
    for (int n=0;n<4;n++) b0[n] = *(const bf16x8*)&Sa[2048 + (waveN + n*16 + r16)*64 + s0];
    stageR_A(Ag, kc2, Sc, tid, srow, gcol);
    __builtin_amdgcn_s_setprio(1);
    #pragma unroll
    for (int n=0;n<4;n++)
      acc[n] = __builtin_amdgcn_mfma_f32_16x16x32_bf16(a0, b0[n], acc[n], 0,0,0);
    __builtin_amdgcn_s_setprio(0);

    // p1: kk=1; stage B(t+2)
    bf16x8 a1 = *(const bf16x8*)&Sa[(waveM + r16)*64 + s1];
    bf16x8 b1[4];
    #pragma unroll
    for (int n=0;n<4;n++) b1[n] = *(const bf16x8*)&Sa[2048 + (waveN + n*16 + r16)*64 + s1];
    stageR_B(Bg, kc2, Sc, tid, srow, gcol);
    __builtin_amdgcn_s_setprio(1);
    #pragma unroll
    for (int n=0;n<4;n++)
      acc[n] = __builtin_amdgcn_mfma_f32_16x16x32_bf16(a1, b1[n], acc[n], 0,0,0);
    __builtin_amdgcn_s_setprio(0);

    asm volatile("s_waitcnt vmcnt(5)" ::: "memory"); // tile t+1 published
    __builtin_amdgcn_s_barrier();
    u16* tp = Sa; Sa = Sb; Sb = Sc; Sc = tp;
  }
  asm volatile("s_waitcnt vmcnt(0)" ::: "memory");   // drain clamped tail DMAs

  #pragma unroll
  for (int n=0;n<4;n++){
    int gcolo = n0 + waveN + n*16 + r16;
    float bv = bias[gcolo];
    #pragma unroll
    for (int reg=0; reg<4; reg++){
      int grow = m0 + waveM + quad*4 + reg;
      float v = acc[n][reg] + bv;
      out[(size_t)grow*256 + gcolo] = f2bf(v > 0.f ? v : 0.f);
    }
  }
}

// ---------------- merged attention: blocks [0,6144) temporal MFMA, [6144,9984) spatial ----------------
// Spatial q/k/v use (bt, j, h, d) layout (qkv epilogue coalescing); sa output layout unchanged.
__global__ __launch_bounds__(256)
void attn_both(const u16* __restrict__ qt, const u16* __restrict__ kt,
               const u16* __restrict__ vt, u16* __restrict__ ta,
               const u16* __restrict__ qsp, const u16* __restrict__ ksp,
               const u16* __restrict__ vsp, u16* __restrict__ sa)
{
  __shared__ __align__(16) char smem[39168];
  int tid = threadIdx.x, lane = tid & 63, wid = tid >> 6;
  int quad = lane >> 4, r16 = lane & 15;

  if (blockIdx.x < 6144){
    // ---- temporal: one block per (b,h,j), T=120 pad 128, d=16 pad 32 ----
    u16* P  = (u16*)smem;             // 128*LDP
    u16* Vt = (u16*)(smem + 34816);   // 16*LDP
    int blk = blockIdx.x;
    int b = blk / 192;
    int rem = blk % 192;
    int h = rem / 24, j = rem % 24;
    const u16* qb = qt + (size_t)blk*1920;
    const u16* kb = kt + (size_t)blk*1920;
    const u16* vb = vt + (size_t)blk*1920;

    // vectorized V staging: 240 threads x one bf16x8 (16B) global load, transpose into LDS
    if (tid < 240){
      int s = tid >> 1, hf = (tid & 1) * 8;
      bf16x8 vv = *(const bf16x8*)&vb[s*16 + hf];
      #pragma unroll
      for (int q=0;q<8;q++) Vt[(hf + q)*LDP + s] = __builtin_bit_cast(u16, (__bf16)vv[q]);
    }
    if (tid < 128){ int dd = tid >> 3, s = 120 + (tid & 7); Vt[dd*LDP + s] = 0; }
    __syncthreads();

    bf16x8 zv;
    #pragma unroll
    for (int i=0;i<8;i++) zv[i] = (__bf16)0.f;

    const int m0 = wid * 32;
    bf16x8 qf[2];
    #pragma unroll
    for (int mt=0; mt<2; mt++){
      int row = m0 + mt*16 + r16; if (row > 119) row = 119;
      qf[mt] = (quad < 2) ? *(const bf16x8*)&qb[row*16 + (quad&1)*8] : zv;
    }

    f4 S[2][8];
    #pragma unroll
    for (int nt=0; nt<8; nt++){
      int col = nt*16 + r16; int colc = col > 119 ? 119 : col;
      bf16x8 kf = (quad < 2) ? *(const bf16x8*)&kb[colc*16 + (quad&1)*8] : zv;
      #pragma unroll
      for (int mt=0; mt<2; mt++){
        f4 zz = {0.f, 0.f, 0.f, 0.f};
        S[mt][nt] = __builtin_amdgcn_mfma_f32_16x16x32_bf16(qf[mt], kf, zz, 0, 0, 0);
      }
    }

    #pragma unroll
    for (int mt=0; mt<2; mt++)
      #pragma unroll
      for (int nt=0; nt<8; nt++)
        #pragma unroll
        for (int reg=0; reg<4; reg++){
          int c = nt*16 + r16;
          int r = m0 + mt*16 + quad*4 + reg;
          float v = S[mt][nt][reg] * 0.25f;
          S[mt][nt][reg] = (c > r || c >= 120) ? -1e30f : v;
        }

    float Zr[2][4];
    #pragma unroll
    for (int mt=0; mt<2; mt++)
      #pragma unroll
      for (int reg=0; reg<4; reg++){
        float m = -1e30f;
        #pragma unroll
        for (int nt=0; nt<8; nt++) m = fmaxf(m, S[mt][nt][reg]);
        #pragma unroll
        for (int off=1; off<16; off<<=1) m = fmaxf(m, __shfl_xor(m, off, 16));
        float z = 0.f;
        #pragma unroll
        for (int nt=0; nt<8; nt++){
          float e = __expf(S[mt][nt][reg] - m);
          S[mt][nt][reg] = e;
          z += e;
        }
        #pragma unroll
        for (int off=1; off<16; off<<=1) z += __shfl_xor(z, off, 16);
        Zr[mt][reg] = z;
      }

    #pragma unroll
    for (int mt=0; mt<2; mt++)
      #pragma unroll
      for (int nt=0; nt<8; nt++)
        #pragma unroll
        for (int reg=0; reg<4; reg++)
          P[(m0 + mt*16 + quad*4 + reg)*LDP + nt*16 + r16] = f2bf(S[mt][nt][reg]);
    // NO barrier here: PV reads only P rows m0..m0+31, written by THIS wave
    // (rows are wave-private); compiler inserts the intra-wave lgkmcnt wait.

    f4 O[2];
    #pragma unroll
    for (int mt=0; mt<2; mt++){ O[mt][0]=0.f; O[mt][1]=0.f; O[mt][2]=0.f; O[mt][3]=0.f; }
    #pragma unroll
    for (int kt8=0; kt8<4; kt8++){
      bf16x8 vf = *(const bf16x8*)&Vt[r16*LDP + kt8*32 + quad*8];
      #pragma unroll
      for (int mt=0; mt<2; mt++){
        bf16x8 pf = *(const bf16x8*)&P[(m0 + mt*16 + r16)*LDP + kt8*32 + quad*8];
        O[mt] = __builtin_amdgcn_mfma_f32_16x16x32_bf16(pf, vf, O[mt], 0, 0, 0);
      }
    }

    #pragma unroll
    for (int mt=0; mt<2; mt++)
      #pragma unroll
      for (int reg=0; reg<4; reg++){
        int r = m0 + mt*16 + quad*4 + reg;
        if (r < 120){
          size_t idx = (size_t)(b*120 + r)*3072 + h*384 + j*16 + r16;
          ta[idx] = f2bf(O[mt][reg] / Zr[mt][reg]);
        }
      }
  } else {
    // ---- spatial: one block per (b,t); threads 0..191 = (h,j); softmax over 24 joints ----
    float* Ks = (float*)smem;            // 3072
    float* Vs = (float*)(smem + 12288);  // 3072
    int bt = blockIdx.x - 6144;
    size_t base = (size_t)bt * 3072;
    for (int c = tid; c < 384; c += 256){
      bf16x8 kv = *(const bf16x8*)&ksp[base + c*8];
      bf16x8 vv = *(const bf16x8*)&vsp[base + c*8];
      #pragma unroll
      for (int i=0;i<8;i++){ Ks[c*8+i] = (float)kv[i]; Vs[c*8+i] = (float)vv[i]; }
    }
    __syncthreads();
    if (tid < 192){
      int h = tid / 24, j = tid % 24;
      float q[16];
      #pragma unroll
      for (int d2=0; d2<16; d2++) q[d2] = bf2f(qsp[base + j*128 + h*16 + d2]);   // (bt,j,h,d)
      float sc[24], mx = -1e30f;
      #pragma unroll
      for (int kk=0; kk<24; kk++){
        float dot = 0.f;
        #pragma unroll
        for (int d2=0; d2<16; d2++) dot += q[d2]*Ks[kk*128 + h*16 + d2];         // (j,h,d)
        sc[kk] = dot * 0.25f;
        mx = fmaxf(mx, sc[kk]);
      }
      float Z = 0.f, acc[16];
      #pragma unroll
      for (int d2=0; d2<16; d2++) acc[d2] = 0.f;
      #pragma unroll
      for (int kk=0; kk<24; kk++){
        float w = __expf(sc[kk] - mx);
        Z += w;
        #pragma unroll
        for (int d2=0; d2<16; d2++) acc[d2] += w*Vs[kk*128 + h*16 + d2];         // (j,h,d)
      }
      float inv = 1.f / Z;
      #pragma unroll
      for (int d2=0; d2<16; d2++) sa[base + h*384 + j*16 + d2] = f2bf(acc[d2]*inv);  // UNCHANGED layout
    }
  }
}

// ---------------- batchnorm (coefs computed inline — bn_coef kernels eliminated) ----------------
// att = BN_t(Yt) + BN_s(Ys). Coef math identical to the old bn_coef2 (same fp32 sequence).
__global__ void bn_apply2(const u16* __restrict__ Ytb, const u16* __restrict__ Ysb,
                          const float* __restrict__ accT, const float* __restrict__ gT,
                          const float* __restrict__ bT,
                          const float* __restrict__ accS, const float* __restrict__ gS,
                          const float* __restrict__ bS,
                          u16* __restrict__ attB){
  int i = blockIdx.x*256 + threadIdx.x;     // < NX/4
  int c = (i*4) % 3072;
  float4v m1T = *(const float4v*)&accT[c];
  float4v m2T = *(const float4v*)&accT[3072+c];
  float4v gvT = *(const float4v*)&gT[c];
  float4v bvT = *(const float4v*)&bT[c];
  float4v m1S = *(const float4v*)&accS[c];
  float4v m2S = *(const float4v*)&accS[3072+c];
  float4v gvS = *(const float4v*)&gS[c];
  float4v bvS = *(const float4v*)&bS[c];
  u16x4 yt = *(const u16x4*)&Ytb[i*4];
  u16x4 ys = *(const u16x4*)&Ysb[i*4];
  u16x4 o;
  #pragma unroll
  for (int k=0;k<4;k++){
    float mT = m1T[k] * (1.f/3840.f);
    float vT = m2T[k] * (1.f/3840.f) - mT*mT;
    float scT = gvT[k] * rsqrtf(vT + 1e-5f);
    float offT = bvT[k] - mT*scT;
    float mS = m1S[k] * (1.f/3840.f);
    float vS = m2S[k] * (1.f/3840.f) - mS*mS;
    float scS = gvS[k] * rsqrtf(vS + 1e-5f);
    float offS = bvS[k] - mS*scS;
    float a = bf2f(yt[k])*scT + offT + bf2f(ys[k])*scS + offS;
    o[k] = f2bf(a);
  }
  *(u16x4*)&attB[i*4] = o;
}

__global__ void bn_out(const u16* __restrict__ Yfb,
                       const float* __restrict__ accF, const float* __restrict__ gF,
                       const float* __restrict__ bF,
                       float* __restrict__ out){
  int i = blockIdx.x*256 + threadIdx.x;     // < NX/4
  int c = (i*4) % 3072;
  float4v m1 = *(const float4v*)&accF[c];
  float4v m2 = *(const float4v*)&accF[3072+c];
  float4v gv = *(const float4v*)&gF[c];
  float4v bv = *(const float4v*)&bF[c];
  u16x4 yf = *(const u16x4*)&Yfb[i*4];
  float4v o;
  #pragma unroll
  for (int k=0;k<4;k++){
    float m = m1[k] * (1.f/3840.f);
    float v = m2[k] * (1.f/3840.f) - m*m;
    float sc = gv[k] * rsqrtf(v + 1e-5f);
    float off = bv[k] - m*sc;
    o[k] = bf2f(yf[k])*sc + off;
  }
  *(float4v*)&out[i*4] = o;
}

// ---------------- launch ----------------
extern "C" void kernel_launch(void* const* d_in, const int* in_sizes, int n_in,
                              void* d_out, int out_size, void* d_ws, size_t ws_size,
                              hipStream_t stream)
{
  const float* src  = (const float*)d_in[0];
  const float* Wq_t = (const float*)d_in[1];
  const float* Wk_t = (const float*)d_in[2];
  const float* Wv_t = (const float*)d_in[3];
  const float* Wp_t = (const float*)d_in[4];
  const float* bp_t = (const float*)d_in[5];
  const float* g_t  = (const float*)d_in[6];
  const float* b_t  = (const float*)d_in[7];
  const float* Wq_s = (const float*)d_in[8];
  const float* Wk_s = (const float*)d_in[9];
  const float* Wv_s = (const float*)d_in[10];
  const float* Wp_s = (const float*)d_in[11];
  const float* bp_s = (const float*)d_in[12];
  const float* g_s  = (const float*)d_in[13];
  const float* b_s  = (const float*)d_in[14];
  const float* W1   = (const float*)d_in[15];
  const float* b1   = (const float*)d_in[16];
  const float* W2   = (const float*)d_in[17];
  const float* b2   = (const float*)d_in[18];
  const float* g_f  = (const float*)d_in[19];
  const float* b_f  = (const float*)d_in[20];

  char* ws = (char*)d_ws;
  u16* x_bf  = (u16*)(ws + 0ull);
  u16* wptb  = (u16*)(ws + 23592960ull);
  u16* wpsb  = (u16*)(ws + 42467328ull);
  u16* w1b   = (u16*)(ws + 61341696ull);
  u16* w2b   = (u16*)(ws + 62914560ull);
  u16* wcat  = (u16*)(ws + 64487424ull);
  u16* qt    = (u16*)(ws + 69206016ull);
  u16* kt    = qt + NX;
  u16* vt    = kt + NX;
  u16* qs    = vt + NX;
  u16* ks    = qs + NX;
  u16* vs    = ks + NX;
  u16* tab   = (u16*)(ws + 210763776ull);
  u16* sab   = (u16*)(ws + 234356736ull);
  float* accT = (float*)(ws + 257949696ull);
  float* accS = accT + 6144;
  float* accF = accS + 6144;
  // bf16 aliases over dead regions
  u16* Ytb  = qt;   // dead after attention
  u16* Ysb  = kt;
  u16* attB = vt;
  u16* Yfb  = qs;
  u16* h1   = wcat; // dead after gemm_qkv
  float* out = (float*)d_out;

  // 1. fused prep (zero accs + conversions + weight pack)
  k_prep<<<40776, 256, 0, stream>>>(src, x_bf, Wp_t, wptb, Wp_s, wpsb, W1, w1b, W2, w2b,
                                    Wq_t, Wk_t, Wv_t, Wq_s, Wk_s, Wv_s, wcat, accT);
  // 2. QKV projections (XCD-chunked; A staged once, 12 double-buffered B-chunks, coalesced stores)
  gemm_qkv<<<dim3(30,24), 256, 0, stream>>>(x_bf, wcat, qt, kt, vt, qs, ks, vs);
  // 3. both attentions in one launch
  attn_both<<<9984, 256, 0, stream>>>(qt, kt, vt, tab, qs, ks, vs, sab);
  // 4. output projections + residual + fused BN stats (256x384, 240 blocks, XCD-chunked)
  gemm_proj384<<<dim3(15,8,2), 512, 0, stream>>>(tab, wptb, bp_t, sab, wpsb, bp_s,
                                                 x_bf, Ytb, Ysb, accT, accS);
  // 5. fused BN coef+apply (t+s)
  bn_apply2<<<11520, 256, 0, stream>>>(Ytb, Ysb, accT, g_t, b_t, accS, g_s, b_s, attB);
  // 6. feed-forward (FF1: 240-block pipelined; FF2: double-buffered, XCD-chunked)
  gemm_relu<<<dim3(120,2), 256, 0, stream>>>(attB, w1b, b1, h1);
  gemm_ff2<<<dim3(30,24), 256, 0, stream>>>(h1, w2b, b2, attB, Yfb, accF);
  // 7. fused final BN coef+apply
  bn_out<<<11520, 256, 0, stream>>>(Yfb, accF, g_f, b_f, out);
}